// Round 1
// baseline (6156.872 us; speedup 1.0000x reference)
//
#include <hip/hip_runtime.h>
#include <hip/hip_bf16.h>

// Problem constants
#define F_  9
#define B_  8
#define S_  512
#define H_  8
#define DH_ 128
#define D_  128
#define NB_ 50
#define BS_ 4096            // B_*S_ rows per feature
#define PERBUF 4194304UL    // B_*H_*S_*DH_ floats per feature for q/k/v/wv

// ---------------------------------------------------------------------------
// Pos-net: per feature f, per row (b,s):
//   gy = [Y(50), Gin_f]  -> h1 = tanh(W1 gy + b1) (50)
//   -> h2 = tanh(W2 h1 + b2) (50) -> x = sigmoid(W3 h2 + b3) (128)
// One wave per row; activations live one-per-lane, broadcast via __shfl.
// ---------------------------------------------------------------------------
__global__ __launch_bounds__(256) void posnet_kernel(
    const float* __restrict__ Y, const float* __restrict__ Gin,
    const float* __restrict__ W1g, const float* __restrict__ B1,
    const float* __restrict__ W2g, const float* __restrict__ B2,
    const float* __restrict__ W3g, const float* __restrict__ B3,
    float* __restrict__ xA)
{
    __shared__ float w1[50*51];
    __shared__ float w2[50*50];
    __shared__ float w3[128*50];
    __shared__ float b1[64], b2[64], b3[128];
    int f = blockIdx.z;
    int t = threadIdx.x;
    for (int i = t; i < 2550; i += 256) w1[i] = W1g[f*2550 + i];
    for (int i = t; i < 2500; i += 256) w2[i] = W2g[f*2500 + i];
    for (int i = t; i < 6400; i += 256) w3[i] = W3g[f*6400 + i];
    if (t < 50) { b1[t] = B1[f*50 + t]; b2[t] = B2[f*50 + t]; }
    if (t < 128) b3[t] = B3[f*128 + t];
    __syncthreads();

    int lane = t & 63, w = t >> 6;
    int row = blockIdx.x * 4 + w;   // 0..4095

    float gy = 0.f;
    if (lane < 50)       gy = Y[(size_t)row*50 + lane];
    else if (lane == 50) gy = Gin[(size_t)row*F_ + f];

    float a1 = (lane < 50) ? b1[lane] : 0.f;
    for (int kk = 0; kk < 51; ++kk) {
        float g = __shfl(gy, kk);
        if (lane < 50) a1 += w1[lane*51 + kk] * g;
    }
    float h1 = tanhf(a1);

    float a2 = (lane < 50) ? b2[lane] : 0.f;
    for (int kk = 0; kk < 50; ++kk) {
        float hh = __shfl(h1, kk);
        if (lane < 50) a2 += w2[lane*50 + kk] * hh;
    }
    float h2 = tanhf(a2);

    float a30 = b3[lane], a31 = b3[64 + lane];
    for (int kk = 0; kk < 50; ++kk) {
        float hh = __shfl(h2, kk);
        a30 += w3[lane*50 + kk] * hh;
        a31 += w3[(64 + lane)*50 + kk] * hh;
    }
    float* out = xA + ((size_t)f*BS_ + row)*128;
    out[lane]      = 1.f / (1.f + expf(-a30));
    out[64 + lane] = 1.f / (1.f + expf(-a31));
}

// ---------------------------------------------------------------------------
// QKV projection GEMM: per (f, which): C[4096 x 1024] = X[4096 x 128] * W^T.
// Tile 128(M) x 64(N), full K=128 in LDS. 8x4 micro-tile.
// Output layout q[fl][b][h][s][dh].
// ---------------------------------------------------------------------------
__global__ __launch_bounds__(256) void qkv_kernel(
    const float* __restrict__ xA,
    const float* __restrict__ Wq, const float* __restrict__ Wk, const float* __restrict__ Wv,
    const float* __restrict__ bq, const float* __restrict__ bk, const float* __restrict__ bv,
    float* __restrict__ qo, float* __restrict__ ko, float* __restrict__ vo,
    int l, int f0)
{
    __shared__ float Xs[128][132];
    __shared__ float Ws[64][132];
    int z = blockIdx.z;
    int fl = z / 3, which = z - fl*3;
    int f = f0 + fl;
    const float* W; const float* bias; float* out;
    if (which == 0)      { W = Wq; bias = bq; out = qo; }
    else if (which == 1) { W = Wk; bias = bk; out = ko; }
    else                 { W = Wv; bias = bv; out = vo; }
    W    += (size_t)(l*F_ + f) * 1024 * 128;
    bias += (size_t)(l*F_ + f) * 1024;
    out  += (size_t)fl * PERBUF;

    int m0 = blockIdx.x * 128;
    int n0 = blockIdx.y * 64;
    const float* Xg = xA + ((size_t)f*BS_ + m0)*128;
    int t = threadIdx.x;

#pragma unroll
    for (int p = 0; p < 16; ++p) {
        int idx = t + 256*p; int r = idx >> 5, c4 = idx & 31;
        *(float4*)&Xs[r][c4*4] = *(const float4*)&Xg[(size_t)r*128 + c4*4];
    }
#pragma unroll
    for (int p = 0; p < 8; ++p) {
        int idx = t + 256*p; int r = idx >> 5, c4 = idx & 31;
        *(float4*)&Ws[r][c4*4] = *(const float4*)&W[(size_t)(n0 + r)*128 + c4*4];
    }
    __syncthreads();

    int tx = t & 15, ty = t >> 4;
    float acc[8][4] = {};
    for (int kk = 0; kk < 128; kk += 4) {
        float4 xf[8], wf[4];
#pragma unroll
        for (int i = 0; i < 8; ++i) xf[i] = *(const float4*)&Xs[ty + 16*i][kk];
#pragma unroll
        for (int j = 0; j < 4; ++j) wf[j] = *(const float4*)&Ws[tx + 16*j][kk];
#pragma unroll
        for (int i = 0; i < 8; ++i)
#pragma unroll
            for (int j = 0; j < 4; ++j)
                acc[i][j] += xf[i].x*wf[j].x + xf[i].y*wf[j].y + xf[i].z*wf[j].z + xf[i].w*wf[j].w;
    }

    int h = n0 >> 7;
#pragma unroll
    for (int i = 0; i < 8; ++i) {
        int m = m0 + ty + 16*i;
        int b = m >> 9, s = m & 511;
        float* orow = out + (((size_t)(b*H_ + h))*S_ + s)*128;
#pragma unroll
        for (int j = 0; j < 4; ++j) {
            int n = n0 + tx + 16*j;
            orow[n & 127] = acc[i][j] + bias[n];
        }
    }
}

// ---------------------------------------------------------------------------
// Flash attention: grid (S/64, B*H, FC). Block 256 (4 waves).
// Q tile 64x128 stays in LDS; loop over 8 K/V tiles; online softmax.
// Thread (tr=t>>4, tc=t&15): rows {tr+16rr}, score cols {tc+16jj}, out cols tc*8..+7.
// ---------------------------------------------------------------------------
__global__ __launch_bounds__(256) void attn_kernel(
    const float* __restrict__ q, const float* __restrict__ k,
    const float* __restrict__ v, float* __restrict__ wv)
{
    __shared__ float Qs[64][132];
    __shared__ float Ks[64][132];
    __shared__ float Vs[64][132];
    __shared__ float Ps[64][65];

    int t = threadIdx.x;
    int tr = t >> 4, tc = t & 15;
    int fl = blockIdx.z, by = blockIdx.y;
    int i0 = blockIdx.x * 64;
    const float* qbp = q + ((size_t)(fl*64 + by))*S_*128;
    const float* kbp = k + ((size_t)(fl*64 + by))*S_*128;
    const float* vbp = v + ((size_t)(fl*64 + by))*S_*128;
    int b = by >> 3, h = by & 7;
    float* wvb = wv + ((size_t)(fl*B_ + b))*S_*1024 + h*128;

#pragma unroll
    for (int p = 0; p < 8; ++p) {
        int idx = t + 256*p; int r = idx >> 5, c4 = idx & 31;
        *(float4*)&Qs[r][c4*4] = *(const float4*)&qbp[(size_t)(i0 + r)*128 + c4*4];
    }

    float m_i[4], l_i[4];
    float4 acc[4][2];
#pragma unroll
    for (int rr = 0; rr < 4; ++rr) {
        m_i[rr] = -1e30f; l_i[rr] = 0.f;
        acc[rr][0] = make_float4(0.f,0.f,0.f,0.f);
        acc[rr][1] = make_float4(0.f,0.f,0.f,0.f);
    }
    const float scale = 0.08838834764831845f;   // 1/sqrt(128)

    for (int kt = 0; kt < 8; ++kt) {
        __syncthreads();   // previous PV done before K/V overwrite
#pragma unroll
        for (int p = 0; p < 8; ++p) {
            int idx = t + 256*p; int r = idx >> 5, c4 = idx & 31;
            *(float4*)&Ks[r][c4*4] = *(const float4*)&kbp[(size_t)(kt*64 + r)*128 + c4*4];
            *(float4*)&Vs[r][c4*4] = *(const float4*)&vbp[(size_t)(kt*64 + r)*128 + c4*4];
        }
        __syncthreads();

        float sc[4][4] = {};
        for (int d4 = 0; d4 < 32; ++d4) {
            float4 qf[4], kf[4];
#pragma unroll
            for (int rr = 0; rr < 4; ++rr) qf[rr] = *(const float4*)&Qs[tr + 16*rr][d4*4];
#pragma unroll
            for (int jj = 0; jj < 4; ++jj) kf[jj] = *(const float4*)&Ks[tc + 16*jj][d4*4];
#pragma unroll
            for (int rr = 0; rr < 4; ++rr)
#pragma unroll
                for (int jj = 0; jj < 4; ++jj)
                    sc[rr][jj] += qf[rr].x*kf[jj].x + qf[rr].y*kf[jj].y
                                + qf[rr].z*kf[jj].z + qf[rr].w*kf[jj].w;
        }

        float corr[4];
#pragma unroll
        for (int rr = 0; rr < 4; ++rr) {
            float tm = -1e30f;
#pragma unroll
            for (int jj = 0; jj < 4; ++jj) { sc[rr][jj] *= scale; tm = fmaxf(tm, sc[rr][jj]); }
#pragma unroll
            for (int off = 1; off < 16; off <<= 1) tm = fmaxf(tm, __shfl_xor(tm, off));
            float mn = fmaxf(m_i[rr], tm);
            corr[rr] = expf(m_i[rr] - mn);
            m_i[rr] = mn;
            float ps = 0.f;
#pragma unroll
            for (int jj = 0; jj < 4; ++jj) {
                float p = expf(sc[rr][jj] - mn);
                Ps[tr + 16*rr][tc + 16*jj] = p;
                ps += p;
            }
#pragma unroll
            for (int off = 1; off < 16; off <<= 1) ps += __shfl_xor(ps, off);
            l_i[rr] = l_i[rr]*corr[rr] + ps;
        }
        __syncthreads();

#pragma unroll
        for (int rr = 0; rr < 4; ++rr) {
            float c0 = corr[rr];
            acc[rr][0].x *= c0; acc[rr][0].y *= c0; acc[rr][0].z *= c0; acc[rr][0].w *= c0;
            acc[rr][1].x *= c0; acc[rr][1].y *= c0; acc[rr][1].z *= c0; acc[rr][1].w *= c0;
        }
        for (int j = 0; j < 64; ++j) {
            float4 v0 = *(const float4*)&Vs[j][tc*8];
            float4 v1 = *(const float4*)&Vs[j][tc*8 + 4];
#pragma unroll
            for (int rr = 0; rr < 4; ++rr) {
                float p = Ps[tr + 16*rr][j];
                acc[rr][0].x += p*v0.x; acc[rr][0].y += p*v0.y;
                acc[rr][0].z += p*v0.z; acc[rr][0].w += p*v0.w;
                acc[rr][1].x += p*v1.x; acc[rr][1].y += p*v1.y;
                acc[rr][1].z += p*v1.z; acc[rr][1].w += p*v1.w;
            }
        }
    }

#pragma unroll
    for (int rr = 0; rr < 4; ++rr) {
        float invl = 1.0f / l_i[rr];
        int s = i0 + tr + 16*rr;
        float4 o0 = acc[rr][0], o1 = acc[rr][1];
        o0.x *= invl; o0.y *= invl; o0.z *= invl; o0.w *= invl;
        o1.x *= invl; o1.y *= invl; o1.z *= invl; o1.w *= invl;
        *(float4*)&wvb[(size_t)s*1024 + tc*8]     = o0;
        *(float4*)&wvb[(size_t)s*1024 + tc*8 + 4] = o1;
    }
}

// ---------------------------------------------------------------------------
// Out-projection + residual: x1 = x0 + wv @ Wo^T + bo.
// Tile 64(M) x 128(N), K=1024 chunked by 32. 4x8 micro-tile.
// ---------------------------------------------------------------------------
__global__ __launch_bounds__(256) void outproj_kernel(
    const float* __restrict__ wv, const float* __restrict__ Wo, const float* __restrict__ bo,
    const float* __restrict__ xin, float* __restrict__ xout, int l, int f0)
{
    __shared__ float As[64][36];
    __shared__ float Bs[128][36];
    int fl = blockIdx.z, f = f0 + fl;
    int m0 = blockIdx.x * 64;
    const float* wvb = wv + ((size_t)fl*BS_ + m0)*1024;
    const float* Wob = Wo + (size_t)(l*F_ + f)*128*1024;
    const float* bob = bo + (size_t)(l*F_ + f)*128;
    int t = threadIdx.x, tx = t & 15, ty = t >> 4;
    float acc[4][8] = {};

    for (int k0 = 0; k0 < 1024; k0 += 32) {
        __syncthreads();
#pragma unroll
        for (int p = 0; p < 2; ++p) {
            int idx = t + 256*p; int r = idx >> 3, c4 = idx & 7;
            *(float4*)&As[r][c4*4] = *(const float4*)&wvb[(size_t)r*1024 + k0 + c4*4];
        }
#pragma unroll
        for (int p = 0; p < 4; ++p) {
            int idx = t + 256*p; int r = idx >> 3, c4 = idx & 7;
            *(float4*)&Bs[r][c4*4] = *(const float4*)&Wob[(size_t)r*1024 + k0 + c4*4];
        }
        __syncthreads();
#pragma unroll
        for (int k4 = 0; k4 < 8; ++k4) {
            float4 af[4], bf[8];
#pragma unroll
            for (int i = 0; i < 4; ++i) af[i] = *(const float4*)&As[ty + 16*i][k4*4];
#pragma unroll
            for (int j = 0; j < 8; ++j) bf[j] = *(const float4*)&Bs[tx + 16*j][k4*4];
#pragma unroll
            for (int i = 0; i < 4; ++i)
#pragma unroll
                for (int j = 0; j < 8; ++j)
                    acc[i][j] += af[i].x*bf[j].x + af[i].y*bf[j].y + af[i].z*bf[j].z + af[i].w*bf[j].w;
        }
    }

#pragma unroll
    for (int i = 0; i < 4; ++i) {
        int m = m0 + ty + 16*i;
        const float* xr = xin + ((size_t)f*BS_ + m)*128;
        float* xo = xout + ((size_t)f*BS_ + m)*128;
#pragma unroll
        for (int j = 0; j < 8; ++j) {
            int c = tx + 16*j;
            xo[c] = acc[i][j] + bob[c] + xr[c];
        }
    }
}

// ---------------------------------------------------------------------------
// LayerNorm over last dim (128). One wave per row, 2 elems per lane.
// gstride=128 for per-f params (lnG/lnB already offset to (l,f0)); 0 for fnG/fnB.
// ---------------------------------------------------------------------------
__global__ __launch_bounds__(256) void ln_kernel(
    const float* __restrict__ xin, float* __restrict__ xout,
    const float* __restrict__ g, const float* __restrict__ bb, int f0, int gstride)
{
    int t = threadIdx.x, lane = t & 63, w = t >> 6;
    int rowl = blockIdx.x * 4 + w;
    int fl = rowl >> 12;
    size_t row = (size_t)f0*BS_ + rowl;
    const float* xi = xin + row*128;
    float a = xi[lane], c = xi[64 + lane];
    float s = a + c;
#pragma unroll
    for (int off = 1; off < 64; off <<= 1) s += __shfl_xor(s, off);
    float mean = s * (1.0f/128.0f);
    float da = a - mean, dc = c - mean;
    float vs = da*da + dc*dc;
#pragma unroll
    for (int off = 1; off < 64; off <<= 1) vs += __shfl_xor(vs, off);
    float inv = rsqrtf(vs * (1.0f/128.0f) + 1e-5f);
    const float* gp = g + (size_t)fl*gstride;
    const float* bp = bb + (size_t)fl*gstride;
    float* xo = xout + row*128;
    xo[lane]      = da*inv*gp[lane]      + bp[lane];
    xo[64 + lane] = dc*inv*gp[64 + lane] + bp[64 + lane];
}

// ---------------------------------------------------------------------------
// Softmax-pool over S: U[b][d][f] = sum_s softmax_s(x_s . poolW) * x_s[d].
// One block per (f, b).
// ---------------------------------------------------------------------------
__global__ __launch_bounds__(256) void pool_kernel(
    const float* __restrict__ xB, const float* __restrict__ poolW,
    float* __restrict__ U, int f0)
{
    int f = f0 + blockIdx.x, b = blockIdx.y;
    const float* xb = xB + ((size_t)f*BS_ + (size_t)b*S_)*128;
    const float* pw = poolW + f*128;
    __shared__ float sc[512];
    __shared__ float red[8];
    __shared__ float MS[2];
    __shared__ float pool2[256];
    int t = threadIdx.x, lane = t & 63, w = t >> 6;

    float p0 = pw[lane], p1 = pw[64 + lane];
    for (int s = w; s < 512; s += 4) {
        float a = xb[(size_t)s*128 + lane]*p0 + xb[(size_t)s*128 + 64 + lane]*p1;
#pragma unroll
        for (int off = 1; off < 64; off <<= 1) a += __shfl_xor(a, off);
        if (lane == 0) sc[s] = a;
    }
    __syncthreads();

    float m = -1e30f;
    for (int s = t; s < 512; s += 256) m = fmaxf(m, sc[s]);
#pragma unroll
    for (int off = 1; off < 64; off <<= 1) m = fmaxf(m, __shfl_xor(m, off));
    if (lane == 0) red[w] = m;
    __syncthreads();
    if (t == 0) MS[0] = fmaxf(fmaxf(red[0], red[1]), fmaxf(red[2], red[3]));
    __syncthreads();
    float M = MS[0];

    float ssum = 0.f;
    for (int s = t; s < 512; s += 256) { float e = expf(sc[s] - M); sc[s] = e; ssum += e; }
#pragma unroll
    for (int off = 1; off < 64; off <<= 1) ssum += __shfl_xor(ssum, off);
    if (lane == 0) red[4 + w] = ssum;
    __syncthreads();
    if (t == 0) MS[1] = red[4] + red[5] + red[6] + red[7];
    __syncthreads();
    float inv = 1.0f / MS[1];

    int d = t & 127, hh = t >> 7;
    float a = 0.f;
    for (int s = hh*256; s < hh*256 + 256; ++s) a += sc[s]*xb[(size_t)s*128 + d];
    pool2[t] = a;
    __syncthreads();
    if (t < 128) U[((size_t)b*128 + d)*F_ + f] = (pool2[t] + pool2[t + 128]) * inv;
}

// ---------------------------------------------------------------------------
// Unified attention per (f,b). Uses algebraic reductions:
//   QK^T = U M U^T (+bias terms), (A@V).mean(-1) = A @ rowmean(V).
// ---------------------------------------------------------------------------
__global__ __launch_bounds__(256) void unified_kernel(
    const float* __restrict__ U,
    const float* __restrict__ uQW, const float* __restrict__ uQB,
    const float* __restrict__ uKW, const float* __restrict__ uKB,
    const float* __restrict__ uVW, const float* __restrict__ uVB,
    float* __restrict__ outp)
{
    int f = blockIdx.x, b = blockIdx.y;
    __shared__ float Ub[128*9];
    __shared__ float Wj[128*9];
    __shared__ float zj[128];
    __shared__ float vm[128];
    __shared__ float Mm[81];
    __shared__ float wvm[9], bvec[9];
    __shared__ float cc_[2];
    int t = threadIdx.x;
    for (int i = t; i < 1152; i += 256) Ub[i] = U[(size_t)b*1152 + i];
    const float* qw = uQW + (size_t)f*1152;   // [k][t] 128x9
    const float* kw = uKW + (size_t)f*1152;
    const float* vw = uVW + (size_t)f*1152;
    const float* qb = uQB + (size_t)f*128;
    const float* kb = uKB + (size_t)f*128;
    const float* vb = uVB + (size_t)f*128;

    if (t < 81) {
        int t1 = t/9, s1 = t%9; float a = 0.f;
        for (int kk = 0; kk < 128; ++kk) a += qw[kk*9 + t1]*kw[kk*9 + s1];
        Mm[t] = a;
    } else if (t < 90) {
        int s1 = t - 81; float a = 0.f;
        for (int kk = 0; kk < 128; ++kk) a += kw[kk*9 + s1]*qb[kk];
        bvec[s1] = a;
    } else if (t < 99) {
        int t1 = t - 90; float a = 0.f;
        for (int kk = 0; kk < 128; ++kk) a += vw[kk*9 + t1];
        wvm[t1] = a * (1.0f/128.0f);
    } else if (t == 99) {
        float a = 0.f, c2 = 0.f;
        for (int kk = 0; kk < 128; ++kk) { a += qb[kk]*kb[kk]; c2 += vb[kk]; }
        cc_[0] = a; cc_[1] = c2 * (1.0f/128.0f);
    }
    __syncthreads();

    if (t < 128) {
        int j = t;
        for (int t1 = 0; t1 < 9; ++t1) {
            float a = 0.f;
            for (int s1 = 0; s1 < 9; ++s1) a += Mm[t1*9 + s1]*Ub[j*9 + s1];
            Wj[j*9 + t1] = a;
        }
        float z = cc_[0], v2 = cc_[1];
        for (int s1 = 0; s1 < 9; ++s1) { z += bvec[s1]*Ub[j*9 + s1]; v2 += wvm[s1]*Ub[j*9 + s1]; }
        zj[j] = z; vm[j] = v2;
    }
    __syncthreads();

    int i = t >> 1, half = t & 1;
    float ui[9];
#pragma unroll
    for (int s1 = 0; s1 < 9; ++s1) ui[s1] = Ub[i*9 + s1];

    float mx = -1e30f;
    for (int jj = 0; jj < 64; ++jj) {
        int j = half*64 + jj;
        float a = zj[j];
#pragma unroll
        for (int s1 = 0; s1 < 9; ++s1) a += ui[s1]*Wj[j*9 + s1];
        mx = fmaxf(mx, a * (1.0f/3.0f));
    }
    mx = fmaxf(mx, __shfl_xor(mx, 1));
    float sum = 0.f, o = 0.f;
    for (int jj = 0; jj < 64; ++jj) {
        int j = half*64 + jj;
        float a = zj[j];
#pragma unroll
        for (int s1 = 0; s1 < 9; ++s1) a += ui[s1]*Wj[j*9 + s1];
        float p = expf(a * (1.0f/3.0f) - mx);
        sum += p; o += p*vm[j];
    }
    sum += __shfl_xor(sum, 1);
    o   += __shfl_xor(o, 1);
    if (half == 0) {
        float base;
        if (f > 0) base = ui[f];
        else { base = 0.f; for (int s1 = 0; s1 < 9; ++s1) base += ui[s1]; base *= (1.0f/9.0f); }
        outp[((size_t)b*128 + i)*10 + f] = o/sum + base;
    }
}

// ---------------------------------------------------------------------------
// Merge attention (features 3..8), writes output column 9.
// ---------------------------------------------------------------------------
__global__ __launch_bounds__(256) void merge_kernel(
    const float* __restrict__ U,
    const float* __restrict__ mQW, const float* __restrict__ mQB,
    const float* __restrict__ mKW, const float* __restrict__ mKB,
    const float* __restrict__ mVW, const float* __restrict__ mVB,
    float* __restrict__ outp)
{
    int b = blockIdx.x;
    __shared__ float Us[128*6];
    __shared__ float Wj[128*6];
    __shared__ float zj[128];
    __shared__ float vm[128];
    __shared__ float Mm[36];
    __shared__ float wvm[6], bvec[6];
    __shared__ float cc_[2];
    int t = threadIdx.x;
    for (int i = t; i < 768; i += 256) {
        int j = i/6, tt = i - j*6;
        Us[i] = U[(size_t)b*1152 + j*9 + 3 + tt];
    }
    if (t < 36) {
        int t1 = t/6, s1 = t%6; float a = 0.f;
        for (int kk = 0; kk < 128; ++kk) a += mQW[kk*6 + t1]*mKW[kk*6 + s1];
        Mm[t] = a;
    } else if (t < 42) {
        int s1 = t - 36; float a = 0.f;
        for (int kk = 0; kk < 128; ++kk) a += mKW[kk*6 + s1]*mQB[kk];
        bvec[s1] = a;
    } else if (t < 48) {
        int t1 = t - 42; float a = 0.f;
        for (int kk = 0; kk < 128; ++kk) a += mVW[kk*6 + t1];
        wvm[t1] = a * (1.0f/128.0f);
    } else if (t == 48) {
        float a = 0.f, c2 = 0.f;
        for (int kk = 0; kk < 128; ++kk) { a += mQB[kk]*mKB[kk]; c2 += mVB[kk]; }
        cc_[0] = a; cc_[1] = c2 * (1.0f/128.0f);
    }
    __syncthreads();

    if (t < 128) {
        int j = t;
        for (int t1 = 0; t1 < 6; ++t1) {
            float a = 0.f;
            for (int s1 = 0; s1 < 6; ++s1) a += Mm[t1*6 + s1]*Us[j*6 + s1];
            Wj[j*6 + t1] = a;
        }
        float z = cc_[0], v2 = cc_[1];
        for (int s1 = 0; s1 < 6; ++s1) { z += bvec[s1]*Us[j*6 + s1]; v2 += wvm[s1]*Us[j*6 + s1]; }
        zj[j] = z; vm[j] = v2;
    }
    __syncthreads();

    int i = t >> 1, half = t & 1;
    float ui[6];
#pragma unroll
    for (int s1 = 0; s1 < 6; ++s1) ui[s1] = Us[i*6 + s1];

    float mx = -1e30f;
    for (int jj = 0; jj < 64; ++jj) {
        int j = half*64 + jj;
        float a = zj[j];
#pragma unroll
        for (int s1 = 0; s1 < 6; ++s1) a += ui[s1]*Wj[j*6 + s1];
        mx = fmaxf(mx, a * (1.0f/3.0f));
    }
    mx = fmaxf(mx, __shfl_xor(mx, 1));
    float sum = 0.f, o = 0.f;
    for (int jj = 0; jj < 64; ++jj) {
        int j = half*64 + jj;
        float a = zj[j];
#pragma unroll
        for (int s1 = 0; s1 < 6; ++s1) a += ui[s1]*Wj[j*6 + s1];
        float p = expf(a * (1.0f/3.0f) - mx);
        sum += p; o += p*vm[j];
    }
    sum += __shfl_xor(sum, 1);
    o   += __shfl_xor(o, 1);
    if (half == 0) {
        float base = 0.f;
        for (int s1 = 0; s1 < 6; ++s1) base += ui[s1];
        base *= (1.0f/6.0f);
        outp[((size_t)b*128 + i)*10 + 9] = o/sum + base;
    }
}

// ---------------------------------------------------------------------------
extern "C" void kernel_launch(void* const* d_in, const int* in_sizes, int n_in,
                              void* d_out, int out_size, void* d_ws, size_t ws_size,
                              hipStream_t stream)
{
    const float* Y     = (const float*)d_in[0];
    const float* Gin   = (const float*)d_in[1];
    const float* posW1 = (const float*)d_in[2];
    const float* posB1 = (const float*)d_in[3];
    const float* posW2 = (const float*)d_in[4];
    const float* posB2 = (const float*)d_in[5];
    const float* posW3 = (const float*)d_in[6];
    const float* posB3 = (const float*)d_in[7];
    const float* Wq    = (const float*)d_in[8];
    const float* bq    = (const float*)d_in[9];
    const float* Wk    = (const float*)d_in[10];
    const float* bk    = (const float*)d_in[11];
    const float* Wv    = (const float*)d_in[12];
    const float* bv    = (const float*)d_in[13];
    const float* Wo    = (const float*)d_in[14];
    const float* bo    = (const float*)d_in[15];
    const float* lnG   = (const float*)d_in[16];
    const float* lnB   = (const float*)d_in[17];
    const float* fnG   = (const float*)d_in[18];
    const float* fnB   = (const float*)d_in[19];
    const float* poolW = (const float*)d_in[20];
    const float* uQW   = (const float*)d_in[21];
    const float* uQB   = (const float*)d_in[22];
    const float* uKW   = (const float*)d_in[23];
    const float* uKB   = (const float*)d_in[24];
    const float* uVW   = (const float*)d_in[25];
    const float* uVB   = (const float*)d_in[26];
    const float* mQW   = (const float*)d_in[27];
    const float* mQB   = (const float*)d_in[28];
    const float* mKW   = (const float*)d_in[29];
    const float* mKB   = (const float*)d_in[30];
    const float* mVW   = (const float*)d_in[31];
    const float* mVB   = (const float*)d_in[32];

    float* ws = (float*)d_ws;
    const size_t xelems = (size_t)F_ * BS_ * 128;     // 4,718,592 floats
    float* xA   = ws;
    float* xB   = xA + xelems;
    float* Ubuf = xB + xelems;                        // 9216 floats used
    size_t qoff = 2*xelems + 16384;                   // padded past U
    size_t avail = (ws_size/4 > qoff) ? (ws_size/4 - qoff) : 0;
    int FC = (int)(avail / (4*PERBUF));               // features in flight
    if (FC < 1) FC = 1;
    if (FC > F_) FC = F_;
    float* qb  = ws + qoff;
    float* kb  = qb + (size_t)FC*PERBUF;
    float* vb  = kb + (size_t)FC*PERBUF;
    float* wvb = vb + (size_t)FC*PERBUF;

    posnet_kernel<<<dim3(1024, 1, F_), 256, 0, stream>>>(
        Y, Gin, posW1, posB1, posW2, posB2, posW3, posB3, xA);

    for (int l = 0; l < 2; ++l) {
        for (int f0 = 0; f0 < F_; f0 += FC) {
            int fc = (F_ - f0) < FC ? (F_ - f0) : FC;
            qkv_kernel<<<dim3(32, 16, 3*fc), 256, 0, stream>>>(
                xA, Wq, Wk, Wv, bq, bk, bv, qb, kb, vb, l, f0);
            attn_kernel<<<dim3(8, 64, fc), 256, 0, stream>>>(qb, kb, vb, wvb);
            outproj_kernel<<<dim3(64, 1, fc), 256, 0, stream>>>(
                wvb, Wo, bo, xA, xB, l, f0);
            ln_kernel<<<dim3(fc*1024), 256, 0, stream>>>(
                xB, xA, lnG + (size_t)(l*F_ + f0)*128, lnB + (size_t)(l*F_ + f0)*128, f0, 128);
        }
    }

    for (int f0 = 0; f0 < F_; f0 += FC) {
        int fc = (F_ - f0) < FC ? (F_ - f0) : FC;
        ln_kernel<<<dim3(fc*1024), 256, 0, stream>>>(xA, xB, fnG, fnB, f0, 0);
        pool_kernel<<<dim3(fc, 8), 256, 0, stream>>>(xB, poolW, Ubuf, f0);
    }

    unified_kernel<<<dim3(F_, B_), 256, 0, stream>>>(
        Ubuf, uQW, uQB, uKW, uKB, uVW, uVB, (float*)d_out);
    merge_kernel<<<dim3(B_), 256, 0, stream>>>(
        Ubuf, mQW, mQB, mKW, mKB, mVW, mVB, (float*)d_out);
}

// Round 2
// 3965.381 us; speedup vs baseline: 1.5527x; 1.5527x over previous
//
#include <hip/hip_runtime.h>
#include <hip/hip_bf16.h>

// Problem constants
#define F_  9
#define B_  8
#define S_  512
#define H_  8
#define DH_ 128
#define D_  128
#define NB_ 50
#define BS_ 4096            // B_*S_ rows per feature
#define PERBUF 4194304UL    // B_*H_*S_*DH_ elements per feature for q/k/v/wv

typedef short bf16x8 __attribute__((ext_vector_type(8)));
typedef float f32x4  __attribute__((ext_vector_type(4)));

static __device__ __forceinline__ unsigned short f2b(float f) {
    unsigned int u = __float_as_uint(f);
    unsigned int r = (u + 0x7FFFu + ((u >> 16) & 1u)) >> 16;
    return (unsigned short)r;
}
static __device__ __forceinline__ float b2f(unsigned short u) {
    return __uint_as_float(((unsigned int)u) << 16);
}

// ---------------------------------------------------------------------------
// Pos-net (unchanged): one wave per row, activations one-per-lane via shfl.
// ---------------------------------------------------------------------------
__global__ __launch_bounds__(256) void posnet_kernel(
    const float* __restrict__ Y, const float* __restrict__ Gin,
    const float* __restrict__ W1g, const float* __restrict__ B1,
    const float* __restrict__ W2g, const float* __restrict__ B2,
    const float* __restrict__ W3g, const float* __restrict__ B3,
    float* __restrict__ xA)
{
    __shared__ float w1[50*51];
    __shared__ float w2[50*50];
    __shared__ float w3[128*50];
    __shared__ float b1[64], b2[64], b3[128];
    int f = blockIdx.z;
    int t = threadIdx.x;
    for (int i = t; i < 2550; i += 256) w1[i] = W1g[f*2550 + i];
    for (int i = t; i < 2500; i += 256) w2[i] = W2g[f*2500 + i];
    for (int i = t; i < 6400; i += 256) w3[i] = W3g[f*6400 + i];
    if (t < 50) { b1[t] = B1[f*50 + t]; b2[t] = B2[f*50 + t]; }
    if (t < 128) b3[t] = B3[f*128 + t];
    __syncthreads();

    int lane = t & 63, w = t >> 6;
    int row = blockIdx.x * 4 + w;   // 0..4095

    float gy = 0.f;
    if (lane < 50)       gy = Y[(size_t)row*50 + lane];
    else if (lane == 50) gy = Gin[(size_t)row*F_ + f];

    float a1 = (lane < 50) ? b1[lane] : 0.f;
    for (int kk = 0; kk < 51; ++kk) {
        float g = __shfl(gy, kk);
        if (lane < 50) a1 += w1[lane*51 + kk] * g;
    }
    float h1 = tanhf(a1);

    float a2 = (lane < 50) ? b2[lane] : 0.f;
    for (int kk = 0; kk < 50; ++kk) {
        float hh = __shfl(h1, kk);
        if (lane < 50) a2 += w2[lane*50 + kk] * hh;
    }
    float h2 = tanhf(a2);

    float a30 = b3[lane], a31 = b3[64 + lane];
    for (int kk = 0; kk < 50; ++kk) {
        float hh = __shfl(h2, kk);
        a30 += w3[lane*50 + kk] * hh;
        a31 += w3[(64 + lane)*50 + kk] * hh;
    }
    float* out = xA + ((size_t)f*BS_ + row)*128;
    out[lane]      = 1.f / (1.f + expf(-a30));
    out[64 + lane] = 1.f / (1.f + expf(-a31));
}

// ---------------------------------------------------------------------------
// QKV projection GEMM (fp32 compute, bf16 outputs): C[4096x1024] = X * W^T.
// Tile 128(M) x 64(N), full K=128 in LDS. 8x4 micro-tile.
// Output layout q/k/v[fl][b][h][s][dh] bf16 row-major.
// ---------------------------------------------------------------------------
__global__ __launch_bounds__(256) void qkv_kernel(
    const float* __restrict__ xA,
    const float* __restrict__ Wq, const float* __restrict__ Wk, const float* __restrict__ Wv,
    const float* __restrict__ bq, const float* __restrict__ bk, const float* __restrict__ bv,
    unsigned short* __restrict__ qo, unsigned short* __restrict__ ko, unsigned short* __restrict__ vo,
    int l, int f0)
{
    __shared__ float Xs[128][132];
    __shared__ float Ws[64][132];
    int z = blockIdx.z;
    int fl = z / 3, which = z - fl*3;
    int f = f0 + fl;
    const float* W; const float* bias; unsigned short* out;
    if (which == 0)      { W = Wq; bias = bq; out = qo; }
    else if (which == 1) { W = Wk; bias = bk; out = ko; }
    else                 { W = Wv; bias = bv; out = vo; }
    W    += (size_t)(l*F_ + f) * 1024 * 128;
    bias += (size_t)(l*F_ + f) * 1024;
    out  += (size_t)fl * PERBUF;

    int m0 = blockIdx.x * 128;
    int n0 = blockIdx.y * 64;
    const float* Xg = xA + ((size_t)f*BS_ + m0)*128;
    int t = threadIdx.x;

#pragma unroll
    for (int p = 0; p < 16; ++p) {
        int idx = t + 256*p; int r = idx >> 5, c4 = idx & 31;
        *(float4*)&Xs[r][c4*4] = *(const float4*)&Xg[(size_t)r*128 + c4*4];
    }
#pragma unroll
    for (int p = 0; p < 8; ++p) {
        int idx = t + 256*p; int r = idx >> 5, c4 = idx & 31;
        *(float4*)&Ws[r][c4*4] = *(const float4*)&W[(size_t)(n0 + r)*128 + c4*4];
    }
    __syncthreads();

    int tx = t & 15, ty = t >> 4;
    float acc[8][4] = {};
    for (int kk = 0; kk < 128; kk += 4) {
        float4 xf[8], wf[4];
#pragma unroll
        for (int i = 0; i < 8; ++i) xf[i] = *(const float4*)&Xs[ty + 16*i][kk];
#pragma unroll
        for (int j = 0; j < 4; ++j) wf[j] = *(const float4*)&Ws[tx + 16*j][kk];
#pragma unroll
        for (int i = 0; i < 8; ++i)
#pragma unroll
            for (int j = 0; j < 4; ++j)
                acc[i][j] += xf[i].x*wf[j].x + xf[i].y*wf[j].y + xf[i].z*wf[j].z + xf[i].w*wf[j].w;
    }

    int h = n0 >> 7;
#pragma unroll
    for (int i = 0; i < 8; ++i) {
        int m = m0 + ty + 16*i;
        int b = m >> 9, s = m & 511;
        unsigned short* orow = out + (((size_t)(b*H_ + h))*S_ + s)*128;
#pragma unroll
        for (int j = 0; j < 4; ++j) {
            int n = n0 + tx + 16*j;
            orow[n & 127] = f2b(acc[i][j] + bias[n]);
        }
    }
}

// ---------------------------------------------------------------------------
// V transpose-pack: v[bh][s][d] bf16 -> Vt[bh][d][s/2] u32 (lo=even s, hi=odd s).
// Tile: 64 s x 128 d per block.
// ---------------------------------------------------------------------------
__global__ __launch_bounds__(256) void vtrans_kernel(
    const unsigned short* __restrict__ v, unsigned int* __restrict__ vt)
{
    __shared__ alignas(16) unsigned short L[64][136];
    int t = threadIdx.x;
    int fl = blockIdx.z, by = blockIdx.y, s0 = blockIdx.x * 64;
    const unsigned short* vh = v + ((size_t)(fl*64 + by))*S_*128;
    unsigned int* vth = vt + ((size_t)(fl*64 + by))*32768;

#pragma unroll
    for (int p = 0; p < 4; ++p) {
        int r = p*16 + (t >> 4), c8 = t & 15;
        *(uint4*)&L[r][c8*8] = *(const uint4*)&vh[(size_t)(s0 + r)*128 + c8*8];
    }
    __syncthreads();

    int d = t >> 1, half = t & 1;
    unsigned int o[16];
#pragma unroll
    for (int kk = 0; kk < 16; ++kk) {
        int sp = half*16 + kk;
        o[kk] = (unsigned int)L[2*sp][d] | ((unsigned int)L[2*sp + 1][d] << 16);
    }
    unsigned int* og = vth + (size_t)d*256 + (s0 >> 1) + half*16;
#pragma unroll
    for (int qq = 0; qq < 4; ++qq)
        *(uint4*)&og[qq*4] = *(uint4*)&o[qq*4];
}

// ---------------------------------------------------------------------------
// MFMA flash attention. Block 256 = 4 waves; each wave owns 16 q-rows.
// KV tiles of 32. Fragments read directly from global (L2-resident).
// P-transpose via per-wave LDS bounce (no barriers in the loop).
// Layouts (mfma_f32_16x16x32_bf16):
//   A-frag: lane l -> A[m=l&15][k=8*(l>>4)+j]
//   B-frag: lane l -> B[k=8*(l>>4)+j][n=l&15]
//   D:      lane l, reg r -> D[m=4*(l>>4)+r][n=l&15]
// ---------------------------------------------------------------------------
__global__ __launch_bounds__(256) void attn_mfma_kernel(
    const unsigned short* __restrict__ q, const unsigned short* __restrict__ k,
    const unsigned int* __restrict__ vt, unsigned short* __restrict__ wv)
{
    int t = threadIdx.x;
    int w = t >> 6, l = t & 63, g = l >> 4, c = l & 15;
    int fl = blockIdx.z, by = blockIdx.y;
    int i0 = blockIdx.x * 64;
    int q0 = i0 + w*16;
    const unsigned short* qh = q + ((size_t)(fl*64 + by))*S_*128;
    const unsigned short* kh = k + ((size_t)(fl*64 + by))*S_*128;
    const unsigned int*  vth = vt + ((size_t)(fl*64 + by))*32768;
    int b = by >> 3, h = by & 7;
    unsigned short* wvh = wv + ((size_t)(fl*B_ + b))*S_*1024 + h*128;

    __shared__ alignas(16) unsigned short Pl[4][16][40];   // per-wave, pitch 80 B

    bf16x8 qf[4];
#pragma unroll
    for (int d0 = 0; d0 < 4; ++d0)
        qf[d0] = *(const bf16x8*)&qh[(size_t)(q0 + c)*128 + d0*32 + g*8];

    f32x4 acc[8];
#pragma unroll
    for (int i = 0; i < 8; ++i) acc[i] = (f32x4){0.f, 0.f, 0.f, 0.f};
    float mrow[4] = {-1e30f, -1e30f, -1e30f, -1e30f};
    float lrow[4] = {0.f, 0.f, 0.f, 0.f};
    const float scale = 0.08838834764831845f;   // 1/sqrt(128)

    for (int kt = 0; kt < 16; ++kt) {
        f32x4 s0 = (f32x4){0.f,0.f,0.f,0.f}, s1 = (f32x4){0.f,0.f,0.f,0.f};
        const unsigned short* kp = &kh[(size_t)(kt*32 + c)*128 + g*8];
#pragma unroll
        for (int d0 = 0; d0 < 4; ++d0) {
            bf16x8 k0 = *(const bf16x8*)(kp + d0*32);
            bf16x8 k1 = *(const bf16x8*)(kp + 16*128 + d0*32);
            s0 = __builtin_amdgcn_mfma_f32_16x16x32_bf16(qf[d0], k0, s0, 0, 0, 0);
            s1 = __builtin_amdgcn_mfma_f32_16x16x32_bf16(qf[d0], k1, s1, 0, 0, 0);
        }

        float corr[4];
#pragma unroll
        for (int r = 0; r < 4; ++r) {
            float a0 = s0[r]*scale, a1 = s1[r]*scale;
            float tm = fmaxf(a0, a1);
            tm = fmaxf(tm, __shfl_xor(tm, 1));
            tm = fmaxf(tm, __shfl_xor(tm, 2));
            tm = fmaxf(tm, __shfl_xor(tm, 4));
            tm = fmaxf(tm, __shfl_xor(tm, 8));
            float mn = fmaxf(mrow[r], tm);
            corr[r] = __expf(mrow[r] - mn);
            mrow[r] = mn;
            float p0 = __expf(a0 - mn), p1 = __expf(a1 - mn);
            float ps = p0 + p1;
            ps += __shfl_xor(ps, 1);
            ps += __shfl_xor(ps, 2);
            ps += __shfl_xor(ps, 4);
            ps += __shfl_xor(ps, 8);
            lrow[r] = lrow[r]*corr[r] + ps;
            Pl[w][4*g + r][c]      = f2b(p0);
            Pl[w][4*g + r][16 + c] = f2b(p1);
        }
#pragma unroll
        for (int i = 0; i < 8; ++i) {
            f32x4 a = acc[i];
            a[0] *= corr[0]; a[1] *= corr[1]; a[2] *= corr[2]; a[3] *= corr[3];
            acc[i] = a;
        }

        // PV: A = P[16 q-rows x 32 kj] (per-wave LDS, DS in-order within wave)
        bf16x8 pa = *(const bf16x8*)&Pl[w][c][g*8];
        const unsigned int* vp = vth + kt*16 + 4*g;
#pragma unroll
        for (int i = 0; i < 8; ++i) {
            bf16x8 vf = *(const bf16x8*)&vp[(size_t)(i*16 + c)*256];
            acc[i] = __builtin_amdgcn_mfma_f32_16x16x32_bf16(pa, vf, acc[i], 0, 0, 0);
        }
    }

    float inv[4];
#pragma unroll
    for (int r = 0; r < 4; ++r) inv[r] = 1.0f / lrow[r];
#pragma unroll
    for (int i = 0; i < 8; ++i)
#pragma unroll
        for (int r = 0; r < 4; ++r)
            wvh[(size_t)(q0 + 4*g + r)*1024 + i*16 + c] = f2b(acc[i][r]*inv[r]);
}

// ---------------------------------------------------------------------------
// Out-projection + residual: x1 = x0 + wv @ Wo^T + bo.  wv is bf16 now.
// Tile 64(M) x 128(N), K=1024 chunked by 32. 4x8 micro-tile.
// ---------------------------------------------------------------------------
__global__ __launch_bounds__(256) void outproj_kernel(
    const unsigned short* __restrict__ wv, const float* __restrict__ Wo, const float* __restrict__ bo,
    const float* __restrict__ xin, float* __restrict__ xout, int l, int f0)
{
    __shared__ float As[64][36];
    __shared__ float Bs[128][36];
    int fl = blockIdx.z, f = f0 + fl;
    int m0 = blockIdx.x * 64;
    const unsigned short* wvb = wv + ((size_t)fl*BS_ + m0)*1024;
    const float* Wob = Wo + (size_t)(l*F_ + f)*128*1024;
    const float* bob = bo + (size_t)(l*F_ + f)*128;
    int t = threadIdx.x, tx = t & 15, ty = t >> 4;
    float acc[4][8] = {};

    for (int k0 = 0; k0 < 1024; k0 += 32) {
        __syncthreads();
#pragma unroll
        for (int p = 0; p < 2; ++p) {
            int idx = t + 256*p; int r = idx >> 3, c4 = idx & 7;
            ushort4 v4 = *(const ushort4*)&wvb[(size_t)r*1024 + k0 + c4*4];
            As[r][c4*4+0] = b2f(v4.x);
            As[r][c4*4+1] = b2f(v4.y);
            As[r][c4*4+2] = b2f(v4.z);
            As[r][c4*4+3] = b2f(v4.w);
        }
#pragma unroll
        for (int p = 0; p < 4; ++p) {
            int idx = t + 256*p; int r = idx >> 3, c4 = idx & 7;
            *(float4*)&Bs[r][c4*4] = *(const float4*)&Wob[(size_t)r*1024 + k0 + c4*4];
        }
        __syncthreads();
#pragma unroll
        for (int k4 = 0; k4 < 8; ++k4) {
            float4 af[4], bf[8];
#pragma unroll
            for (int i = 0; i < 4; ++i) af[i] = *(const float4*)&As[ty + 16*i][k4*4];
#pragma unroll
            for (int j = 0; j < 8; ++j) bf[j] = *(const float4*)&Bs[tx + 16*j][k4*4];
#pragma unroll
            for (int i = 0; i < 4; ++i)
#pragma unroll
                for (int j = 0; j < 8; ++j)
                    acc[i][j] += af[i].x*bf[j].x + af[i].y*bf[j].y + af[i].z*bf[j].z + af[i].w*bf[j].w;
        }
    }

#pragma unroll
    for (int i = 0; i < 4; ++i) {
        int m = m0 + ty + 16*i;
        const float* xr = xin + ((size_t)f*BS_ + m)*128;
        float* xo = xout + ((size_t)f*BS_ + m)*128;
#pragma unroll
        for (int j = 0; j < 8; ++j) {
            int ccol = tx + 16*j;
            xo[ccol] = acc[i][j] + bob[ccol] + xr[ccol];
        }
    }
}

// ---------------------------------------------------------------------------
// LayerNorm over last dim (128). One wave per row, 2 elems per lane.
// ---------------------------------------------------------------------------
__global__ __launch_bounds__(256) void ln_kernel(
    const float* __restrict__ xin, float* __restrict__ xout,
    const float* __restrict__ g, const float* __restrict__ bb, int f0, int gstride)
{
    int t = threadIdx.x, lane = t & 63, w = t >> 6;
    int rowl = blockIdx.x * 4 + w;
    int fl = rowl >> 12;
    size_t row = (size_t)f0*BS_ + rowl;
    const float* xi = xin + row*128;
    float a = xi[lane], c = xi[64 + lane];
    float s = a + c;
#pragma unroll
    for (int off = 1; off < 64; off <<= 1) s += __shfl_xor(s, off);
    float mean = s * (1.0f/128.0f);
    float da = a - mean, dc = c - mean;
    float vs = da*da + dc*dc;
#pragma unroll
    for (int off = 1; off < 64; off <<= 1) vs += __shfl_xor(vs, off);
    float inv = rsqrtf(vs * (1.0f/128.0f) + 1e-5f);
    const float* gp = g + (size_t)fl*gstride;
    const float* bp = bb + (size_t)fl*gstride;
    float* xo = xout + row*128;
    xo[lane]      = da*inv*gp[lane]      + bp[lane];
    xo[64 + lane] = dc*inv*gp[64 + lane] + bp[64 + lane];
}

// ---------------------------------------------------------------------------
// Softmax-pool over S (unchanged).
// ---------------------------------------------------------------------------
__global__ __launch_bounds__(256) void pool_kernel(
    const float* __restrict__ xB, const float* __restrict__ poolW,
    float* __restrict__ U, int f0)
{
    int f = f0 + blockIdx.x, b = blockIdx.y;
    const float* xb = xB + ((size_t)f*BS_ + (size_t)b*S_)*128;
    const float* pw = poolW + f*128;
    __shared__ float sc[512];
    __shared__ float red[8];
    __shared__ float MS[2];
    __shared__ float pool2[256];
    int t = threadIdx.x, lane = t & 63, w = t >> 6;

    float p0 = pw[lane], p1 = pw[64 + lane];
    for (int s = w; s < 512; s += 4) {
        float a = xb[(size_t)s*128 + lane]*p0 + xb[(size_t)s*128 + 64 + lane]*p1;
#pragma unroll
        for (int off = 1; off < 64; off <<= 1) a += __shfl_xor(a, off);
        if (lane == 0) sc[s] = a;
    }
    __syncthreads();

    float m = -1e30f;
    for (int s = t; s < 512; s += 256) m = fmaxf(m, sc[s]);
#pragma unroll
    for (int off = 1; off < 64; off <<= 1) m = fmaxf(m, __shfl_xor(m, off));
    if (lane == 0) red[w] = m;
    __syncthreads();
    if (t == 0) MS[0] = fmaxf(fmaxf(red[0], red[1]), fmaxf(red[2], red[3]));
    __syncthreads();
    float M = MS[0];

    float ssum = 0.f;
    for (int s = t; s < 512; s += 256) { float e = expf(sc[s] - M); sc[s] = e; ssum += e; }
#pragma unroll
    for (int off = 1; off < 64; off <<= 1) ssum += __shfl_xor(ssum, off);
    if (lane == 0) red[4 + w] = ssum;
    __syncthreads();
    if (t == 0) MS[1] = red[4] + red[5] + red[6] + red[7];
    __syncthreads();
    float inv = 1.0f / MS[1];

    int d = t & 127, hh = t >> 7;
    float a = 0.f;
    for (int s = hh*256; s < hh*256 + 256; ++s) a += sc[s]*xb[(size_t)s*128 + d];
    pool2[t] = a;
    __syncthreads();
    if (t < 128) U[((size_t)b*128 + d)*F_ + f] = (pool2[t] + pool2[t + 128]) * inv;
}

// ---------------------------------------------------------------------------
// Unified attention per (f,b) (unchanged).
// ---------------------------------------------------------------------------
__global__ __launch_bounds__(256) void unified_kernel(
    const float* __restrict__ U,
    const float* __restrict__ uQW, const float* __restrict__ uQB,
    const float* __restrict__ uKW, const float* __restrict__ uKB,
    const float* __restrict__ uVW, const float* __restrict__ uVB,
    float* __restrict__ outp)
{
    int f = blockIdx.x, b = blockIdx.y;
    __shared__ float Ub[128*9];
    __shared__ float Wj[128*9];
    __shared__ float zj[128];
    __shared__ float vm[128];
    __shared__ float Mm[81];
    __shared__ float wvm[9], bvec[9];
    __shared__ float cc_[2];
    int t = threadIdx.x;
    for (int i = t; i < 1152; i += 256) Ub[i] = U[(size_t)b*1152 + i];
    const float* qw = uQW + (size_t)f*1152;
    const float* kw = uKW + (size_t)f*1152;
    const float* vw = uVW + (size_t)f*1152;
    const float* qb = uQB + (size_t)f*128;
    const float* kb = uKB + (size_t)f*128;
    const float* vb = uVB + (size_t)f*128;

    if (t < 81) {
        int t1 = t/9, s1 = t%9; float a = 0.f;
        for (int kk = 0; kk < 128; ++kk) a += qw[kk*9 + t1]*kw[kk*9 + s1];
        Mm[t] = a;
    } else if (t < 90) {
        int s1 = t - 81; float a = 0.f;
        for (int kk = 0; kk < 128; ++kk) a += kw[kk*9 + s1]*qb[kk];
        bvec[s1] = a;
    } else if (t < 99) {
        int t1 = t - 90; float a = 0.f;
        for (int kk = 0; kk < 128; ++kk) a += vw[kk*9 + t1];
        wvm[t1] = a * (1.0f/128.0f);
    } else if (t == 99) {
        float a = 0.f, c2 = 0.f;
        for (int kk = 0; kk < 128; ++kk) { a += qb[kk]*kb[kk]; c2 += vb[kk]; }
        cc_[0] = a; cc_[1] = c2 * (1.0f/128.0f);
    }
    __syncthreads();

    if (t < 128) {
        int j = t;
        for (int t1 = 0; t1 < 9; ++t1) {
            float a = 0.f;
            for (int s1 = 0; s1 < 9; ++s1) a += Mm[t1*9 + s1]*Ub[j*9 + s1];
            Wj[j*9 + t1] = a;
        }
        float z = cc_[0], v2 = cc_[1];
        for (int s1 = 0; s1 < 9; ++s1) { z += bvec[s1]*Ub[j*9 + s1]; v2 += wvm[s1]*Ub[j*9 + s1]; }
        zj[j] = z; vm[j] = v2;
    }
    __syncthreads();

    int i = t >> 1, half = t & 1;
    float ui[9];
#pragma unroll
    for (int s1 = 0; s1 < 9; ++s1) ui[s1] = Ub[i*9 + s1];

    float mx = -1e30f;
    for (int jj = 0; jj < 64; ++jj) {
        int j = half*64 + jj;
        float a = zj[j];
#pragma unroll
        for (int s1 = 0; s1 < 9; ++s1) a += ui[s1]*Wj[j*9 + s1];
        mx = fmaxf(mx, a * (1.0f/3.0f));
    }
    mx = fmaxf(mx, __shfl_xor(mx, 1));
    float sum = 0.f, o = 0.f;
    for (int jj = 0; jj < 64; ++jj) {
        int j = half*64 + jj;
        float a = zj[j];
#pragma unroll
        for (int s1 = 0; s1 < 9; ++s1) a += ui[s1]*Wj[j*9 + s1];
        float p = expf(a * (1.0f/3.0f) - mx);
        sum += p; o += p*vm[j];
    }
    sum += __shfl_xor(sum, 1);
    o   += __shfl_xor(o, 1);
    if (half == 0) {
        float base;
        if (f > 0) base = ui[f];
        else { base = 0.f; for (int s1 = 0; s1 < 9; ++s1) base += ui[s1]; base *= (1.0f/9.0f); }
        outp[((size_t)b*128 + i)*10 + f] = o/sum + base;
    }
}

// ---------------------------------------------------------------------------
// Merge attention (features 3..8), writes output column 9 (unchanged).
// ---------------------------------------------------------------------------
__global__ __launch_bounds__(256) void merge_kernel(
    const float* __restrict__ U,
    const float* __restrict__ mQW, const float* __restrict__ mQB,
    const float* __restrict__ mKW, const float* __restrict__ mKB,
    const float* __restrict__ mVW, const float* __restrict__ mVB,
    float* __restrict__ outp)
{
    int b = blockIdx.x;
    __shared__ float Us[128*6];
    __shared__ float Wj[128*6];
    __shared__ float zj[128];
    __shared__ float vm[128];
    __shared__ float Mm[36];
    __shared__ float wvm[6], bvec[6];
    __shared__ float cc_[2];
    int t = threadIdx.x;
    for (int i = t; i < 768; i += 256) {
        int j = i/6, tt = i - j*6;
        Us[i] = U[(size_t)b*1152 + j*9 + 3 + tt];
    }
    if (t < 36) {
        int t1 = t/6, s1 = t%6; float a = 0.f;
        for (int kk = 0; kk < 128; ++kk) a += mQW[kk*6 + t1]*mKW[kk*6 + s1];
        Mm[t] = a;
    } else if (t < 42) {
        int s1 = t - 36; float a = 0.f;
        for (int kk = 0; kk < 128; ++kk) a += mKW[kk*6 + s1]*mQB[kk];
        bvec[s1] = a;
    } else if (t < 48) {
        int t1 = t - 42; float a = 0.f;
        for (int kk = 0; kk < 128; ++kk) a += mVW[kk*6 + t1];
        wvm[t1] = a * (1.0f/128.0f);
    } else if (t == 48) {
        float a = 0.f, c2 = 0.f;
        for (int kk = 0; kk < 128; ++kk) { a += mQB[kk]*mKB[kk]; c2 += mVB[kk]; }
        cc_[0] = a; cc_[1] = c2 * (1.0f/128.0f);
    }
    __syncthreads();

    if (t < 128) {
        int j = t;
        for (int t1 = 0; t1 < 6; ++t1) {
            float a = 0.f;
            for (int s1 = 0; s1 < 6; ++s1) a += Mm[t1*6 + s1]*Us[j*6 + s1];
            Wj[j*6 + t1] = a;
        }
        float z = cc_[0], v2 = cc_[1];
        for (int s1 = 0; s1 < 6; ++s1) { z += bvec[s1]*Us[j*6 + s1]; v2 += wvm[s1]*Us[j*6 + s1]; }
        zj[j] = z; vm[j] = v2;
    }
    __syncthreads();

    int i = t >> 1, half = t & 1;
    float ui[6];
#pragma unroll
    for (int s1 = 0; s1 < 6; ++s1) ui[s1] = Us[i*6 + s1];

    float mx = -1e30f;
    for (int jj = 0; jj < 64; ++jj) {
        int j = half*64 + jj;
        float a = zj[j];
#pragma unroll
        for (int s1 = 0; s1 < 6; ++s1) a += ui[s1]*Wj[j*6 + s1];
        mx = fmaxf(mx, a * (1.0f/3.0f));
    }
    mx = fmaxf(mx, __shfl_xor(mx, 1));
    float sum = 0.f, o = 0.f;
    for (int jj = 0; jj < 64; ++jj) {
        int j = half*64 + jj;
        float a = zj[j];
#pragma unroll
        for (int s1 = 0; s1 < 6; ++s1) a += ui[s1]*Wj[j*6 + s1];
        float p = expf(a * (1.0f/3.0f) - mx);
        sum += p; o += p*vm[j];
    }
    sum += __shfl_xor(sum, 1);
    o   += __shfl_xor(o, 1);
    if (half == 0) {
        float base = 0.f;
        for (int s1 = 0; s1 < 6; ++s1) base += ui[s1];
        base *= (1.0f/6.0f);
        outp[((size_t)b*128 + i)*10 + 9] = o/sum + base;
    }
}

// ---------------------------------------------------------------------------
extern "C" void kernel_launch(void* const* d_in, const int* in_sizes, int n_in,
                              void* d_out, int out_size, void* d_ws, size_t ws_size,
                              hipStream_t stream)
{
    const float* Y     = (const float*)d_in[0];
    const float* Gin   = (const float*)d_in[1];
    const float* posW1 = (const float*)d_in[2];
    const float* posB1 = (const float*)d_in[3];
    const float* posW2 = (const float*)d_in[4];
    const float* posB2 = (const float*)d_in[5];
    const float* posW3 = (const float*)d_in[6];
    const float* posB3 = (const float*)d_in[7];
    const float* Wq    = (const float*)d_in[8];
    const float* bq    = (const float*)d_in[9];
    const float* Wk    = (const float*)d_in[10];
    const float* bk    = (const float*)d_in[11];
    const float* Wv    = (const float*)d_in[12];
    const float* bv    = (const float*)d_in[13];
    const float* Wo    = (const float*)d_in[14];
    const float* bo    = (const float*)d_in[15];
    const float* lnG   = (const float*)d_in[16];
    const float* lnB   = (const float*)d_in[17];
    const float* fnG   = (const float*)d_in[18];
    const float* fnB   = (const float*)d_in[19];
    const float* poolW = (const float*)d_in[20];
    const float* uQW   = (const float*)d_in[21];
    const float* uQB   = (const float*)d_in[22];
    const float* uKW   = (const float*)d_in[23];
    const float* uKB   = (const float*)d_in[24];
    const float* uVW   = (const float*)d_in[25];
    const float* uVB   = (const float*)d_in[26];
    const float* mQW   = (const float*)d_in[27];
    const float* mQB   = (const float*)d_in[28];
    const float* mKW   = (const float*)d_in[29];
    const float* mKB   = (const float*)d_in[30];
    const float* mVW   = (const float*)d_in[31];
    const float* mVB   = (const float*)d_in[32];

    float* ws = (float*)d_ws;
    const size_t xelems = (size_t)F_ * BS_ * 128;     // 4,718,592 floats
    float* xA   = ws;
    float* xB   = xA + xelems;
    float* Ubuf = xB + xelems;                        // 9216 floats used
    size_t fixed_floats = 2*xelems + 16384;
    size_t fixed_bytes  = fixed_floats * 4;

    size_t avail = (ws_size > fixed_bytes) ? (ws_size - fixed_bytes) : 0;
    size_t per_f = 5UL * PERBUF * 2UL;                // q,k,v,wv bf16 + Vt u32
    int FC = (int)(avail / per_f);
    if (FC < 1) FC = 1;
    if (FC > F_) FC = F_;

    unsigned short* qb  = (unsigned short*)((char*)d_ws + fixed_bytes);
    unsigned short* kb  = qb + (size_t)FC*PERBUF;
    unsigned short* vb  = kb + (size_t)FC*PERBUF;
    unsigned short* wvb = vb + (size_t)FC*PERBUF;
    unsigned int*   vtb = (unsigned int*)(wvb + (size_t)FC*PERBUF);

    posnet_kernel<<<dim3(1024, 1, F_), 256, 0, stream>>>(
        Y, Gin, posW1, posB1, posW2, posB2, posW3, posB3, xA);

    for (int l = 0; l < 2; ++l) {
        for (int f0 = 0; f0 < F_; f0 += FC) {
            int fc = (F_ - f0) < FC ? (F_ - f0) : FC;
            qkv_kernel<<<dim3(32, 16, 3*fc), 256, 0, stream>>>(
                xA, Wq, Wk, Wv, bq, bk, bv, qb, kb, vb, l, f0);
            vtrans_kernel<<<dim3(8, 64, fc), 256, 0, stream>>>(vb, vtb);
            attn_mfma_kernel<<<dim3(8, 64, fc), 256, 0, stream>>>(qb, kb, vtb, wvb);
            outproj_kernel<<<dim3(64, 1, fc), 256, 0, stream>>>(
                wvb, Wo, bo, xA, xB, l, f0);
            ln_kernel<<<dim3(fc*1024), 256, 0, stream>>>(
                xB, xA, lnG + (size_t)(l*F_ + f0)*128, lnB + (size_t)(l*F_ + f0)*128, f0, 128);
        }
    }

    for (int f0 = 0; f0 < F_; f0 += FC) {
        int fc = (F_ - f0) < FC ? (F_ - f0) : FC;
        ln_kernel<<<dim3(fc*1024), 256, 0, stream>>>(xA, xB, fnG, fnB, f0, 0);
        pool_kernel<<<dim3(fc, 8), 256, 0, stream>>>(xB, poolW, Ubuf, f0);
    }

    unified_kernel<<<dim3(F_, B_), 256, 0, stream>>>(
        Ubuf, uQW, uQB, uKW, uKB, uVW, uVB, (float*)d_out);
    merge_kernel<<<dim3(B_), 256, 0, stream>>>(
        Ubuf, mQW, mQB, mKW, mKB, mVW, mVB, (float*)d_out);
}

// Round 3
// 1958.421 us; speedup vs baseline: 3.1438x; 2.0248x over previous
//
#include <hip/hip_runtime.h>
#include <hip/hip_bf16.h>

// Problem constants
#define F_  9
#define B_  8
#define S_  512
#define H_  8
#define DH_ 128
#define D_  128
#define NB_ 50
#define BS_ 4096            // B_*S_ rows per feature
#define PERBUF 4194304UL    // B_*H_*S_*DH_ elements per feature
#define WELEMS 2359296UL    // 2*9*1024*128 elements per projection weight tensor

typedef short bf16x8 __attribute__((ext_vector_type(8)));
typedef float f32x4  __attribute__((ext_vector_type(4)));

static __device__ __forceinline__ unsigned short f2b(float f) {
    unsigned int u = __float_as_uint(f);
    unsigned int r = (u + 0x7FFFu + ((u >> 16) & 1u)) >> 16;
    return (unsigned short)r;
}
static __device__ __forceinline__ float b2f(unsigned short u) {
    return __uint_as_float(((unsigned int)u) << 16);
}

// ---------------------------------------------------------------------------
// fp32 -> bf16 bulk convert (for projection weights), 8 elems/thread.
// ---------------------------------------------------------------------------
__global__ __launch_bounds__(256) void cvt_kernel(
    const float* __restrict__ in, unsigned short* __restrict__ out, int n)
{
    int i = (blockIdx.x * 256 + threadIdx.x) * 8;
    if (i + 8 <= n) {
        float4 a = *(const float4*)&in[i];
        float4 b = *(const float4*)&in[i + 4];
        ushort4 o0 = { f2b(a.x), f2b(a.y), f2b(a.z), f2b(a.w) };
        ushort4 o1 = { f2b(b.x), f2b(b.y), f2b(b.z), f2b(b.w) };
        *(ushort4*)&out[i]     = o0;
        *(ushort4*)&out[i + 4] = o1;
    }
}

// ---------------------------------------------------------------------------
// Pos-net: one wave per row, activations one-per-lane via shfl.
// Emits fp32 x (for residual) and bf16 x (for MFMA GEMMs).
// ---------------------------------------------------------------------------
__global__ __launch_bounds__(256) void posnet_kernel(
    const float* __restrict__ Y, const float* __restrict__ Gin,
    const float* __restrict__ W1g, const float* __restrict__ B1,
    const float* __restrict__ W2g, const float* __restrict__ B2,
    const float* __restrict__ W3g, const float* __restrict__ B3,
    float* __restrict__ xA, unsigned short* __restrict__ xAb)
{
    __shared__ float w1[50*51];
    __shared__ float w2[50*50];
    __shared__ float w3[128*50];
    __shared__ float b1[64], b2[64], b3[128];
    int f = blockIdx.z;
    int t = threadIdx.x;
    for (int i = t; i < 2550; i += 256) w1[i] = W1g[f*2550 + i];
    for (int i = t; i < 2500; i += 256) w2[i] = W2g[f*2500 + i];
    for (int i = t; i < 6400; i += 256) w3[i] = W3g[f*6400 + i];
    if (t < 50) { b1[t] = B1[f*50 + t]; b2[t] = B2[f*50 + t]; }
    if (t < 128) b3[t] = B3[f*128 + t];
    __syncthreads();

    int lane = t & 63, w = t >> 6;
    int row = blockIdx.x * 4 + w;   // 0..4095

    float gy = 0.f;
    if (lane < 50)       gy = Y[(size_t)row*50 + lane];
    else if (lane == 50) gy = Gin[(size_t)row*F_ + f];

    float a1 = (lane < 50) ? b1[lane] : 0.f;
    for (int kk = 0; kk < 51; ++kk) {
        float g = __shfl(gy, kk);
        if (lane < 50) a1 += w1[lane*51 + kk] * g;
    }
    float h1 = tanhf(a1);

    float a2 = (lane < 50) ? b2[lane] : 0.f;
    for (int kk = 0; kk < 50; ++kk) {
        float hh = __shfl(h1, kk);
        if (lane < 50) a2 += w2[lane*50 + kk] * hh;
    }
    float h2 = tanhf(a2);

    float a30 = b3[lane], a31 = b3[64 + lane];
    for (int kk = 0; kk < 50; ++kk) {
        float hh = __shfl(h2, kk);
        a30 += w3[lane*50 + kk] * hh;
        a31 += w3[(64 + lane)*50 + kk] * hh;
    }
    float s0v = 1.f / (1.f + expf(-a30));
    float s1v = 1.f / (1.f + expf(-a31));
    size_t roff = ((size_t)f*BS_ + row)*128;
    xA[roff + lane]       = s0v;
    xA[roff + 64 + lane]  = s1v;
    xAb[roff + lane]      = f2b(s0v);
    xAb[roff + 64 + lane] = f2b(s1v);
}

// ---------------------------------------------------------------------------
// QKV projection via MFMA: C[4096x1024] = Xb[4096x128] * Wb^T (+bias).
// 128x128 tile, 4 waves (2x2), each wave 64x64 = 4x4 16x16 frags, K=128.
// Fragments read directly from global (L2-resident), no LDS, no barriers.
// which==0/1 -> q/k row-major bf16 [bh][s][dh]; which==2 -> Vt packed u32.
// ---------------------------------------------------------------------------
__global__ __launch_bounds__(256) void qkv_mfma_kernel(
    const unsigned short* __restrict__ xb,
    const unsigned short* __restrict__ Wqb, const unsigned short* __restrict__ Wkb,
    const unsigned short* __restrict__ Wvb,
    const float* __restrict__ bq, const float* __restrict__ bk, const float* __restrict__ bv,
    unsigned short* __restrict__ qo, unsigned short* __restrict__ ko,
    unsigned int* __restrict__ vto, int l, int f0)
{
    int z = blockIdx.z;
    int fl = z / 3, which = z - fl*3;
    int f = f0 + fl;
    const unsigned short* W; const float* bias;
    if (which == 0)      { W = Wqb; bias = bq; }
    else if (which == 1) { W = Wkb; bias = bk; }
    else                 { W = Wvb; bias = bv; }
    W    += (size_t)(l*F_ + f) * 1024 * 128;
    bias += (size_t)(l*F_ + f) * 1024;

    int m0 = blockIdx.x * 128;
    int n0 = blockIdx.y * 128;
    int t = threadIdx.x, w = t >> 6, ln = t & 63, g = ln >> 4, c = ln & 15;
    int wr = w >> 1, wc = w & 1;

    const unsigned short* Ab = xb + ((size_t)f*BS_ + m0 + wr*64)*128;
    const unsigned short* Bb = W + (size_t)(n0 + wc*64)*128;

    f32x4 acc[4][4];
#pragma unroll
    for (int mi = 0; mi < 4; ++mi)
#pragma unroll
        for (int ni = 0; ni < 4; ++ni) acc[mi][ni] = (f32x4){0.f,0.f,0.f,0.f};

#pragma unroll
    for (int kt = 0; kt < 4; ++kt) {
        bf16x8 af[4], bfr[4];
#pragma unroll
        for (int mi = 0; mi < 4; ++mi)
            af[mi] = *(const bf16x8*)&Ab[(size_t)(mi*16 + c)*128 + kt*32 + g*8];
#pragma unroll
        for (int ni = 0; ni < 4; ++ni)
            bfr[ni] = *(const bf16x8*)&Bb[(size_t)(ni*16 + c)*128 + kt*32 + g*8];
#pragma unroll
        for (int mi = 0; mi < 4; ++mi)
#pragma unroll
            for (int ni = 0; ni < 4; ++ni)
                acc[mi][ni] = __builtin_amdgcn_mfma_f32_16x16x32_bf16(af[mi], bfr[ni], acc[mi][ni], 0, 0, 0);
    }

    int h = n0 >> 7;                       // head index (tile spans one head)
    float bs_[4];
#pragma unroll
    for (int ni = 0; ni < 4; ++ni) bs_[ni] = bias[n0 + wc*64 + ni*16 + c];

    if (which < 2) {
        unsigned short* out = (which == 0 ? qo : ko) + (size_t)fl * PERBUF;
#pragma unroll
        for (int mi = 0; mi < 4; ++mi) {
#pragma unroll
            for (int r = 0; r < 4; ++r) {
                int m = m0 + wr*64 + mi*16 + 4*g + r;
                int b = m >> 9, s = m & 511;
                unsigned short* orow = out + (((size_t)(b*H_ + h))*S_ + s)*128;
#pragma unroll
                for (int ni = 0; ni < 4; ++ni)
                    orow[wc*64 + ni*16 + c] = f2b(acc[mi][ni][r] + bs_[ni]);
            }
        }
    } else {
        // Vt[bh][d][s/2] u32: lo = even s, hi = odd s.
        unsigned int* vtf = vto + (size_t)fl * (PERBUF/2);
#pragma unroll
        for (int mi = 0; mi < 4; ++mi) {
            int mbase = m0 + wr*64 + mi*16 + 4*g;      // multiple of 4
            int b = mbase >> 9, sh = (mbase & 511) >> 1;
            unsigned int* vtp = vtf + ((size_t)(b*H_ + h))*32768;
#pragma unroll
            for (int ni = 0; ni < 4; ++ni) {
                int d = wc*64 + ni*16 + c;
                float bb_ = bs_[ni];
                unsigned int p01 = (unsigned int)f2b(acc[mi][ni][0] + bb_)
                                 | ((unsigned int)f2b(acc[mi][ni][1] + bb_) << 16);
                unsigned int p23 = (unsigned int)f2b(acc[mi][ni][2] + bb_)
                                 | ((unsigned int)f2b(acc[mi][ni][3] + bb_) << 16);
                vtp[(size_t)d*256 + sh]     = p01;
                vtp[(size_t)d*256 + sh + 1] = p23;
            }
        }
    }
}

// ---------------------------------------------------------------------------
// MFMA flash attention (unchanged from round 2; verified).
// ---------------------------------------------------------------------------
__global__ __launch_bounds__(256) void attn_mfma_kernel(
    const unsigned short* __restrict__ q, const unsigned short* __restrict__ k,
    const unsigned int* __restrict__ vt, unsigned short* __restrict__ wv)
{
    int t = threadIdx.x;
    int w = t >> 6, l = t & 63, g = l >> 4, c = l & 15;
    int fl = blockIdx.z, by = blockIdx.y;
    int i0 = blockIdx.x * 64;
    int q0 = i0 + w*16;
    const unsigned short* qh = q + ((size_t)(fl*64 + by))*S_*128;
    const unsigned short* kh = k + ((size_t)(fl*64 + by))*S_*128;
    const unsigned int*  vth = vt + ((size_t)(fl*64 + by))*32768;
    int b = by >> 3, h = by & 7;
    unsigned short* wvh = wv + ((size_t)(fl*B_ + b))*S_*1024 + h*128;

    __shared__ alignas(16) unsigned short Pl[4][16][40];   // per-wave, pitch 80 B

    bf16x8 qf[4];
#pragma unroll
    for (int d0 = 0; d0 < 4; ++d0)
        qf[d0] = *(const bf16x8*)&qh[(size_t)(q0 + c)*128 + d0*32 + g*8];

    f32x4 acc[8];
#pragma unroll
    for (int i = 0; i < 8; ++i) acc[i] = (f32x4){0.f, 0.f, 0.f, 0.f};
    float mrow[4] = {-1e30f, -1e30f, -1e30f, -1e30f};
    float lrow[4] = {0.f, 0.f, 0.f, 0.f};
    const float scale = 0.08838834764831845f;   // 1/sqrt(128)

    for (int kt = 0; kt < 16; ++kt) {
        f32x4 s0 = (f32x4){0.f,0.f,0.f,0.f}, s1 = (f32x4){0.f,0.f,0.f,0.f};
        const unsigned short* kp = &kh[(size_t)(kt*32 + c)*128 + g*8];
#pragma unroll
        for (int d0 = 0; d0 < 4; ++d0) {
            bf16x8 k0 = *(const bf16x8*)(kp + d0*32);
            bf16x8 k1 = *(const bf16x8*)(kp + 16*128 + d0*32);
            s0 = __builtin_amdgcn_mfma_f32_16x16x32_bf16(qf[d0], k0, s0, 0, 0, 0);
            s1 = __builtin_amdgcn_mfma_f32_16x16x32_bf16(qf[d0], k1, s1, 0, 0, 0);
        }

        float corr[4];
#pragma unroll
        for (int r = 0; r < 4; ++r) {
            float a0 = s0[r]*scale, a1 = s1[r]*scale;
            float tm = fmaxf(a0, a1);
            tm = fmaxf(tm, __shfl_xor(tm, 1));
            tm = fmaxf(tm, __shfl_xor(tm, 2));
            tm = fmaxf(tm, __shfl_xor(tm, 4));
            tm = fmaxf(tm, __shfl_xor(tm, 8));
            float mn = fmaxf(mrow[r], tm);
            corr[r] = __expf(mrow[r] - mn);
            mrow[r] = mn;
            float p0 = __expf(a0 - mn), p1 = __expf(a1 - mn);
            float ps = p0 + p1;
            ps += __shfl_xor(ps, 1);
            ps += __shfl_xor(ps, 2);
            ps += __shfl_xor(ps, 4);
            ps += __shfl_xor(ps, 8);
            lrow[r] = lrow[r]*corr[r] + ps;
            Pl[w][4*g + r][c]      = f2b(p0);
            Pl[w][4*g + r][16 + c] = f2b(p1);
        }
#pragma unroll
        for (int i = 0; i < 8; ++i) {
            f32x4 a = acc[i];
            a[0] *= corr[0]; a[1] *= corr[1]; a[2] *= corr[2]; a[3] *= corr[3];
            acc[i] = a;
        }

        bf16x8 pa = *(const bf16x8*)&Pl[w][c][g*8];
        const unsigned int* vp = vth + kt*16 + 4*g;
#pragma unroll
        for (int i = 0; i < 8; ++i) {
            bf16x8 vf = *(const bf16x8*)&vp[(size_t)(i*16 + c)*256];
            acc[i] = __builtin_amdgcn_mfma_f32_16x16x32_bf16(pa, vf, acc[i], 0, 0, 0);
        }
    }

    float inv[4];
#pragma unroll
    for (int r = 0; r < 4; ++r) inv[r] = 1.0f / lrow[r];
#pragma unroll
    for (int i = 0; i < 8; ++i)
#pragma unroll
        for (int r = 0; r < 4; ++r)
            wvh[(size_t)(q0 + 4*g + r)*1024 + i*16 + c] = f2b(acc[i][r]*inv[r]);
}

// ---------------------------------------------------------------------------
// Out-projection via MFMA + residual: x1 = x0 + wv @ Wo^T + bo (fp32 out).
// M=4096, N=128, K=1024. 128x128 tile, 4 waves (2x2), 4x4 frags/wave.
// ---------------------------------------------------------------------------
__global__ __launch_bounds__(256) void outproj_mfma_kernel(
    const unsigned short* __restrict__ wv, const unsigned short* __restrict__ Wob,
    const float* __restrict__ bo, const float* __restrict__ xin,
    float* __restrict__ xout, int l, int f0)
{
    int fl = blockIdx.z, f = f0 + fl;
    int m0 = blockIdx.x * 128;
    int t = threadIdx.x, w = t >> 6, ln = t & 63, g = ln >> 4, c = ln & 15;
    int wr = w >> 1, wc = w & 1;

    const unsigned short* Ab = wv + ((size_t)fl*BS_ + m0 + wr*64)*1024;
    const unsigned short* Bb = Wob + (size_t)(l*F_ + f)*128*1024 + (size_t)(wc*64)*1024;
    const float* bob = bo + (size_t)(l*F_ + f)*128;

    f32x4 acc[4][4];
#pragma unroll
    for (int mi = 0; mi < 4; ++mi)
#pragma unroll
        for (int ni = 0; ni < 4; ++ni) acc[mi][ni] = (f32x4){0.f,0.f,0.f,0.f};

#pragma unroll 4
    for (int kt = 0; kt < 32; ++kt) {
        bf16x8 af[4], bfr[4];
#pragma unroll
        for (int mi = 0; mi < 4; ++mi)
            af[mi] = *(const bf16x8*)&Ab[(size_t)(mi*16 + c)*1024 + kt*32 + g*8];
#pragma unroll
        for (int ni = 0; ni < 4; ++ni)
            bfr[ni] = *(const bf16x8*)&Bb[(size_t)(ni*16 + c)*1024 + kt*32 + g*8];
#pragma unroll
        for (int mi = 0; mi < 4; ++mi)
#pragma unroll
            for (int ni = 0; ni < 4; ++ni)
                acc[mi][ni] = __builtin_amdgcn_mfma_f32_16x16x32_bf16(af[mi], bfr[ni], acc[mi][ni], 0, 0, 0);
    }

    float bs_[4];
#pragma unroll
    for (int ni = 0; ni < 4; ++ni) bs_[ni] = bob[wc*64 + ni*16 + c];

#pragma unroll
    for (int mi = 0; mi < 4; ++mi) {
#pragma unroll
        for (int r = 0; r < 4; ++r) {
            int m = m0 + wr*64 + mi*16 + 4*g + r;
            const float* xr = xin + ((size_t)f*BS_ + m)*128;
            float* xo = xout + ((size_t)f*BS_ + m)*128;
#pragma unroll
            for (int ni = 0; ni < 4; ++ni) {
                int n = wc*64 + ni*16 + c;
                xo[n] = acc[mi][ni][r] + bs_[ni] + xr[n];
            }
        }
    }
}

// ---------------------------------------------------------------------------
// LayerNorm over last dim (128). One wave per row. Emits fp32 + bf16.
// ---------------------------------------------------------------------------
__global__ __launch_bounds__(256) void ln_kernel(
    const float* __restrict__ xin, float* __restrict__ xout,
    unsigned short* __restrict__ xoutb,
    const float* __restrict__ g, const float* __restrict__ bb, int f0, int gstride)
{
    int t = threadIdx.x, lane = t & 63, w = t >> 6;
    int rowl = blockIdx.x * 4 + w;
    int fl = rowl >> 12;
    size_t row = (size_t)f0*BS_ + rowl;
    const float* xi = xin + row*128;
    float a = xi[lane], c = xi[64 + lane];
    float s = a + c;
#pragma unroll
    for (int off = 1; off < 64; off <<= 1) s += __shfl_xor(s, off);
    float mean = s * (1.0f/128.0f);
    float da = a - mean, dc = c - mean;
    float vs = da*da + dc*dc;
#pragma unroll
    for (int off = 1; off < 64; off <<= 1) vs += __shfl_xor(vs, off);
    float inv = rsqrtf(vs * (1.0f/128.0f) + 1e-5f);
    const float* gp = g + (size_t)fl*gstride;
    const float* bp = bb + (size_t)fl*gstride;
    float o0 = da*inv*gp[lane]      + bp[lane];
    float o1 = dc*inv*gp[64 + lane] + bp[64 + lane];
    float* xo = xout + row*128;
    xo[lane]      = o0;
    xo[64 + lane] = o1;
    xoutb[row*128 + lane]      = f2b(o0);
    xoutb[row*128 + 64 + lane] = f2b(o1);
}

// ---------------------------------------------------------------------------
// Softmax-pool over S (unchanged).
// ---------------------------------------------------------------------------
__global__ __launch_bounds__(256) void pool_kernel(
    const float* __restrict__ xB, const float* __restrict__ poolW,
    float* __restrict__ U, int f0)
{
    int f = f0 + blockIdx.x, b = blockIdx.y;
    const float* xb = xB + ((size_t)f*BS_ + (size_t)b*S_)*128;
    const float* pw = poolW + f*128;
    __shared__ float sc[512];
    __shared__ float red[8];
    __shared__ float MS[2];
    __shared__ float pool2[256];
    int t = threadIdx.x, lane = t & 63, w = t >> 6;

    float p0 = pw[lane], p1 = pw[64 + lane];
    for (int s = w; s < 512; s += 4) {
        float a = xb[(size_t)s*128 + lane]*p0 + xb[(size_t)s*128 + 64 + lane]*p1;
#pragma unroll
        for (int off = 1; off < 64; off <<= 1) a += __shfl_xor(a, off);
        if (lane == 0) sc[s] = a;
    }
    __syncthreads();

    float m = -1e30f;
    for (int s = t; s < 512; s += 256) m = fmaxf(m, sc[s]);
#pragma unroll
    for (int off = 1; off < 64; off <<= 1) m = fmaxf(m, __shfl_xor(m, off));
    if (lane == 0) red[w] = m;
    __syncthreads();
    if (t == 0) MS[0] = fmaxf(fmaxf(red[0], red[1]), fmaxf(red[2], red[3]));
    __syncthreads();
    float M = MS[0];

    float ssum = 0.f;
    for (int s = t; s < 512; s += 256) { float e = expf(sc[s] - M); sc[s] = e; ssum += e; }
#pragma unroll
    for (int off = 1; off < 64; off <<= 1) ssum += __shfl_xor(ssum, off);
    if (lane == 0) red[4 + w] = ssum;
    __syncthreads();
    if (t == 0) MS[1] = red[4] + red[5] + red[6] + red[7];
    __syncthreads();
    float inv = 1.0f / MS[1];

    int d = t & 127, hh = t >> 7;
    float a = 0.f;
    for (int s = hh*256; s < hh*256 + 256; ++s) a += sc[s]*xb[(size_t)s*128 + d];
    pool2[t] = a;
    __syncthreads();
    if (t < 128) U[((size_t)b*128 + d)*F_ + f] = (pool2[t] + pool2[t + 128]) * inv;
}

// ---------------------------------------------------------------------------
// Unified attention per (f,b) (unchanged).
// ---------------------------------------------------------------------------
__global__ __launch_bounds__(256) void unified_kernel(
    const float* __restrict__ U,
    const float* __restrict__ uQW, const float* __restrict__ uQB,
    const float* __restrict__ uKW, const float* __restrict__ uKB,
    const float* __restrict__ uVW, const float* __restrict__ uVB,
    float* __restrict__ outp)
{
    int f = blockIdx.x, b = blockIdx.y;
    __shared__ float Ub[128*9];
    __shared__ float Wj[128*9];
    __shared__ float zj[128];
    __shared__ float vm[128];
    __shared__ float Mm[81];
    __shared__ float wvm[9], bvec[9];
    __shared__ float cc_[2];
    int t = threadIdx.x;
    for (int i = t; i < 1152; i += 256) Ub[i] = U[(size_t)b*1152 + i];
    const float* qw = uQW + (size_t)f*1152;
    const float* kw = uKW + (size_t)f*1152;
    const float* vw = uVW + (size_t)f*1152;
    const float* qb = uQB + (size_t)f*128;
    const float* kb = uKB + (size_t)f*128;
    const float* vb = uVB + (size_t)f*128;

    if (t < 81) {
        int t1 = t/9, s1 = t%9; float a = 0.f;
        for (int kk = 0; kk < 128; ++kk) a += qw[kk*9 + t1]*kw[kk*9 + s1];
        Mm[t] = a;
    } else if (t < 90) {
        int s1 = t - 81; float a = 0.f;
        for (int kk = 0; kk < 128; ++kk) a += kw[kk*9 + s1]*qb[kk];
        bvec[s1] = a;
    } else if (t < 99) {
        int t1 = t - 90; float a = 0.f;
        for (int kk = 0; kk < 128; ++kk) a += vw[kk*9 + t1];
        wvm[t1] = a * (1.0f/128.0f);
    } else if (t == 99) {
        float a = 0.f, c2 = 0.f;
        for (int kk = 0; kk < 128; ++kk) { a += qb[kk]*kb[kk]; c2 += vb[kk]; }
        cc_[0] = a; cc_[1] = c2 * (1.0f/128.0f);
    }
    __syncthreads();

    if (t < 128) {
        int j = t;
        for (int t1 = 0; t1 < 9; ++t1) {
            float a = 0.f;
            for (int s1 = 0; s1 < 9; ++s1) a += Mm[t1*9 + s1]*Ub[j*9 + s1];
            Wj[j*9 + t1] = a;
        }
        float z = cc_[0], v2 = cc_[1];
        for (int s1 = 0; s1 < 9; ++s1) { z += bvec[s1]*Ub[j*9 + s1]; v2 += wvm[s1]*Ub[j*9 + s1]; }
        zj[j] = z; vm[j] = v2;
    }
    __syncthreads();

    int i = t >> 1, half = t & 1;
    float ui[9];
#pragma unroll
    for (int s1 = 0; s1 < 9; ++s1) ui[s1] = Ub[i*9 + s1];

    float mx = -1e30f;
    for (int jj = 0; jj < 64; ++jj) {
        int j = half*64 + jj;
        float a = zj[j];
#pragma unroll
        for (int s1 = 0; s1 < 9; ++s1) a += ui[s1]*Wj[j*9 + s1];
        mx = fmaxf(mx, a * (1.0f/3.0f));
    }
    mx = fmaxf(mx, __shfl_xor(mx, 1));
    float sum = 0.f, o = 0.f;
    for (int jj = 0; jj < 64; ++jj) {
        int j = half*64 + jj;
        float a = zj[j];
#pragma unroll
        for (int s1 = 0; s1 < 9; ++s1) a += ui[s1]*Wj[j*9 + s1];
        float p = expf(a * (1.0f/3.0f) - mx);
        sum += p; o += p*vm[j];
    }
    sum += __shfl_xor(sum, 1);
    o   += __shfl_xor(o, 1);
    if (half == 0) {
        float base;
        if (f > 0) base = ui[f];
        else { base = 0.f; for (int s1 = 0; s1 < 9; ++s1) base += ui[s1]; base *= (1.0f/9.0f); }
        outp[((size_t)b*128 + i)*10 + f] = o/sum + base;
    }
}

// ---------------------------------------------------------------------------
// Merge attention (features 3..8), writes output column 9 (unchanged).
// ---------------------------------------------------------------------------
__global__ __launch_bounds__(256) void merge_kernel(
    const float* __restrict__ U,
    const float* __restrict__ mQW, const float* __restrict__ mQB,
    const float* __restrict__ mKW, const float* __restrict__ mKB,
    const float* __restrict__ mVW, const float* __restrict__ mVB,
    float* __restrict__ outp)
{
    int b = blockIdx.x;
    __shared__ float Us[128*6];
    __shared__ float Wj[128*6];
    __shared__ float zj[128];
    __shared__ float vm[128];
    __shared__ float Mm[36];
    __shared__ float wvm[6], bvec[6];
    __shared__ float cc_[2];
    int t = threadIdx.x;
    for (int i = t; i < 768; i += 256) {
        int j = i/6, tt = i - j*6;
        Us[i] = U[(size_t)b*1152 + j*9 + 3 + tt];
    }
    if (t < 36) {
        int t1 = t/6, s1 = t%6; float a = 0.f;
        for (int kk = 0; kk < 128; ++kk) a += mQW[kk*6 + t1]*mKW[kk*6 + s1];
        Mm[t] = a;
    } else if (t < 42) {
        int s1 = t - 36; float a = 0.f;
        for (int kk = 0; kk < 128; ++kk) a += mKW[kk*6 + s1]*mQB[kk];
        bvec[s1] = a;
    } else if (t < 48) {
        int t1 = t - 42; float a = 0.f;
        for (int kk = 0; kk < 128; ++kk) a += mVW[kk*6 + t1];
        wvm[t1] = a * (1.0f/128.0f);
    } else if (t == 48) {
        float a = 0.f, c2 = 0.f;
        for (int kk = 0; kk < 128; ++kk) { a += mQB[kk]*mKB[kk]; c2 += mVB[kk]; }
        cc_[0] = a; cc_[1] = c2 * (1.0f/128.0f);
    }
    __syncthreads();

    if (t < 128) {
        int j = t;
        for (int t1 = 0; t1 < 6; ++t1) {
            float a = 0.f;
            for (int s1 = 0; s1 < 6; ++s1) a += Mm[t1*6 + s1]*Us[j*6 + s1];
            Wj[j*6 + t1] = a;
        }
        float z = cc_[0], v2 = cc_[1];
        for (int s1 = 0; s1 < 6; ++s1) { z += bvec[s1]*Us[j*6 + s1]; v2 += wvm[s1]*Us[j*6 + s1]; }
        zj[j] = z; vm[j] = v2;
    }
    __syncthreads();

    int i = t >> 1, half = t & 1;
    float ui[6];
#pragma unroll
    for (int s1 = 0; s1 < 6; ++s1) ui[s1] = Us[i*6 + s1];

    float mx = -1e30f;
    for (int jj = 0; jj < 64; ++jj) {
        int j = half*64 + jj;
        float a = zj[j];
#pragma unroll
        for (int s1 = 0; s1 < 6; ++s1) a += ui[s1]*Wj[j*6 + s1];
        mx = fmaxf(mx, a * (1.0f/3.0f));
    }
    mx = fmaxf(mx, __shfl_xor(mx, 1));
    float sum = 0.f, o = 0.f;
    for (int jj = 0; jj < 64; ++jj) {
        int j = half*64 + jj;
        float a = zj[j];
#pragma unroll
        for (int s1 = 0; s1 < 6; ++s1) a += ui[s1]*Wj[j*6 + s1];
        float p = expf(a * (1.0f/3.0f) - mx);
        sum += p; o += p*vm[j];
    }
    sum += __shfl_xor(sum, 1);
    o   += __shfl_xor(o, 1);
    if (half == 0) {
        float base = 0.f;
        for (int s1 = 0; s1 < 6; ++s1) base += ui[s1];
        base *= (1.0f/6.0f);
        outp[((size_t)b*128 + i)*10 + 9] = o/sum + base;
    }
}

// ---------------------------------------------------------------------------
extern "C" void kernel_launch(void* const* d_in, const int* in_sizes, int n_in,
                              void* d_out, int out_size, void* d_ws, size_t ws_size,
                              hipStream_t stream)
{
    const float* Y     = (const float*)d_in[0];
    const float* Gin   = (const float*)d_in[1];
    const float* posW1 = (const float*)d_in[2];
    const float* posB1 = (const float*)d_in[3];
    const float* posW2 = (const float*)d_in[4];
    const float* posB2 = (const float*)d_in[5];
    const float* posW3 = (const float*)d_in[6];
    const float* posB3 = (const float*)d_in[7];
    const float* Wq    = (const float*)d_in[8];
    const float* bq    = (const float*)d_in[9];
    const float* Wk    = (const float*)d_in[10];
    const float* bk    = (const float*)d_in[11];
    const float* Wv    = (const float*)d_in[12];
    const float* bv    = (const float*)d_in[13];
    const float* Wo    = (const float*)d_in[14];
    const float* bo    = (const float*)d_in[15];
    const float* lnG   = (const float*)d_in[16];
    const float* lnB   = (const float*)d_in[17];
    const float* fnG   = (const float*)d_in[18];
    const float* fnB   = (const float*)d_in[19];
    const float* poolW = (const float*)d_in[20];
    const float* uQW   = (const float*)d_in[21];
    const float* uQB   = (const float*)d_in[22];
    const float* uKW   = (const float*)d_in[23];
    const float* uKB   = (const float*)d_in[24];
    const float* uVW   = (const float*)d_in[25];
    const float* uVB   = (const float*)d_in[26];
    const float* mQW   = (const float*)d_in[27];
    const float* mQB   = (const float*)d_in[28];
    const float* mKW   = (const float*)d_in[29];
    const float* mKB   = (const float*)d_in[30];
    const float* mVW   = (const float*)d_in[31];
    const float* mVB   = (const float*)d_in[32];

    const size_t xelems = (size_t)F_ * BS_ * 128;     // 4,718,592
    char* p = (char*)d_ws;
    float* xA   = (float*)p;               p += xelems*4;
    float* xB   = (float*)p;               p += xelems*4;
    float* Ubuf = (float*)p;               p += 16384*4;
    unsigned short* xAb = (unsigned short*)p; p += xelems*2;
    unsigned short* Wqb = (unsigned short*)p; p += WELEMS*2;
    unsigned short* Wkb = (unsigned short*)p; p += WELEMS*2;
    unsigned short* Wvb = (unsigned short*)p; p += WELEMS*2;
    unsigned short* Wob = (unsigned short*)p; p += WELEMS*2;
    size_t fixed_bytes = (size_t)(p - (char*)d_ws);

    size_t avail = (ws_size > fixed_bytes) ? (ws_size - fixed_bytes) : 0;
    size_t per_f = 8UL * PERBUF;            // q(2B)+k(2B)+wv(2B)+Vt(2B eff) per elem
    int FC = (int)(avail / per_f);
    if (FC < 1) FC = 1;
    if (FC > F_) FC = F_;

    unsigned short* qb  = (unsigned short*)p;
    unsigned short* kb  = qb + (size_t)FC*PERBUF;
    unsigned short* wvb = kb + (size_t)FC*PERBUF;
    unsigned int*   vtb = (unsigned int*)(wvb + (size_t)FC*PERBUF);

    // Weight conversion to bf16 (once per launch, ~19 MB)
    {
        int n = (int)WELEMS, grid = (n/8 + 255)/256;
        cvt_kernel<<<grid, 256, 0, stream>>>(Wq, Wqb, n);
        cvt_kernel<<<grid, 256, 0, stream>>>(Wk, Wkb, n);
        cvt_kernel<<<grid, 256, 0, stream>>>(Wv, Wvb, n);
        cvt_kernel<<<grid, 256, 0, stream>>>(Wo, Wob, n);
    }

    posnet_kernel<<<dim3(1024, 1, F_), 256, 0, stream>>>(
        Y, Gin, posW1, posB1, posW2, posB2, posW3, posB3, xA, xAb);

    for (int l = 0; l < 2; ++l) {
        for (int f0 = 0; f0 < F_; f0 += FC) {
            int fc = (F_ - f0) < FC ? (F_ - f0) : FC;
            qkv_mfma_kernel<<<dim3(32, 8, 3*fc), 256, 0, stream>>>(
                xAb, Wqb, Wkb, Wvb, bq, bk, bv, qb, kb, vtb, l, f0);
            attn_mfma_kernel<<<dim3(8, 64, fc), 256, 0, stream>>>(qb, kb, vtb, wvb);
            outproj_mfma_kernel<<<dim3(32, 1, fc), 256, 0, stream>>>(
                wvb, Wob, bo, xA, xB, l, f0);
            ln_kernel<<<dim3(fc*1024), 256, 0, stream>>>(
                xB, xA, xAb, lnG + (size_t)(l*F_ + f0)*128, lnB + (size_t)(l*F_ + f0)*128, f0, 128);
        }
    }

    for (int f0 = 0; f0 < F_; f0 += FC) {
        int fc = (F_ - f0) < FC ? (F_ - f0) : FC;
        ln_kernel<<<dim3(fc*1024), 256, 0, stream>>>(xA, xB, xAb, fnG, fnB, f0, 0);
        pool_kernel<<<dim3(fc, 8), 256, 0, stream>>>(xB, poolW, Ubuf, f0);
    }

    unified_kernel<<<dim3(F_, B_), 256, 0, stream>>>(
        Ubuf, uQW, uQB, uKW, uKB, uVW, uVB, (float*)d_out);
    merge_kernel<<<dim3(B_), 256, 0, stream>>>(
        Ubuf, mQW, mQB, mKW, mKB, mVW, mVB, (float*)d_out);
}

// Round 4
// 1769.600 us; speedup vs baseline: 3.4792x; 1.1067x over previous
//
#include <hip/hip_runtime.h>
#include <hip/hip_bf16.h>

// Problem constants
#define F_  9
#define B_  8
#define S_  512
#define H_  8
#define DH_ 128
#define D_  128
#define NB_ 50
#define BS_ 4096            // B_*S_ rows per feature
#define PERBUF 4194304UL    // B_*H_*S_*DH_ elements per feature
#define WELEMS 2359296UL    // 2*9*1024*128 elements per projection weight tensor

typedef short bf16x8 __attribute__((ext_vector_type(8)));
typedef float f32x4  __attribute__((ext_vector_type(4)));

static __device__ __forceinline__ unsigned short f2b(float f) {
    unsigned int u = __float_as_uint(f);
    unsigned int r = (u + 0x7FFFu + ((u >> 16) & 1u)) >> 16;
    return (unsigned short)r;
}
static __device__ __forceinline__ float b2f(unsigned short u) {
    return __uint_as_float(((unsigned int)u) << 16);
}

// ---------------------------------------------------------------------------
// fp32 -> bf16 bulk convert (for projection weights), 8 elems/thread.
// ---------------------------------------------------------------------------
__global__ __launch_bounds__(256) void cvt_kernel(
    const float* __restrict__ in, unsigned short* __restrict__ out, int n)
{
    int i = (blockIdx.x * 256 + threadIdx.x) * 8;
    if (i + 8 <= n) {
        float4 a = *(const float4*)&in[i];
        float4 b = *(const float4*)&in[i + 4];
        ushort4 o0 = { f2b(a.x), f2b(a.y), f2b(a.z), f2b(a.w) };
        ushort4 o1 = { f2b(b.x), f2b(b.y), f2b(b.z), f2b(b.w) };
        *(ushort4*)&out[i]     = o0;
        *(ushort4*)&out[i + 4] = o1;
    }
}

// ---------------------------------------------------------------------------
// Pos-net: one wave per row, activations one-per-lane via shfl.
// Emits fp32 x (for residual) and bf16 x (for MFMA GEMMs).
// ---------------------------------------------------------------------------
__global__ __launch_bounds__(256) void posnet_kernel(
    const float* __restrict__ Y, const float* __restrict__ Gin,
    const float* __restrict__ W1g, const float* __restrict__ B1,
    const float* __restrict__ W2g, const float* __restrict__ B2,
    const float* __restrict__ W3g, const float* __restrict__ B3,
    float* __restrict__ xA, unsigned short* __restrict__ xAb)
{
    __shared__ float w1[50*51];
    __shared__ float w2[50*50];
    __shared__ float w3[128*50];
    __shared__ float b1[64], b2[64], b3[128];
    int f = blockIdx.z;
    int t = threadIdx.x;
    for (int i = t; i < 2550; i += 256) w1[i] = W1g[f*2550 + i];
    for (int i = t; i < 2500; i += 256) w2[i] = W2g[f*2500 + i];
    for (int i = t; i < 6400; i += 256) w3[i] = W3g[f*6400 + i];
    if (t < 50) { b1[t] = B1[f*50 + t]; b2[t] = B2[f*50 + t]; }
    if (t < 128) b3[t] = B3[f*128 + t];
    __syncthreads();

    int lane = t & 63, w = t >> 6;
    int row = blockIdx.x * 4 + w;   // 0..4095

    float gy = 0.f;
    if (lane < 50)       gy = Y[(size_t)row*50 + lane];
    else if (lane == 50) gy = Gin[(size_t)row*F_ + f];

    float a1 = (lane < 50) ? b1[lane] : 0.f;
    for (int kk = 0; kk < 51; ++kk) {
        float g = __shfl(gy, kk);
        if (lane < 50) a1 += w1[lane*51 + kk] * g;
    }
    float h1 = tanhf(a1);

    float a2 = (lane < 50) ? b2[lane] : 0.f;
    for (int kk = 0; kk < 50; ++kk) {
        float hh = __shfl(h1, kk);
        if (lane < 50) a2 += w2[lane*50 + kk] * hh;
    }
    float h2 = tanhf(a2);

    float a30 = b3[lane], a31 = b3[64 + lane];
    for (int kk = 0; kk < 50; ++kk) {
        float hh = __shfl(h2, kk);
        a30 += w3[lane*50 + kk] * hh;
        a31 += w3[(64 + lane)*50 + kk] * hh;
    }
    float s0v = 1.f / (1.f + expf(-a30));
    float s1v = 1.f / (1.f + expf(-a31));
    size_t roff = ((size_t)f*BS_ + row)*128;
    xA[roff + lane]       = s0v;
    xA[roff + 64 + lane]  = s1v;
    xAb[roff + lane]      = f2b(s0v);
    xAb[roff + 64 + lane] = f2b(s1v);
}

// ---------------------------------------------------------------------------
// QKV projection via MFMA: C[4096x1024] = Xb[4096x128] * Wb^T (+bias).
// 128x128 tile, 4 waves (2x2), each wave 64x64 = 4x4 16x16 frags, K=128.
// Fragments read directly from global (L2-resident), no LDS, no barriers.
// which==0/1 -> q/k row-major bf16 [bh][s][dh]; which==2 -> Vt packed u32.
// ---------------------------------------------------------------------------
__global__ __launch_bounds__(256) void qkv_mfma_kernel(
    const unsigned short* __restrict__ xb,
    const unsigned short* __restrict__ Wqb, const unsigned short* __restrict__ Wkb,
    const unsigned short* __restrict__ Wvb,
    const float* __restrict__ bq, const float* __restrict__ bk, const float* __restrict__ bv,
    unsigned short* __restrict__ qo, unsigned short* __restrict__ ko,
    unsigned int* __restrict__ vto, int l, int f0)
{
    int z = blockIdx.z;
    int fl = z / 3, which = z - fl*3;
    int f = f0 + fl;
    const unsigned short* W; const float* bias;
    if (which == 0)      { W = Wqb; bias = bq; }
    else if (which == 1) { W = Wkb; bias = bk; }
    else                 { W = Wvb; bias = bv; }
    W    += (size_t)(l*F_ + f) * 1024 * 128;
    bias += (size_t)(l*F_ + f) * 1024;

    int m0 = blockIdx.x * 128;
    int n0 = blockIdx.y * 128;
    int t = threadIdx.x, w = t >> 6, ln = t & 63, g = ln >> 4, c = ln & 15;
    int wr = w >> 1, wc = w & 1;

    const unsigned short* Ab = xb + ((size_t)f*BS_ + m0 + wr*64)*128;
    const unsigned short* Bb = W + (size_t)(n0 + wc*64)*128;

    f32x4 acc[4][4];
#pragma unroll
    for (int mi = 0; mi < 4; ++mi)
#pragma unroll
        for (int ni = 0; ni < 4; ++ni) acc[mi][ni] = (f32x4){0.f,0.f,0.f,0.f};

#pragma unroll
    for (int kt = 0; kt < 4; ++kt) {
        bf16x8 af[4], bfr[4];
#pragma unroll
        for (int mi = 0; mi < 4; ++mi)
            af[mi] = *(const bf16x8*)&Ab[(size_t)(mi*16 + c)*128 + kt*32 + g*8];
#pragma unroll
        for (int ni = 0; ni < 4; ++ni)
            bfr[ni] = *(const bf16x8*)&Bb[(size_t)(ni*16 + c)*128 + kt*32 + g*8];
#pragma unroll
        for (int mi = 0; mi < 4; ++mi)
#pragma unroll
            for (int ni = 0; ni < 4; ++ni)
                acc[mi][ni] = __builtin_amdgcn_mfma_f32_16x16x32_bf16(af[mi], bfr[ni], acc[mi][ni], 0, 0, 0);
    }

    int h = n0 >> 7;                       // head index (tile spans one head)
    float bs_[4];
#pragma unroll
    for (int ni = 0; ni < 4; ++ni) bs_[ni] = bias[n0 + wc*64 + ni*16 + c];

    if (which < 2) {
        unsigned short* out = (which == 0 ? qo : ko) + (size_t)fl * PERBUF;
#pragma unroll
        for (int mi = 0; mi < 4; ++mi) {
#pragma unroll
            for (int r = 0; r < 4; ++r) {
                int m = m0 + wr*64 + mi*16 + 4*g + r;
                int b = m >> 9, s = m & 511;
                unsigned short* orow = out + (((size_t)(b*H_ + h))*S_ + s)*128;
#pragma unroll
                for (int ni = 0; ni < 4; ++ni)
                    orow[wc*64 + ni*16 + c] = f2b(acc[mi][ni][r] + bs_[ni]);
            }
        }
    } else {
        // Vt[bh][d][s/2] u32: lo = even s, hi = odd s.
        unsigned int* vtf = vto + (size_t)fl * (PERBUF/2);
#pragma unroll
        for (int mi = 0; mi < 4; ++mi) {
            int mbase = m0 + wr*64 + mi*16 + 4*g;      // multiple of 4
            int b = mbase >> 9, sh = (mbase & 511) >> 1;
            unsigned int* vtp = vtf + ((size_t)(b*H_ + h))*32768;
#pragma unroll
            for (int ni = 0; ni < 4; ++ni) {
                int d = wc*64 + ni*16 + c;
                float bb_ = bs_[ni];
                unsigned int p01 = (unsigned int)f2b(acc[mi][ni][0] + bb_)
                                 | ((unsigned int)f2b(acc[mi][ni][1] + bb_) << 16);
                unsigned int p23 = (unsigned int)f2b(acc[mi][ni][2] + bb_)
                                 | ((unsigned int)f2b(acc[mi][ni][3] + bb_) << 16);
                vtp[(size_t)d*256 + sh]     = p01;
                vtp[(size_t)d*256 + sh + 1] = p23;
            }
        }
    }
}

// ---------------------------------------------------------------------------
// MFMA flash attention, XCD-locality version.
// 1-D grid, nwg = 4 q-blocks * 64 heads * fc. Decode:
//   bid = group*32 + i*8 + hl ; hIdx = group*8 + hl ; i0 = i*128
// => all 4 q-blocks of a head share bid%8 (same XCD under round-robin),
//    so K/Vt are fetched from HBM once per head and L2-hit afterwards.
// Block 256 = 4 waves; each wave owns 32 q-rows (2 fragment groups of 16).
// K/V fragments are loaded once and feed both groups (2x reuse).
// ---------------------------------------------------------------------------
__global__ __launch_bounds__(256) void attn_mfma_kernel(
    const unsigned short* __restrict__ q, const unsigned short* __restrict__ k,
    const unsigned int* __restrict__ vt, unsigned short* __restrict__ wv)
{
    int t = threadIdx.x;
    int w = t >> 6, ln = t & 63, g = ln >> 4, c = ln & 15;
    int bid = blockIdx.x;
    int group = bid >> 5, within = bid & 31;
    int i = within >> 3, hl = within & 7;
    int hIdx = group*8 + hl;                 // 0 .. 64*fc-1
    int fl = hIdx >> 6, by = hIdx & 63;
    int i0 = i*128;
    int q0 = i0 + w*32;

    const unsigned short* qh = q + ((size_t)(fl*64 + by))*S_*128;
    const unsigned short* kh = k + ((size_t)(fl*64 + by))*S_*128;
    const unsigned int*  vth = vt + ((size_t)(fl*64 + by))*32768;
    int b = by >> 3, h = by & 7;
    unsigned short* wvh = wv + ((size_t)(fl*B_ + b))*S_*1024 + h*128;

    __shared__ alignas(16) unsigned short Pl[4][32][40];   // per-wave, pitch 80 B

    bf16x8 qf[2][4];
#pragma unroll
    for (int gq = 0; gq < 2; ++gq)
#pragma unroll
        for (int d0 = 0; d0 < 4; ++d0)
            qf[gq][d0] = *(const bf16x8*)&qh[(size_t)(q0 + gq*16 + c)*128 + d0*32 + g*8];

    f32x4 acc[2][8];
#pragma unroll
    for (int gq = 0; gq < 2; ++gq)
#pragma unroll
        for (int i2 = 0; i2 < 8; ++i2) acc[gq][i2] = (f32x4){0.f, 0.f, 0.f, 0.f};
    float mrow[2][4], lrow[2][4];
#pragma unroll
    for (int gq = 0; gq < 2; ++gq)
#pragma unroll
        for (int r = 0; r < 4; ++r) { mrow[gq][r] = -1e30f; lrow[gq][r] = 0.f; }
    const float scale = 0.08838834764831845f;   // 1/sqrt(128)

    for (int kt = 0; kt < 16; ++kt) {
        f32x4 s[2][2];
        s[0][0] = (f32x4){0.f,0.f,0.f,0.f}; s[0][1] = (f32x4){0.f,0.f,0.f,0.f};
        s[1][0] = (f32x4){0.f,0.f,0.f,0.f}; s[1][1] = (f32x4){0.f,0.f,0.f,0.f};
        const unsigned short* kp = &kh[(size_t)(kt*32 + c)*128 + g*8];
#pragma unroll
        for (int d0 = 0; d0 < 4; ++d0) {
            bf16x8 k0 = *(const bf16x8*)(kp + d0*32);
            bf16x8 k1 = *(const bf16x8*)(kp + 16*128 + d0*32);
#pragma unroll
            for (int gq = 0; gq < 2; ++gq) {
                s[gq][0] = __builtin_amdgcn_mfma_f32_16x16x32_bf16(qf[gq][d0], k0, s[gq][0], 0, 0, 0);
                s[gq][1] = __builtin_amdgcn_mfma_f32_16x16x32_bf16(qf[gq][d0], k1, s[gq][1], 0, 0, 0);
            }
        }

        float corr[2][4];
#pragma unroll
        for (int gq = 0; gq < 2; ++gq) {
#pragma unroll
            for (int r = 0; r < 4; ++r) {
                float a0 = s[gq][0][r]*scale, a1 = s[gq][1][r]*scale;
                float tm = fmaxf(a0, a1);
                tm = fmaxf(tm, __shfl_xor(tm, 1));
                tm = fmaxf(tm, __shfl_xor(tm, 2));
                tm = fmaxf(tm, __shfl_xor(tm, 4));
                tm = fmaxf(tm, __shfl_xor(tm, 8));
                float mn = fmaxf(mrow[gq][r], tm);
                corr[gq][r] = __expf(mrow[gq][r] - mn);
                mrow[gq][r] = mn;
                float p0 = __expf(a0 - mn), p1 = __expf(a1 - mn);
                float ps = p0 + p1;
                ps += __shfl_xor(ps, 1);
                ps += __shfl_xor(ps, 2);
                ps += __shfl_xor(ps, 4);
                ps += __shfl_xor(ps, 8);
                lrow[gq][r] = lrow[gq][r]*corr[gq][r] + ps;
                Pl[w][gq*16 + 4*g + r][c]      = f2b(p0);
                Pl[w][gq*16 + 4*g + r][16 + c] = f2b(p1);
            }
#pragma unroll
            for (int i2 = 0; i2 < 8; ++i2) {
                f32x4 a = acc[gq][i2];
                a[0] *= corr[gq][0]; a[1] *= corr[gq][1];
                a[2] *= corr[gq][2]; a[3] *= corr[gq][3];
                acc[gq][i2] = a;
            }
        }

        // PV: pa[gq] from per-wave LDS (DS in-order within wave, no barrier)
        bf16x8 pa[2];
        pa[0] = *(const bf16x8*)&Pl[w][c][g*8];
        pa[1] = *(const bf16x8*)&Pl[w][16 + c][g*8];
        const unsigned int* vp = vth + kt*16 + 4*g;
#pragma unroll
        for (int i2 = 0; i2 < 8; ++i2) {
            bf16x8 vf = *(const bf16x8*)&vp[(size_t)(i2*16 + c)*256];
            acc[0][i2] = __builtin_amdgcn_mfma_f32_16x16x32_bf16(pa[0], vf, acc[0][i2], 0, 0, 0);
            acc[1][i2] = __builtin_amdgcn_mfma_f32_16x16x32_bf16(pa[1], vf, acc[1][i2], 0, 0, 0);
        }
    }

#pragma unroll
    for (int gq = 0; gq < 2; ++gq) {
        float inv[4];
#pragma unroll
        for (int r = 0; r < 4; ++r) inv[r] = 1.0f / lrow[gq][r];
#pragma unroll
        for (int i2 = 0; i2 < 8; ++i2)
#pragma unroll
            for (int r = 0; r < 4; ++r)
                wvh[(size_t)(q0 + gq*16 + 4*g + r)*1024 + i2*16 + c] = f2b(acc[gq][i2][r]*inv[gq == 0 ? r : r]*1.0f) ;
    }
}

// ---------------------------------------------------------------------------
// Out-projection via MFMA + residual: x1 = x0 + wv @ Wo^T + bo (fp32 out).
// M=4096, N=128, K=1024. 128x128 tile, 4 waves (2x2), 4x4 frags/wave.
// ---------------------------------------------------------------------------
__global__ __launch_bounds__(256) void outproj_mfma_kernel(
    const unsigned short* __restrict__ wv, const unsigned short* __restrict__ Wob,
    const float* __restrict__ bo, const float* __restrict__ xin,
    float* __restrict__ xout, int l, int f0)
{
    int fl = blockIdx.z, f = f0 + fl;
    int m0 = blockIdx.x * 128;
    int t = threadIdx.x, w = t >> 6, ln = t & 63, g = ln >> 4, c = ln & 15;
    int wr = w >> 1, wc = w & 1;

    const unsigned short* Ab = wv + ((size_t)fl*BS_ + m0 + wr*64)*1024;
    const unsigned short* Bb = Wob + (size_t)(l*F_ + f)*128*1024 + (size_t)(wc*64)*1024;
    const float* bob = bo + (size_t)(l*F_ + f)*128;

    f32x4 acc[4][4];
#pragma unroll
    for (int mi = 0; mi < 4; ++mi)
#pragma unroll
        for (int ni = 0; ni < 4; ++ni) acc[mi][ni] = (f32x4){0.f,0.f,0.f,0.f};

#pragma unroll 4
    for (int kt = 0; kt < 32; ++kt) {
        bf16x8 af[4], bfr[4];
#pragma unroll
        for (int mi = 0; mi < 4; ++mi)
            af[mi] = *(const bf16x8*)&Ab[(size_t)(mi*16 + c)*1024 + kt*32 + g*8];
#pragma unroll
        for (int ni = 0; ni < 4; ++ni)
            bfr[ni] = *(const bf16x8*)&Bb[(size_t)(ni*16 + c)*1024 + kt*32 + g*8];
#pragma unroll
        for (int mi = 0; mi < 4; ++mi)
#pragma unroll
            for (int ni = 0; ni < 4; ++ni)
                acc[mi][ni] = __builtin_amdgcn_mfma_f32_16x16x32_bf16(af[mi], bfr[ni], acc[mi][ni], 0, 0, 0);
    }

    float bs_[4];
#pragma unroll
    for (int ni = 0; ni < 4; ++ni) bs_[ni] = bob[wc*64 + ni*16 + c];

#pragma unroll
    for (int mi = 0; mi < 4; ++mi) {
#pragma unroll
        for (int r = 0; r < 4; ++r) {
            int m = m0 + wr*64 + mi*16 + 4*g + r;
            const float* xr = xin + ((size_t)f*BS_ + m)*128;
            float* xo = xout + ((size_t)f*BS_ + m)*128;
#pragma unroll
            for (int ni = 0; ni < 4; ++ni) {
                int n = wc*64 + ni*16 + c;
                xo[n] = acc[mi][ni][r] + bs_[ni] + xr[n];
            }
        }
    }
}

// ---------------------------------------------------------------------------
// LayerNorm over last dim (128). One wave per row. Emits fp32 + bf16.
// ---------------------------------------------------------------------------
__global__ __launch_bounds__(256) void ln_kernel(
    const float* __restrict__ xin, float* __restrict__ xout,
    unsigned short* __restrict__ xoutb,
    const float* __restrict__ g, const float* __restrict__ bb, int f0, int gstride)
{
    int t = threadIdx.x, lane = t & 63, w = t >> 6;
    int rowl = blockIdx.x * 4 + w;
    int fl = rowl >> 12;
    size_t row = (size_t)f0*BS_ + rowl;
    const float* xi = xin + row*128;
    float a = xi[lane], c = xi[64 + lane];
    float s = a + c;
#pragma unroll
    for (int off = 1; off < 64; off <<= 1) s += __shfl_xor(s, off);
    float mean = s * (1.0f/128.0f);
    float da = a - mean, dc = c - mean;
    float vs = da*da + dc*dc;
#pragma unroll
    for (int off = 1; off < 64; off <<= 1) vs += __shfl_xor(vs, off);
    float inv = rsqrtf(vs * (1.0f/128.0f) + 1e-5f);
    const float* gp = g + (size_t)fl*gstride;
    const float* bp = bb + (size_t)fl*gstride;
    float o0 = da*inv*gp[lane]      + bp[lane];
    float o1 = dc*inv*gp[64 + lane] + bp[64 + lane];
    float* xo = xout + row*128;
    xo[lane]      = o0;
    xo[64 + lane] = o1;
    xoutb[row*128 + lane]      = f2b(o0);
    xoutb[row*128 + 64 + lane] = f2b(o1);
}

// ---------------------------------------------------------------------------
// Softmax-pool over S (unchanged).
// ---------------------------------------------------------------------------
__global__ __launch_bounds__(256) void pool_kernel(
    const float* __restrict__ xB, const float* __restrict__ poolW,
    float* __restrict__ U, int f0)
{
    int f = f0 + blockIdx.x, b = blockIdx.y;
    const float* xb = xB + ((size_t)f*BS_ + (size_t)b*S_)*128;
    const float* pw = poolW + f*128;
    __shared__ float sc[512];
    __shared__ float red[8];
    __shared__ float MS[2];
    __shared__ float pool2[256];
    int t = threadIdx.x, lane = t & 63, w = t >> 6;

    float p0 = pw[lane], p1 = pw[64 + lane];
    for (int s = w; s < 512; s += 4) {
        float a = xb[(size_t)s*128 + lane]*p0 + xb[(size_t)s*128 + 64 + lane]*p1;
#pragma unroll
        for (int off = 1; off < 64; off <<= 1) a += __shfl_xor(a, off);
        if (lane == 0) sc[s] = a;
    }
    __syncthreads();

    float m = -1e30f;
    for (int s = t; s < 512; s += 256) m = fmaxf(m, sc[s]);
#pragma unroll
    for (int off = 1; off < 64; off <<= 1) m = fmaxf(m, __shfl_xor(m, off));
    if (lane == 0) red[w] = m;
    __syncthreads();
    if (t == 0) MS[0] = fmaxf(fmaxf(red[0], red[1]), fmaxf(red[2], red[3]));
    __syncthreads();
    float M = MS[0];

    float ssum = 0.f;
    for (int s = t; s < 512; s += 256) { float e = expf(sc[s] - M); sc[s] = e; ssum += e; }
#pragma unroll
    for (int off = 1; off < 64; off <<= 1) ssum += __shfl_xor(ssum, off);
    if (lane == 0) red[4 + w] = ssum;
    __syncthreads();
    if (t == 0) MS[1] = red[4] + red[5] + red[6] + red[7];
    __syncthreads();
    float inv = 1.0f / MS[1];

    int d = t & 127, hh = t >> 7;
    float a = 0.f;
    for (int s = hh*256; s < hh*256 + 256; ++s) a += sc[s]*xb[(size_t)s*128 + d];
    pool2[t] = a;
    __syncthreads();
    if (t < 128) U[((size_t)b*128 + d)*F_ + f] = (pool2[t] + pool2[t + 128]) * inv;
}

// ---------------------------------------------------------------------------
// Unified attention per (f,b) (unchanged).
// ---------------------------------------------------------------------------
__global__ __launch_bounds__(256) void unified_kernel(
    const float* __restrict__ U,
    const float* __restrict__ uQW, const float* __restrict__ uQB,
    const float* __restrict__ uKW, const float* __restrict__ uKB,
    const float* __restrict__ uVW, const float* __restrict__ uVB,
    float* __restrict__ outp)
{
    int f = blockIdx.x, b = blockIdx.y;
    __shared__ float Ub[128*9];
    __shared__ float Wj[128*9];
    __shared__ float zj[128];
    __shared__ float vm[128];
    __shared__ float Mm[81];
    __shared__ float wvm[9], bvec[9];
    __shared__ float cc_[2];
    int t = threadIdx.x;
    for (int i = t; i < 1152; i += 256) Ub[i] = U[(size_t)b*1152 + i];
    const float* qw = uQW + (size_t)f*1152;
    const float* kw = uKW + (size_t)f*1152;
    const float* vw = uVW + (size_t)f*1152;
    const float* qb = uQB + (size_t)f*128;
    const float* kb = uKB + (size_t)f*128;
    const float* vb = uVB + (size_t)f*128;

    if (t < 81) {
        int t1 = t/9, s1 = t%9; float a = 0.f;
        for (int kk = 0; kk < 128; ++kk) a += qw[kk*9 + t1]*kw[kk*9 + s1];
        Mm[t] = a;
    } else if (t < 90) {
        int s1 = t - 81; float a = 0.f;
        for (int kk = 0; kk < 128; ++kk) a += kw[kk*9 + s1]*qb[kk];
        bvec[s1] = a;
    } else if (t < 99) {
        int t1 = t - 90; float a = 0.f;
        for (int kk = 0; kk < 128; ++kk) a += vw[kk*9 + t1];
        wvm[t1] = a * (1.0f/128.0f);
    } else if (t == 99) {
        float a = 0.f, c2 = 0.f;
        for (int kk = 0; kk < 128; ++kk) { a += qb[kk]*kb[kk]; c2 += vb[kk]; }
        cc_[0] = a; cc_[1] = c2 * (1.0f/128.0f);
    }
    __syncthreads();

    if (t < 128) {
        int j = t;
        for (int t1 = 0; t1 < 9; ++t1) {
            float a = 0.f;
            for (int s1 = 0; s1 < 9; ++s1) a += Mm[t1*9 + s1]*Ub[j*9 + s1];
            Wj[j*9 + t1] = a;
        }
        float z = cc_[0], v2 = cc_[1];
        for (int s1 = 0; s1 < 9; ++s1) { z += bvec[s1]*Ub[j*9 + s1]; v2 += wvm[s1]*Ub[j*9 + s1]; }
        zj[j] = z; vm[j] = v2;
    }
    __syncthreads();

    int i = t >> 1, half = t & 1;
    float ui[9];
#pragma unroll
    for (int s1 = 0; s1 < 9; ++s1) ui[s1] = Ub[i*9 + s1];

    float mx = -1e30f;
    for (int jj = 0; jj < 64; ++jj) {
        int j = half*64 + jj;
        float a = zj[j];
#pragma unroll
        for (int s1 = 0; s1 < 9; ++s1) a += ui[s1]*Wj[j*9 + s1];
        mx = fmaxf(mx, a * (1.0f/3.0f));
    }
    mx = fmaxf(mx, __shfl_xor(mx, 1));
    float sum = 0.f, o = 0.f;
    for (int jj = 0; jj < 64; ++jj) {
        int j = half*64 + jj;
        float a = zj[j];
#pragma unroll
        for (int s1 = 0; s1 < 9; ++s1) a += ui[s1]*Wj[j*9 + s1];
        float p = expf(a * (1.0f/3.0f) - mx);
        sum += p; o += p*vm[j];
    }
    sum += __shfl_xor(sum, 1);
    o   += __shfl_xor(o, 1);
    if (half == 0) {
        float base;
        if (f > 0) base = ui[f];
        else { base = 0.f; for (int s1 = 0; s1 < 9; ++s1) base += ui[s1]; base *= (1.0f/9.0f); }
        outp[((size_t)b*128 + i)*10 + f] = o/sum + base;
    }
}

// ---------------------------------------------------------------------------
// Merge attention (features 3..8), writes output column 9 (unchanged).
// ---------------------------------------------------------------------------
__global__ __launch_bounds__(256) void merge_kernel(
    const float* __restrict__ U,
    const float* __restrict__ mQW, const float* __restrict__ mQB,
    const float* __restrict__ mKW, const float* __restrict__ mKB,
    const float* __restrict__ mVW, const float* __restrict__ mVB,
    float* __restrict__ outp)
{
    int b = blockIdx.x;
    __shared__ float Us[128*6];
    __shared__ float Wj[128*6];
    __shared__ float zj[128];
    __shared__ float vm[128];
    __shared__ float Mm[36];
    __shared__ float wvm[6], bvec[6];
    __shared__ float cc_[2];
    int t = threadIdx.x;
    for (int i = t; i < 768; i += 256) {
        int j = i/6, tt = i - j*6;
        Us[i] = U[(size_t)b*1152 + j*9 + 3 + tt];
    }
    if (t < 36) {
        int t1 = t/6, s1 = t%6; float a = 0.f;
        for (int kk = 0; kk < 128; ++kk) a += mQW[kk*6 + t1]*mKW[kk*6 + s1];
        Mm[t] = a;
    } else if (t < 42) {
        int s1 = t - 36; float a = 0.f;
        for (int kk = 0; kk < 128; ++kk) a += mKW[kk*6 + s1]*mQB[kk];
        bvec[s1] = a;
    } else if (t < 48) {
        int t1 = t - 42; float a = 0.f;
        for (int kk = 0; kk < 128; ++kk) a += mVW[kk*6 + t1];
        wvm[t1] = a * (1.0f/128.0f);
    } else if (t == 48) {
        float a = 0.f, c2 = 0.f;
        for (int kk = 0; kk < 128; ++kk) { a += mQB[kk]*mKB[kk]; c2 += mVB[kk]; }
        cc_[0] = a; cc_[1] = c2 * (1.0f/128.0f);
    }
    __syncthreads();

    if (t < 128) {
        int j = t;
        for (int t1 = 0; t1 < 6; ++t1) {
            float a = 0.f;
            for (int s1 = 0; s1 < 6; ++s1) a += Mm[t1*6 + s1]*Us[j*6 + s1];
            Wj[j*6 + t1] = a;
        }
        float z = cc_[0], v2 = cc_[1];
        for (int s1 = 0; s1 < 6; ++s1) { z += bvec[s1]*Us[j*6 + s1]; v2 += wvm[s1]*Us[j*6 + s1]; }
        zj[j] = z; vm[j] = v2;
    }
    __syncthreads();

    int i = t >> 1, half = t & 1;
    float ui[6];
#pragma unroll
    for (int s1 = 0; s1 < 6; ++s1) ui[s1] = Us[i*6 + s1];

    float mx = -1e30f;
    for (int jj = 0; jj < 64; ++jj) {
        int j = half*64 + jj;
        float a = zj[j];
#pragma unroll
        for (int s1 = 0; s1 < 6; ++s1) a += ui[s1]*Wj[j*6 + s1];
        mx = fmaxf(mx, a * (1.0f/3.0f));
    }
    mx = fmaxf(mx, __shfl_xor(mx, 1));
    float sum = 0.f, o = 0.f;
    for (int jj = 0; jj < 64; ++jj) {
        int j = half*64 + jj;
        float a = zj[j];
#pragma unroll
        for (int s1 = 0; s1 < 6; ++s1) a += ui[s1]*Wj[j*6 + s1];
        float p = expf(a * (1.0f/3.0f) - mx);
        sum += p; o += p*vm[j];
    }
    sum += __shfl_xor(sum, 1);
    o   += __shfl_xor(o, 1);
    if (half == 0) {
        float base = 0.f;
        for (int s1 = 0; s1 < 6; ++s1) base += ui[s1];
        base *= (1.0f/6.0f);
        outp[((size_t)b*128 + i)*10 + 9] = o/sum + base;
    }
}

// ---------------------------------------------------------------------------
extern "C" void kernel_launch(void* const* d_in, const int* in_sizes, int n_in,
                              void* d_out, int out_size, void* d_ws, size_t ws_size,
                              hipStream_t stream)
{
    const float* Y     = (const float*)d_in[0];
    const float* Gin   = (const float*)d_in[1];
    const float* posW1 = (const float*)d_in[2];
    const float* posB1 = (const float*)d_in[3];
    const float* posW2 = (const float*)d_in[4];
    const float* posB2 = (const float*)d_in[5];
    const float* posW3 = (const float*)d_in[6];
    const float* posB3 = (const float*)d_in[7];
    const float* Wq    = (const float*)d_in[8];
    const float* bq    = (const float*)d_in[9];
    const float* Wk    = (const float*)d_in[10];
    const float* bk    = (const float*)d_in[11];
    const float* Wv    = (const float*)d_in[12];
    const float* bv    = (const float*)d_in[13];
    const float* Wo    = (const float*)d_in[14];
    const float* bo    = (const float*)d_in[15];
    const float* lnG   = (const float*)d_in[16];
    const float* lnB   = (const float*)d_in[17];
    const float* fnG   = (const float*)d_in[18];
    const float* fnB   = (const float*)d_in[19];
    const float* poolW = (const float*)d_in[20];
    const float* uQW   = (const float*)d_in[21];
    const float* uQB   = (const float*)d_in[22];
    const float* uKW   = (const float*)d_in[23];
    const float* uKB   = (const float*)d_in[24];
    const float* uVW   = (const float*)d_in[25];
    const float* uVB   = (const float*)d_in[26];
    const float* mQW   = (const float*)d_in[27];
    const float* mQB   = (const float*)d_in[28];
    const float* mKW   = (const float*)d_in[29];
    const float* mKB   = (const float*)d_in[30];
    const float* mVW   = (const float*)d_in[31];
    const float* mVB   = (const float*)d_in[32];

    const size_t xelems = (size_t)F_ * BS_ * 128;     // 4,718,592
    char* p = (char*)d_ws;
    float* xA   = (float*)p;               p += xelems*4;
    float* xB   = (float*)p;               p += xelems*4;
    float* Ubuf = (float*)p;               p += 16384*4;
    unsigned short* xAb = (unsigned short*)p; p += xelems*2;
    unsigned short* Wqb = (unsigned short*)p; p += WELEMS*2;
    unsigned short* Wkb = (unsigned short*)p; p += WELEMS*2;
    unsigned short* Wvb = (unsigned short*)p; p += WELEMS*2;
    unsigned short* Wob = (unsigned short*)p; p += WELEMS*2;
    size_t fixed_bytes = (size_t)(p - (char*)d_ws);

    size_t avail = (ws_size > fixed_bytes) ? (ws_size - fixed_bytes) : 0;
    size_t per_f = 8UL * PERBUF;            // q(2B)+k(2B)+wv(2B)+Vt(2B eff) per elem
    int FC = (int)(avail / per_f);
    if (FC < 1) FC = 1;
    if (FC > F_) FC = F_;

    unsigned short* qb  = (unsigned short*)p;
    unsigned short* kb  = qb + (size_t)FC*PERBUF;
    unsigned short* wvb = kb + (size_t)FC*PERBUF;
    unsigned int*   vtb = (unsigned int*)(wvb + (size_t)FC*PERBUF);

    // Weight conversion to bf16 (once per launch, ~19 MB)
    {
        int n = (int)WELEMS, grid = (n/8 + 255)/256;
        cvt_kernel<<<grid, 256, 0, stream>>>(Wq, Wqb, n);
        cvt_kernel<<<grid, 256, 0, stream>>>(Wk, Wkb, n);
        cvt_kernel<<<grid, 256, 0, stream>>>(Wv, Wvb, n);
        cvt_kernel<<<grid, 256, 0, stream>>>(Wo, Wob, n);
    }

    posnet_kernel<<<dim3(1024, 1, F_), 256, 0, stream>>>(
        Y, Gin, posW1, posB1, posW2, posB2, posW3, posB3, xA, xAb);

    for (int l = 0; l < 2; ++l) {
        for (int f0 = 0; f0 < F_; f0 += FC) {
            int fc = (F_ - f0) < FC ? (F_ - f0) : FC;
            qkv_mfma_kernel<<<dim3(32, 8, 3*fc), 256, 0, stream>>>(
                xAb, Wqb, Wkb, Wvb, bq, bk, bv, qb, kb, vtb, l, f0);
            attn_mfma_kernel<<<dim3(256*fc), 256, 0, stream>>>(qb, kb, vtb, wvb);
            outproj_mfma_kernel<<<dim3(32, 1, fc), 256, 0, stream>>>(
                wvb, Wob, bo, xA, xB, l, f0);
            ln_kernel<<<dim3(fc*1024), 256, 0, stream>>>(
                xB, xA, xAb, lnG + (size_t)(l*F_ + f0)*128, lnB + (size_t)(l*F_ + f0)*128, f0, 128);
        }
    }

    for (int f0 = 0; f0 < F_; f0 += FC) {
        int fc = (F_ - f0) < FC ? (F_ - f0) : FC;
        ln_kernel<<<dim3(fc*1024), 256, 0, stream>>>(xA, xB, xAb, fnG, fnB, f0, 0);
        pool_kernel<<<dim3(fc, 8), 256, 0, stream>>>(xB, poolW, Ubuf, f0);
    }

    unified_kernel<<<dim3(F_, B_), 256, 0, stream>>>(
        Ubuf, uQW, uQB, uKW, uKB, uVW, uVB, (float*)d_out);
    merge_kernel<<<dim3(B_), 256, 0, stream>>>(
        Ubuf, mQW, mQB, mKW, mKB, mVW, mVB, (float*)d_out);
}

// Round 5
// 1509.847 us; speedup vs baseline: 4.0778x; 1.1720x over previous
//
#include <hip/hip_runtime.h>
#include <hip/hip_bf16.h>

// Problem constants
#define F_  9
#define B_  8
#define S_  512
#define H_  8
#define DH_ 128
#define D_  128
#define NB_ 50
#define BS_ 4096            // B_*S_ rows per feature
#define PERBUF 4194304UL    // B_*H_*S_*DH_ elements per feature
#define WELEMS 2359296UL    // 2*9*1024*128 elements per projection weight tensor

typedef short bf16x8 __attribute__((ext_vector_type(8)));
typedef float f32x4  __attribute__((ext_vector_type(4)));

static __device__ __forceinline__ unsigned short f2b(float f) {
    unsigned int u = __float_as_uint(f);
    unsigned int r = (u + 0x7FFFu + ((u >> 16) & 1u)) >> 16;
    return (unsigned short)r;
}
static __device__ __forceinline__ float b2f(unsigned short u) {
    return __uint_as_float(((unsigned int)u) << 16);
}

// ---------------------------------------------------------------------------
// fp32 -> bf16 bulk convert (for projection weights), 8 elems/thread.
// ---------------------------------------------------------------------------
__global__ __launch_bounds__(256) void cvt_kernel(
    const float* __restrict__ in, unsigned short* __restrict__ out, int n)
{
    int i = (blockIdx.x * 256 + threadIdx.x) * 8;
    if (i + 8 <= n) {
        float4 a = *(const float4*)&in[i];
        float4 b = *(const float4*)&in[i + 4];
        ushort4 o0 = { f2b(a.x), f2b(a.y), f2b(a.z), f2b(a.w) };
        ushort4 o1 = { f2b(b.x), f2b(b.y), f2b(b.z), f2b(b.w) };
        *(ushort4*)&out[i]     = o0;
        *(ushort4*)&out[i + 4] = o1;
    }
}

// ---------------------------------------------------------------------------
// Pos-net: one wave per row; emits fp32 x (residual) and bf16 x (MFMA).
// ---------------------------------------------------------------------------
__global__ __launch_bounds__(256) void posnet_kernel(
    const float* __restrict__ Y, const float* __restrict__ Gin,
    const float* __restrict__ W1g, const float* __restrict__ B1,
    const float* __restrict__ W2g, const float* __restrict__ B2,
    const float* __restrict__ W3g, const float* __restrict__ B3,
    float* __restrict__ xA, unsigned short* __restrict__ xAb)
{
    __shared__ float w1[50*51];
    __shared__ float w2[50*50];
    __shared__ float w3[128*50];
    __shared__ float b1[64], b2[64], b3[128];
    int f = blockIdx.z;
    int t = threadIdx.x;
    for (int i = t; i < 2550; i += 256) w1[i] = W1g[f*2550 + i];
    for (int i = t; i < 2500; i += 256) w2[i] = W2g[f*2500 + i];
    for (int i = t; i < 6400; i += 256) w3[i] = W3g[f*6400 + i];
    if (t < 50) { b1[t] = B1[f*50 + t]; b2[t] = B2[f*50 + t]; }
    if (t < 128) b3[t] = B3[f*128 + t];
    __syncthreads();

    int lane = t & 63, w = t >> 6;
    int row = blockIdx.x * 4 + w;   // 0..4095

    float gy = 0.f;
    if (lane < 50)       gy = Y[(size_t)row*50 + lane];
    else if (lane == 50) gy = Gin[(size_t)row*F_ + f];

    float a1 = (lane < 50) ? b1[lane] : 0.f;
    for (int kk = 0; kk < 51; ++kk) {
        float g = __shfl(gy, kk);
        if (lane < 50) a1 += w1[lane*51 + kk] * g;
    }
    float h1 = tanhf(a1);

    float a2 = (lane < 50) ? b2[lane] : 0.f;
    for (int kk = 0; kk < 50; ++kk) {
        float hh = __shfl(h1, kk);
        if (lane < 50) a2 += w2[lane*50 + kk] * hh;
    }
    float h2 = tanhf(a2);

    float a30 = b3[lane], a31 = b3[64 + lane];
    for (int kk = 0; kk < 50; ++kk) {
        float hh = __shfl(h2, kk);
        a30 += w3[lane*50 + kk] * hh;
        a31 += w3[(64 + lane)*50 + kk] * hh;
    }
    float s0v = 1.f / (1.f + expf(-a30));
    float s1v = 1.f / (1.f + expf(-a31));
    size_t roff = ((size_t)f*BS_ + row)*128;
    xA[roff + lane]       = s0v;
    xA[roff + 64 + lane]  = s1v;
    xAb[roff + lane]      = f2b(s0v);
    xAb[roff + 64 + lane] = f2b(s1v);
}

// ---------------------------------------------------------------------------
// QKV projection via MFMA. q output is PRE-SCALED by 1/sqrt(128).
// which==0/1 -> q/k row-major bf16 [bh][s][dh]; which==2 -> Vt packed u32.
// ---------------------------------------------------------------------------
__global__ __launch_bounds__(256) void qkv_mfma_kernel(
    const unsigned short* __restrict__ xb,
    const unsigned short* __restrict__ Wqb, const unsigned short* __restrict__ Wkb,
    const unsigned short* __restrict__ Wvb,
    const float* __restrict__ bq, const float* __restrict__ bk, const float* __restrict__ bv,
    unsigned short* __restrict__ qo, unsigned short* __restrict__ ko,
    unsigned int* __restrict__ vto, int l, int f0)
{
    int z = blockIdx.z;
    int fl = z / 3, which = z - fl*3;
    int f = f0 + fl;
    const unsigned short* W; const float* bias;
    if (which == 0)      { W = Wqb; bias = bq; }
    else if (which == 1) { W = Wkb; bias = bk; }
    else                 { W = Wvb; bias = bv; }
    W    += (size_t)(l*F_ + f) * 1024 * 128;
    bias += (size_t)(l*F_ + f) * 1024;

    int m0 = blockIdx.x * 128;
    int n0 = blockIdx.y * 128;
    int t = threadIdx.x, w = t >> 6, ln = t & 63, g = ln >> 4, c = ln & 15;
    int wr = w >> 1, wc = w & 1;

    const unsigned short* Ab = xb + ((size_t)f*BS_ + m0 + wr*64)*128;
    const unsigned short* Bb = W + (size_t)(n0 + wc*64)*128;

    f32x4 acc[4][4];
#pragma unroll
    for (int mi = 0; mi < 4; ++mi)
#pragma unroll
        for (int ni = 0; ni < 4; ++ni) acc[mi][ni] = (f32x4){0.f,0.f,0.f,0.f};

#pragma unroll
    for (int kt = 0; kt < 4; ++kt) {
        bf16x8 af[4], bfr[4];
#pragma unroll
        for (int mi = 0; mi < 4; ++mi)
            af[mi] = *(const bf16x8*)&Ab[(size_t)(mi*16 + c)*128 + kt*32 + g*8];
#pragma unroll
        for (int ni = 0; ni < 4; ++ni)
            bfr[ni] = *(const bf16x8*)&Bb[(size_t)(ni*16 + c)*128 + kt*32 + g*8];
#pragma unroll
        for (int mi = 0; mi < 4; ++mi)
#pragma unroll
            for (int ni = 0; ni < 4; ++ni)
                acc[mi][ni] = __builtin_amdgcn_mfma_f32_16x16x32_bf16(af[mi], bfr[ni], acc[mi][ni], 0, 0, 0);
    }

    int h = n0 >> 7;
    float bs_[4];
#pragma unroll
    for (int ni = 0; ni < 4; ++ni) bs_[ni] = bias[n0 + wc*64 + ni*16 + c];

    if (which < 2) {
        float qscale = (which == 0) ? 0.08838834764831845f : 1.0f;
        unsigned short* out = (which == 0 ? qo : ko) + (size_t)fl * PERBUF;
#pragma unroll
        for (int mi = 0; mi < 4; ++mi) {
#pragma unroll
            for (int r = 0; r < 4; ++r) {
                int m = m0 + wr*64 + mi*16 + 4*g + r;
                int b = m >> 9, s = m & 511;
                unsigned short* orow = out + (((size_t)(b*H_ + h))*S_ + s)*128;
#pragma unroll
                for (int ni = 0; ni < 4; ++ni)
                    orow[wc*64 + ni*16 + c] = f2b((acc[mi][ni][r] + bs_[ni]) * qscale);
            }
        }
    } else {
        // Vt[bh][d][s/2] u32: lo = even s, hi = odd s.
        unsigned int* vtf = vto + (size_t)fl * (PERBUF/2);
#pragma unroll
        for (int mi = 0; mi < 4; ++mi) {
            int mbase = m0 + wr*64 + mi*16 + 4*g;      // multiple of 4
            int b = mbase >> 9, sh = (mbase & 511) >> 1;
            unsigned int* vtp = vtf + ((size_t)(b*H_ + h))*32768;
#pragma unroll
            for (int ni = 0; ni < 4; ++ni) {
                int d = wc*64 + ni*16 + c;
                float bb_ = bs_[ni];
                unsigned int p01 = (unsigned int)f2b(acc[mi][ni][0] + bb_)
                                 | ((unsigned int)f2b(acc[mi][ni][1] + bb_) << 16);
                unsigned int p23 = (unsigned int)f2b(acc[mi][ni][2] + bb_)
                                 | ((unsigned int)f2b(acc[mi][ni][3] + bb_) << 16);
                vtp[(size_t)d*256 + sh]     = p01;
                vtp[(size_t)d*256 + sh + 1] = p23;
            }
        }
    }
}

// ---------------------------------------------------------------------------
// MFMA flash attention, LDS-staged + double-buffered pipeline.
// Grid/swizzle as round 4 (4 q-blocks/head grouped per XCD).
// Per kt-tile (32 keys): K tile (32x128 bf16, pitch 136) and Vt tile
// (128x16 u32, pitch 20) staged in LDS by all 256 threads; global loads for
// tile kt+1 issued BEFORE compute(kt) (T14), ds_write after barrier.
// q arrives pre-scaled by 1/sqrt(128). Defer-max (THR=8) skips acc rescale.
// ---------------------------------------------------------------------------
__global__ __launch_bounds__(256) void attn_mfma_kernel(
    const unsigned short* __restrict__ q, const unsigned short* __restrict__ k,
    const unsigned int* __restrict__ vt, unsigned short* __restrict__ wv)
{
    int t = threadIdx.x;
    int w = t >> 6, ln = t & 63, g = ln >> 4, c = ln & 15;
    int bid = blockIdx.x;
    int group = bid >> 5, within = bid & 31;
    int i = within >> 3, hl = within & 7;
    int hIdx = group*8 + hl;                 // 0 .. 64*fc-1
    int fl = hIdx >> 6, by = hIdx & 63;
    int q0 = i*128 + w*32;

    const unsigned short* qh = q + ((size_t)(fl*64 + by))*S_*128;
    const unsigned short* kh = k + ((size_t)(fl*64 + by))*S_*128;
    const unsigned int*  vth = vt + ((size_t)(fl*64 + by))*32768;
    int b = by >> 3, h = by & 7;
    unsigned short* wvh = wv + ((size_t)(fl*B_ + b))*S_*1024 + h*128;

    __shared__ alignas(16) unsigned short Ks[2][32][136];  // 17408 B
    __shared__ alignas(16) unsigned int   Vs[2][128][20];  // 20480 B
    __shared__ alignas(16) unsigned short Pl[4][32][40];   // 10240 B

    // staging index split (256 threads)
    int krow = t >> 4, kseg = t & 15;   // K rows krow, krow+16 ; 16B segs
    int vrow = t >> 2, vseg = t & 3;    // V rows vrow, vrow+64 ; 16B segs

    bf16x8 qf[2][4];
#pragma unroll
    for (int gq = 0; gq < 2; ++gq)
#pragma unroll
        for (int d0 = 0; d0 < 4; ++d0)
            qf[gq][d0] = *(const bf16x8*)&qh[(size_t)(q0 + gq*16 + c)*128 + d0*32 + g*8];

    f32x4 acc[2][8];
#pragma unroll
    for (int gq = 0; gq < 2; ++gq)
#pragma unroll
        for (int i2 = 0; i2 < 8; ++i2) acc[gq][i2] = (f32x4){0.f, 0.f, 0.f, 0.f};
    float mrow[2][4], lrow[2][4];
#pragma unroll
    for (int gq = 0; gq < 2; ++gq)
#pragma unroll
        for (int r = 0; r < 4; ++r) { mrow[gq][r] = -1e30f; lrow[gq][r] = 0.f; }

    uint4 kr0, kr1, vr0, vr1;
    // prologue: tile 0 -> buf 0
    {
        kr0 = *(const uint4*)&kh[(size_t)krow*128 + kseg*8];
        kr1 = *(const uint4*)&kh[(size_t)(krow + 16)*128 + kseg*8];
        vr0 = *(const uint4*)&vth[(size_t)vrow*256 + vseg*4];
        vr1 = *(const uint4*)&vth[(size_t)(vrow + 64)*256 + vseg*4];
        *(uint4*)&Ks[0][krow][kseg*8]      = kr0;
        *(uint4*)&Ks[0][krow + 16][kseg*8] = kr1;
        *(uint4*)&Vs[0][vrow][vseg*4]      = vr0;
        *(uint4*)&Vs[0][vrow + 64][vseg*4] = vr1;
    }
    __syncthreads();

    int cur = 0;
    for (int kt = 0; kt < 16; ++kt) {
        if (kt < 15) {
            const unsigned short* ks = kh + (size_t)(kt + 1)*32*128;
            const unsigned int*  vsp = vth + (kt + 1)*16;
            kr0 = *(const uint4*)&ks[(size_t)krow*128 + kseg*8];
            kr1 = *(const uint4*)&ks[(size_t)(krow + 16)*128 + kseg*8];
            vr0 = *(const uint4*)&vsp[(size_t)vrow*256 + vseg*4];
            vr1 = *(const uint4*)&vsp[(size_t)(vrow + 64)*256 + vseg*4];
        }

        // QK^T from LDS
        f32x4 s[2][2];
        s[0][0] = (f32x4){0.f,0.f,0.f,0.f}; s[0][1] = (f32x4){0.f,0.f,0.f,0.f};
        s[1][0] = (f32x4){0.f,0.f,0.f,0.f}; s[1][1] = (f32x4){0.f,0.f,0.f,0.f};
        __builtin_amdgcn_s_setprio(1);
#pragma unroll
        for (int d0 = 0; d0 < 4; ++d0) {
            bf16x8 k0 = *(const bf16x8*)&Ks[cur][c][g*8 + d0*32];
            bf16x8 k1 = *(const bf16x8*)&Ks[cur][16 + c][g*8 + d0*32];
#pragma unroll
            for (int gq = 0; gq < 2; ++gq) {
                s[gq][0] = __builtin_amdgcn_mfma_f32_16x16x32_bf16(qf[gq][d0], k0, s[gq][0], 0, 0, 0);
                s[gq][1] = __builtin_amdgcn_mfma_f32_16x16x32_bf16(qf[gq][d0], k1, s[gq][1], 0, 0, 0);
            }
        }
        __builtin_amdgcn_s_setprio(0);

        // online softmax with defer-max (THR=8)
        float corr[2][4];
        bool need = false;
#pragma unroll
        for (int gq = 0; gq < 2; ++gq) {
#pragma unroll
            for (int r = 0; r < 4; ++r) {
                float a0 = s[gq][0][r], a1 = s[gq][1][r];
                float tm = fmaxf(a0, a1);
                tm = fmaxf(tm, __shfl_xor(tm, 1));
                tm = fmaxf(tm, __shfl_xor(tm, 2));
                tm = fmaxf(tm, __shfl_xor(tm, 4));
                tm = fmaxf(tm, __shfl_xor(tm, 8));
                float mo = mrow[gq][r];
                float mn = (tm > mo + 8.f) ? tm : mo;
                float co = __expf(mo - mn);
                corr[gq][r] = co;
                mrow[gq][r] = mn;
                float p0 = __expf(a0 - mn), p1 = __expf(a1 - mn);
                float ps = p0 + p1;
                ps += __shfl_xor(ps, 1);
                ps += __shfl_xor(ps, 2);
                ps += __shfl_xor(ps, 4);
                ps += __shfl_xor(ps, 8);
                lrow[gq][r] = lrow[gq][r]*co + ps;
                Pl[w][gq*16 + 4*g + r][c]      = f2b(p0);
                Pl[w][gq*16 + 4*g + r][16 + c] = f2b(p1);
                need = need || (co != 1.0f);
            }
        }
        if (__any(need)) {
#pragma unroll
            for (int gq = 0; gq < 2; ++gq)
#pragma unroll
                for (int i2 = 0; i2 < 8; ++i2) {
                    f32x4 a = acc[gq][i2];
                    a[0] *= corr[gq][0]; a[1] *= corr[gq][1];
                    a[2] *= corr[gq][2]; a[3] *= corr[gq][3];
                    acc[gq][i2] = a;
                }
        }

        // PV (per-wave P bounce; DS in-order within wave)
        bf16x8 pa[2];
        pa[0] = *(const bf16x8*)&Pl[w][c][g*8];
        pa[1] = *(const bf16x8*)&Pl[w][16 + c][g*8];
        __builtin_amdgcn_s_setprio(1);
#pragma unroll
        for (int i2 = 0; i2 < 8; ++i2) {
            bf16x8 vf = *(const bf16x8*)&Vs[cur][i2*16 + c][g*4];
            acc[0][i2] = __builtin_amdgcn_mfma_f32_16x16x32_bf16(pa[0], vf, acc[0][i2], 0, 0, 0);
            acc[1][i2] = __builtin_amdgcn_mfma_f32_16x16x32_bf16(pa[1], vf, acc[1][i2], 0, 0, 0);
        }
        __builtin_amdgcn_s_setprio(0);

        if (kt < 15) {
            __syncthreads();
            int nxt = cur ^ 1;
            *(uint4*)&Ks[nxt][krow][kseg*8]      = kr0;
            *(uint4*)&Ks[nxt][krow + 16][kseg*8] = kr1;
            *(uint4*)&Vs[nxt][vrow][vseg*4]      = vr0;
            *(uint4*)&Vs[nxt][vrow + 64][vseg*4] = vr1;
            __syncthreads();
            cur = nxt;
        }
    }

#pragma unroll
    for (int gq = 0; gq < 2; ++gq) {
        float inv[4];
#pragma unroll
        for (int r = 0; r < 4; ++r) inv[r] = 1.0f / lrow[gq][r];
#pragma unroll
        for (int i2 = 0; i2 < 8; ++i2)
#pragma unroll
            for (int r = 0; r < 4; ++r)
                wvh[(size_t)(q0 + gq*16 + 4*g + r)*1024 + i2*16 + c] = f2b(acc[gq][i2][r]*inv[r]);
    }
}

// ---------------------------------------------------------------------------
// Out-projection via MFMA + residual: x1 = x0 + wv @ Wo^T + bo (fp32 out).
// ---------------------------------------------------------------------------
__global__ __launch_bounds__(256) void outproj_mfma_kernel(
    const unsigned short* __restrict__ wv, const unsigned short* __restrict__ Wob,
    const float* __restrict__ bo, const float* __restrict__ xin,
    float* __restrict__ xout, int l, int f0)
{
    int fl = blockIdx.z, f = f0 + fl;
    int m0 = blockIdx.x * 128;
    int t = threadIdx.x, w = t >> 6, ln = t & 63, g = ln >> 4, c = ln & 15;
    int wr = w >> 1, wc = w & 1;

    const unsigned short* Ab = wv + ((size_t)fl*BS_ + m0 + wr*64)*1024;
    const unsigned short* Bb = Wob + (size_t)(l*F_ + f)*128*1024 + (size_t)(wc*64)*1024;
    const float* bob = bo + (size_t)(l*F_ + f)*128;

    f32x4 acc[4][4];
#pragma unroll
    for (int mi = 0; mi < 4; ++mi)
#pragma unroll
        for (int ni = 0; ni < 4; ++ni) acc[mi][ni] = (f32x4){0.f,0.f,0.f,0.f};

#pragma unroll 4
    for (int kt = 0; kt < 32; ++kt) {
        bf16x8 af[4], bfr[4];
#pragma unroll
        for (int mi = 0; mi < 4; ++mi)
            af[mi] = *(const bf16x8*)&Ab[(size_t)(mi*16 + c)*1024 + kt*32 + g*8];
#pragma unroll
        for (int ni = 0; ni < 4; ++ni)
            bfr[ni] = *(const bf16x8*)&Bb[(size_t)(ni*16 + c)*1024 + kt*32 + g*8];
#pragma unroll
        for (int mi = 0; mi < 4; ++mi)
#pragma unroll
            for (int ni = 0; ni < 4; ++ni)
                acc[mi][ni] = __builtin_amdgcn_mfma_f32_16x16x32_bf16(af[mi], bfr[ni], acc[mi][ni], 0, 0, 0);
    }

    float bs_[4];
#pragma unroll
    for (int ni = 0; ni < 4; ++ni) bs_[ni] = bob[wc*64 + ni*16 + c];

#pragma unroll
    for (int mi = 0; mi < 4; ++mi) {
#pragma unroll
        for (int r = 0; r < 4; ++r) {
            int m = m0 + wr*64 + mi*16 + 4*g + r;
            const float* xr = xin + ((size_t)f*BS_ + m)*128;
            float* xo = xout + ((size_t)f*BS_ + m)*128;
#pragma unroll
            for (int ni = 0; ni < 4; ++ni) {
                int n = wc*64 + ni*16 + c;
                xo[n] = acc[mi][ni][r] + bs_[ni] + xr[n];
            }
        }
    }
}

// ---------------------------------------------------------------------------
// LayerNorm over last dim (128). One wave per row. Emits fp32 + bf16.
// ---------------------------------------------------------------------------
__global__ __launch_bounds__(256) void ln_kernel(
    const float* __restrict__ xin, float* __restrict__ xout,
    unsigned short* __restrict__ xoutb,
    const float* __restrict__ g, const float* __restrict__ bb, int f0, int gstride)
{
    int t = threadIdx.x, lane = t & 63, w = t >> 6;
    int rowl = blockIdx.x * 4 + w;
    int fl = rowl >> 12;
    size_t row = (size_t)f0*BS_ + rowl;
    const float* xi = xin + row*128;
    float a = xi[lane], c = xi[64 + lane];
    float s = a + c;
#pragma unroll
    for (int off = 1; off < 64; off <<= 1) s += __shfl_xor(s, off);
    float mean = s * (1.0f/128.0f);
    float da = a - mean, dc = c - mean;
    float vs = da*da + dc*dc;
#pragma unroll
    for (int off = 1; off < 64; off <<= 1) vs += __shfl_xor(vs, off);
    float inv = rsqrtf(vs * (1.0f/128.0f) + 1e-5f);
    const float* gp = g + (size_t)fl*gstride;
    const float* bp = bb + (size_t)fl*gstride;
    float o0 = da*inv*gp[lane]      + bp[lane];
    float o1 = dc*inv*gp[64 + lane] + bp[64 + lane];
    float* xo = xout + row*128;
    xo[lane]      = o0;
    xo[64 + lane] = o1;
    xoutb[row*128 + lane]      = f2b(o0);
    xoutb[row*128 + 64 + lane] = f2b(o1);
}

// ---------------------------------------------------------------------------
// Softmax-pool over S (unchanged).
// ---------------------------------------------------------------------------
__global__ __launch_bounds__(256) void pool_kernel(
    const float* __restrict__ xB, const float* __restrict__ poolW,
    float* __restrict__ U, int f0)
{
    int f = f0 + blockIdx.x, b = blockIdx.y;
    const float* xb = xB + ((size_t)f*BS_ + (size_t)b*S_)*128;
    const float* pw = poolW + f*128;
    __shared__ float sc[512];
    __shared__ float red[8];
    __shared__ float MS[2];
    __shared__ float pool2[256];
    int t = threadIdx.x, lane = t & 63, w = t >> 6;

    float p0 = pw[lane], p1 = pw[64 + lane];
    for (int s = w; s < 512; s += 4) {
        float a = xb[(size_t)s*128 + lane]*p0 + xb[(size_t)s*128 + 64 + lane]*p1;
#pragma unroll
        for (int off = 1; off < 64; off <<= 1) a += __shfl_xor(a, off);
        if (lane == 0) sc[s] = a;
    }
    __syncthreads();

    float m = -1e30f;
    for (int s = t; s < 512; s += 256) m = fmaxf(m, sc[s]);
#pragma unroll
    for (int off = 1; off < 64; off <<= 1) m = fmaxf(m, __shfl_xor(m, off));
    if (lane == 0) red[w] = m;
    __syncthreads();
    if (t == 0) MS[0] = fmaxf(fmaxf(red[0], red[1]), fmaxf(red[2], red[3]));
    __syncthreads();
    float M = MS[0];

    float ssum = 0.f;
    for (int s = t; s < 512; s += 256) { float e = expf(sc[s] - M); sc[s] = e; ssum += e; }
#pragma unroll
    for (int off = 1; off < 64; off <<= 1) ssum += __shfl_xor(ssum, off);
    if (lane == 0) red[4 + w] = ssum;
    __syncthreads();
    if (t == 0) MS[1] = red[4] + red[5] + red[6] + red[7];
    __syncthreads();
    float inv = 1.0f / MS[1];

    int d = t & 127, hh = t >> 7;
    float a = 0.f;
    for (int s = hh*256; s < hh*256 + 256; ++s) a += sc[s]*xb[(size_t)s*128 + d];
    pool2[t] = a;
    __syncthreads();
    if (t < 128) U[((size_t)b*128 + d)*F_ + f] = (pool2[t] + pool2[t + 128]) * inv;
}

// ---------------------------------------------------------------------------
// Unified attention per (f,b) (unchanged).
// ---------------------------------------------------------------------------
__global__ __launch_bounds__(256) void unified_kernel(
    const float* __restrict__ U,
    const float* __restrict__ uQW, const float* __restrict__ uQB,
    const float* __restrict__ uKW, const float* __restrict__ uKB,
    const float* __restrict__ uVW, const float* __restrict__ uVB,
    float* __restrict__ outp)
{
    int f = blockIdx.x, b = blockIdx.y;
    __shared__ float Ub[128*9];
    __shared__ float Wj[128*9];
    __shared__ float zj[128];
    __shared__ float vm[128];
    __shared__ float Mm[81];
    __shared__ float wvm[9], bvec[9];
    __shared__ float cc_[2];
    int t = threadIdx.x;
    for (int i = t; i < 1152; i += 256) Ub[i] = U[(size_t)b*1152 + i];
    const float* qw = uQW + (size_t)f*1152;
    const float* kw = uKW + (size_t)f*1152;
    const float* vw = uVW + (size_t)f*1152;
    const float* qb = uQB + (size_t)f*128;
    const float* kb = uKB + (size_t)f*128;
    const float* vb = uVB + (size_t)f*128;

    if (t < 81) {
        int t1 = t/9, s1 = t%9; float a = 0.f;
        for (int kk = 0; kk < 128; ++kk) a += qw[kk*9 + t1]*kw[kk*9 + s1];
        Mm[t] = a;
    } else if (t < 90) {
        int s1 = t - 81; float a = 0.f;
        for (int kk = 0; kk < 128; ++kk) a += kw[kk*9 + s1]*qb[kk];
        bvec[s1] = a;
    } else if (t < 99) {
        int t1 = t - 90; float a = 0.f;
        for (int kk = 0; kk < 128; ++kk) a += vw[kk*9 + t1];
        wvm[t1] = a * (1.0f/128.0f);
    } else if (t == 99) {
        float a = 0.f, c2 = 0.f;
        for (int kk = 0; kk < 128; ++kk) { a += qb[kk]*kb[kk]; c2 += vb[kk]; }
        cc_[0] = a; cc_[1] = c2 * (1.0f/128.0f);
    }
    __syncthreads();

    if (t < 128) {
        int j = t;
        for (int t1 = 0; t1 < 9; ++t1) {
            float a = 0.f;
            for (int s1 = 0; s1 < 9; ++s1) a += Mm[t1*9 + s1]*Ub[j*9 + s1];
            Wj[j*9 + t1] = a;
        }
        float z = cc_[0], v2 = cc_[1];
        for (int s1 = 0; s1 < 9; ++s1) { z += bvec[s1]*Ub[j*9 + s1]; v2 += wvm[s1]*Ub[j*9 + s1]; }
        zj[j] = z; vm[j] = v2;
    }
    __syncthreads();

    int i = t >> 1, half = t & 1;
    float ui[9];
#pragma unroll
    for (int s1 = 0; s1 < 9; ++s1) ui[s1] = Ub[i*9 + s1];

    float mx = -1e30f;
    for (int jj = 0; jj < 64; ++jj) {
        int j = half*64 + jj;
        float a = zj[j];
#pragma unroll
        for (int s1 = 0; s1 < 9; ++s1) a += ui[s1]*Wj[j*9 + s1];
        mx = fmaxf(mx, a * (1.0f/3.0f));
    }
    mx = fmaxf(mx, __shfl_xor(mx, 1));
    float sum = 0.f, o = 0.f;
    for (int jj = 0; jj < 64; ++jj) {
        int j = half*64 + jj;
        float a = zj[j];
#pragma unroll
        for (int s1 = 0; s1 < 9; ++s1) a += ui[s1]*Wj[j*9 + s1];
        float p = expf(a * (1.0f/3.0f) - mx);
        sum += p; o += p*vm[j];
    }
    sum += __shfl_xor(sum, 1);
    o   += __shfl_xor(o, 1);
    if (half == 0) {
        float base;
        if (f > 0) base = ui[f];
        else { base = 0.f; for (int s1 = 0; s1 < 9; ++s1) base += ui[s1]; base *= (1.0f/9.0f); }
        outp[((size_t)b*128 + i)*10 + f] = o/sum + base;
    }
}

// ---------------------------------------------------------------------------
// Merge attention (features 3..8), writes output column 9 (unchanged).
// ---------------------------------------------------------------------------
__global__ __launch_bounds__(256) void merge_kernel(
    const float* __restrict__ U,
    const float* __restrict__ mQW, const float* __restrict__ mQB,
    const float* __restrict__ mKW, const float* __restrict__ mKB,
    const float* __restrict__ mVW, const float* __restrict__ mVB,
    float* __restrict__ outp)
{
    int b = blockIdx.x;
    __shared__ float Us[128*6];
    __shared__ float Wj[128*6];
    __shared__ float zj[128];
    __shared__ float vm[128];
    __shared__ float Mm[36];
    __shared__ float wvm[6], bvec[6];
    __shared__ float cc_[2];
    int t = threadIdx.x;
    for (int i = t; i < 768; i += 256) {
        int j = i/6, tt = i - j*6;
        Us[i] = U[(size_t)b*1152 + j*9 + 3 + tt];
    }
    if (t < 36) {
        int t1 = t/6, s1 = t%6; float a = 0.f;
        for (int kk = 0; kk < 128; ++kk) a += mQW[kk*6 + t1]*mKW[kk*6 + s1];
        Mm[t] = a;
    } else if (t < 42) {
        int s1 = t - 36; float a = 0.f;
        for (int kk = 0; kk < 128; ++kk) a += mKW[kk*6 + s1]*mQB[kk];
        bvec[s1] = a;
    } else if (t < 48) {
        int t1 = t - 42; float a = 0.f;
        for (int kk = 0; kk < 128; ++kk) a += mVW[kk*6 + t1];
        wvm[t1] = a * (1.0f/128.0f);
    } else if (t == 48) {
        float a = 0.f, c2 = 0.f;
        for (int kk = 0; kk < 128; ++kk) { a += mQB[kk]*mKB[kk]; c2 += mVB[kk]; }
        cc_[0] = a; cc_[1] = c2 * (1.0f/128.0f);
    }
    __syncthreads();

    if (t < 128) {
        int j = t;
        for (int t1 = 0; t1 < 6; ++t1) {
            float a = 0.f;
            for (int s1 = 0; s1 < 6; ++s1) a += Mm[t1*6 + s1]*Us[j*6 + s1];
            Wj[j*6 + t1] = a;
        }
        float z = cc_[0], v2 = cc_[1];
        for (int s1 = 0; s1 < 6; ++s1) { z += bvec[s1]*Us[j*6 + s1]; v2 += wvm[s1]*Us[j*6 + s1]; }
        zj[j] = z; vm[j] = v2;
    }
    __syncthreads();

    int i = t >> 1, half = t & 1;
    float ui[6];
#pragma unroll
    for (int s1 = 0; s1 < 6; ++s1) ui[s1] = Us[i*6 + s1];

    float mx = -1e30f;
    for (int jj = 0; jj < 64; ++jj) {
        int j = half*64 + jj;
        float a = zj[j];
#pragma unroll
        for (int s1 = 0; s1 < 6; ++s1) a += ui[s1]*Wj[j*6 + s1];
        mx = fmaxf(mx, a * (1.0f/3.0f));
    }
    mx = fmaxf(mx, __shfl_xor(mx, 1));
    float sum = 0.f, o = 0.f;
    for (int jj = 0; jj < 64; ++jj) {
        int j = half*64 + jj;
        float a = zj[j];
#pragma unroll
        for (int s1 = 0; s1 < 6; ++s1) a += ui[s1]*Wj[j*6 + s1];
        float p = expf(a * (1.0f/3.0f) - mx);
        sum += p; o += p*vm[j];
    }
    sum += __shfl_xor(sum, 1);
    o   += __shfl_xor(o, 1);
    if (half == 0) {
        float base = 0.f;
        for (int s1 = 0; s1 < 6; ++s1) base += ui[s1];
        base *= (1.0f/6.0f);
        outp[((size_t)b*128 + i)*10 + 9] = o/sum + base;
    }
}

// ---------------------------------------------------------------------------
extern "C" void kernel_launch(void* const* d_in, const int* in_sizes, int n_in,
                              void* d_out, int out_size, void* d_ws, size_t ws_size,
                              hipStream_t stream)
{
    const float* Y     = (const float*)d_in[0];
    const float* Gin   = (const float*)d_in[1];
    const float* posW1 = (const float*)d_in[2];
    const float* posB1 = (const float*)d_in[3];
    const float* posW2 = (const float*)d_in[4];
    const float* posB2 = (const float*)d_in[5];
    const float* posW3 = (const float*)d_in[6];
    const float* posB3 = (const float*)d_in[7];
    const float* Wq    = (const float*)d_in[8];
    const float* bq    = (const float*)d_in[9];
    const float* Wk    = (const float*)d_in[10];
    const float* bk    = (const float*)d_in[11];
    const float* Wv    = (const float*)d_in[12];
    const float* bv    = (const float*)d_in[13];
    const float* Wo    = (const float*)d_in[14];
    const float* bo    = (const float*)d_in[15];
    const float* lnG   = (const float*)d_in[16];
    const float* lnB   = (const float*)d_in[17];
    const float* fnG   = (const float*)d_in[18];
    const float* fnB   = (const float*)d_in[19];
    const float* poolW = (const float*)d_in[20];
    const float* uQW   = (const float*)d_in[21];
    const float* uQB   = (const float*)d_in[22];
    const float* uKW   = (const float*)d_in[23];
    const float* uKB   = (const float*)d_in[24];
    const float* uVW   = (const float*)d_in[25];
    const float* uVB   = (const float*)d_in[26];
    const float* mQW   = (const float*)d_in[27];
    const float* mQB   = (const float*)d_in[28];
    const float* mKW   = (const float*)d_in[29];
    const float* mKB   = (const float*)d_in[30];
    const float* mVW   = (const float*)d_in[31];
    const float* mVB   = (const float*)d_in[32];

    const size_t xelems = (size_t)F_ * BS_ * 128;     // 4,718,592
    char* p = (char*)d_ws;
    float* xA   = (float*)p;               p += xelems*4;
    float* xB   = (float*)p;               p += xelems*4;
    float* Ubuf = (float*)p;               p += 16384*4;
    unsigned short* xAb = (unsigned short*)p; p += xelems*2;
    unsigned short* Wqb = (unsigned short*)p; p += WELEMS*2;
    unsigned short* Wkb = (unsigned short*)p; p += WELEMS*2;
    unsigned short* Wvb = (unsigned short*)p; p += WELEMS*2;
    unsigned short* Wob = (unsigned short*)p; p += WELEMS*2;
    size_t fixed_bytes = (size_t)(p - (char*)d_ws);

    size_t avail = (ws_size > fixed_bytes) ? (ws_size - fixed_bytes) : 0;
    size_t per_f = 8UL * PERBUF;            // q(2B)+k(2B)+wv(2B)+Vt(2B eff) per elem
    int FC = (int)(avail / per_f);
    if (FC < 1) FC = 1;
    if (FC > F_) FC = F_;

    unsigned short* qb  = (unsigned short*)p;
    unsigned short* kb  = qb + (size_t)FC*PERBUF;
    unsigned short* wvb = kb + (size_t)FC*PERBUF;
    unsigned int*   vtb = (unsigned int*)(wvb + (size_t)FC*PERBUF);

    // Weight conversion to bf16 (once per launch, ~19 MB)
    {
        int n = (int)WELEMS, grid = (n/8 + 255)/256;
        cvt_kernel<<<grid, 256, 0, stream>>>(Wq, Wqb, n);
        cvt_kernel<<<grid, 256, 0, stream>>>(Wk, Wkb, n);
        cvt_kernel<<<grid, 256, 0, stream>>>(Wv, Wvb, n);
        cvt_kernel<<<grid, 256, 0, stream>>>(Wo, Wob, n);
    }

    posnet_kernel<<<dim3(1024, 1, F_), 256, 0, stream>>>(
        Y, Gin, posW1, posB1, posW2, posB2, posW3, posB3, xA, xAb);

    for (int l = 0; l < 2; ++l) {
        for (int f0 = 0; f0 < F_; f0 += FC) {
            int fc = (F_ - f0) < FC ? (F_ - f0) : FC;
            qkv_mfma_kernel<<<dim3(32, 8, 3*fc), 256, 0, stream>>>(
                xAb, Wqb, Wkb, Wvb, bq, bk, bv, qb, kb, vtb, l, f0);
            attn_mfma_kernel<<<dim3(256*fc), 256, 0, stream>>>(qb, kb, vtb, wvb);
            outproj_mfma_kernel<<<dim3(32, 1, fc), 256, 0, stream>>>(
                wvb, Wob, bo, xA, xB, l, f0);
            ln_kernel<<<dim3(fc*1024), 256, 0, stream>>>(
                xB, xA, xAb, lnG + (size_t)(l*F_ + f0)*128, lnB + (size_t)(l*F_ + f0)*128, f0, 128);
        }
    }

    for (int f0 = 0; f0 < F_; f0 += FC) {
        int fc = (F_ - f0) < FC ? (F_ - f0) : FC;
        ln_kernel<<<dim3(fc*1024), 256, 0, stream>>>(xA, xB, xAb, fnG, fnB, f0, 0);
        pool_kernel<<<dim3(fc, 8), 256, 0, stream>>>(xB, poolW, Ubuf, f0);
    }

    unified_kernel<<<dim3(F_, B_), 256, 0, stream>>>(
        Ubuf, uQW, uQB, uKW, uKB, uVW, uVB, (float*)d_out);
    merge_kernel<<<dim3(B_), 256, 0, stream>>>(
        Ubuf, mQW, mQB, mKW, mKB, mVW, mVB, (float*)d_out);
}

// Round 6
// 1174.182 us; speedup vs baseline: 5.2435x; 1.2859x over previous
//
#include <hip/hip_runtime.h>
#include <hip/hip_bf16.h>

// Problem constants
#define F_  9
#define B_  8
#define S_  512
#define H_  8
#define DH_ 128
#define D_  128
#define NB_ 50
#define BS_ 4096            // B_*S_ rows per feature
#define PERBUF 4194304UL    // B_*H_*S_*DH_ elements per feature
#define WELEMS 2359296UL    // 2*9*1024*128 elements per projection weight tensor

typedef short bf16x8 __attribute__((ext_vector_type(8)));
typedef float f32x4  __attribute__((ext_vector_type(4)));
typedef unsigned int u32x4 __attribute__((ext_vector_type(4)));

static __device__ __forceinline__ unsigned short f2b(float f) {
    unsigned int u = __float_as_uint(f);
    unsigned int r = (u + 0x7FFFu + ((u >> 16) & 1u)) >> 16;
    return (unsigned short)r;
}
static __device__ __forceinline__ float b2f(unsigned short u) {
    return __uint_as_float(((unsigned int)u) << 16);
}
// pack two f32 -> (lo,hi) bf16 pair in one instr (T12 recipe, m214v22)
static __device__ __forceinline__ unsigned int cvtpk(float lo, float hi) {
    unsigned int r;
    asm("v_cvt_pk_bf16_f32 %0, %1, %2" : "=v"(r) : "v"(lo), "v"(hi));
    return r;
}

// ---------------------------------------------------------------------------
// fp32 -> bf16 bulk convert (for projection weights), 8 elems/thread.
// ---------------------------------------------------------------------------
__global__ __launch_bounds__(256) void cvt_kernel(
    const float* __restrict__ in, unsigned short* __restrict__ out, int n)
{
    int i = (blockIdx.x * 256 + threadIdx.x) * 8;
    if (i + 8 <= n) {
        float4 a = *(const float4*)&in[i];
        float4 b = *(const float4*)&in[i + 4];
        ushort4 o0 = { f2b(a.x), f2b(a.y), f2b(a.z), f2b(a.w) };
        ushort4 o1 = { f2b(b.x), f2b(b.y), f2b(b.z), f2b(b.w) };
        *(ushort4*)&out[i]     = o0;
        *(ushort4*)&out[i + 4] = o1;
    }
}

// ---------------------------------------------------------------------------
// Pos-net: one wave per row; emits fp32 x (residual) and bf16 x (MFMA).
// ---------------------------------------------------------------------------
__global__ __launch_bounds__(256) void posnet_kernel(
    const float* __restrict__ Y, const float* __restrict__ Gin,
    const float* __restrict__ W1g, const float* __restrict__ B1,
    const float* __restrict__ W2g, const float* __restrict__ B2,
    const float* __restrict__ W3g, const float* __restrict__ B3,
    float* __restrict__ xA, unsigned short* __restrict__ xAb)
{
    __shared__ float w1[50*51];
    __shared__ float w2[50*50];
    __shared__ float w3[128*50];
    __shared__ float b1[64], b2[64], b3[128];
    int f = blockIdx.z;
    int t = threadIdx.x;
    for (int i = t; i < 2550; i += 256) w1[i] = W1g[f*2550 + i];
    for (int i = t; i < 2500; i += 256) w2[i] = W2g[f*2500 + i];
    for (int i = t; i < 6400; i += 256) w3[i] = W3g[f*6400 + i];
    if (t < 50) { b1[t] = B1[f*50 + t]; b2[t] = B2[f*50 + t]; }
    if (t < 128) b3[t] = B3[f*128 + t];
    __syncthreads();

    int lane = t & 63, w = t >> 6;
    int row = blockIdx.x * 4 + w;   // 0..4095

    float gy = 0.f;
    if (lane < 50)       gy = Y[(size_t)row*50 + lane];
    else if (lane == 50) gy = Gin[(size_t)row*F_ + f];

    float a1 = (lane < 50) ? b1[lane] : 0.f;
    for (int kk = 0; kk < 51; ++kk) {
        float g = __shfl(gy, kk);
        if (lane < 50) a1 += w1[lane*51 + kk] * g;
    }
    float h1 = tanhf(a1);

    float a2 = (lane < 50) ? b2[lane] : 0.f;
    for (int kk = 0; kk < 50; ++kk) {
        float hh = __shfl(h1, kk);
        if (lane < 50) a2 += w2[lane*50 + kk] * hh;
    }
    float h2 = tanhf(a2);

    float a30 = b3[lane], a31 = b3[64 + lane];
    for (int kk = 0; kk < 50; ++kk) {
        float hh = __shfl(h2, kk);
        a30 += w3[lane*50 + kk] * hh;
        a31 += w3[(64 + lane)*50 + kk] * hh;
    }
    float s0v = 1.f / (1.f + expf(-a30));
    float s1v = 1.f / (1.f + expf(-a31));
    size_t roff = ((size_t)f*BS_ + row)*128;
    xA[roff + lane]       = s0v;
    xA[roff + 64 + lane]  = s1v;
    xAb[roff + lane]      = f2b(s0v);
    xAb[roff + 64 + lane] = f2b(s1v);
}

// ---------------------------------------------------------------------------
// QKV projection via MFMA. q output is PRE-SCALED by 1/sqrt(128).
// which==0/1 -> q/k row-major bf16 [bh][s][dh]; which==2 -> Vt packed u32.
// ---------------------------------------------------------------------------
__global__ __launch_bounds__(256) void qkv_mfma_kernel(
    const unsigned short* __restrict__ xb,
    const unsigned short* __restrict__ Wqb, const unsigned short* __restrict__ Wkb,
    const unsigned short* __restrict__ Wvb,
    const float* __restrict__ bq, const float* __restrict__ bk, const float* __restrict__ bv,
    unsigned short* __restrict__ qo, unsigned short* __restrict__ ko,
    unsigned int* __restrict__ vto, int l, int f0)
{
    int z = blockIdx.z;
    int fl = z / 3, which = z - fl*3;
    int f = f0 + fl;
    const unsigned short* W; const float* bias;
    if (which == 0)      { W = Wqb; bias = bq; }
    else if (which == 1) { W = Wkb; bias = bk; }
    else                 { W = Wvb; bias = bv; }
    W    += (size_t)(l*F_ + f) * 1024 * 128;
    bias += (size_t)(l*F_ + f) * 1024;

    int m0 = blockIdx.x * 128;
    int n0 = blockIdx.y * 128;
    int t = threadIdx.x, w = t >> 6, ln = t & 63, g = ln >> 4, c = ln & 15;
    int wr = w >> 1, wc = w & 1;

    const unsigned short* Ab = xb + ((size_t)f*BS_ + m0 + wr*64)*128;
    const unsigned short* Bb = W + (size_t)(n0 + wc*64)*128;

    f32x4 acc[4][4];
#pragma unroll
    for (int mi = 0; mi < 4; ++mi)
#pragma unroll
        for (int ni = 0; ni < 4; ++ni) acc[mi][ni] = (f32x4){0.f,0.f,0.f,0.f};

#pragma unroll
    for (int kt = 0; kt < 4; ++kt) {
        bf16x8 af[4], bfr[4];
#pragma unroll
        for (int mi = 0; mi < 4; ++mi)
            af[mi] = *(const bf16x8*)&Ab[(size_t)(mi*16 + c)*128 + kt*32 + g*8];
#pragma unroll
        for (int ni = 0; ni < 4; ++ni)
            bfr[ni] = *(const bf16x8*)&Bb[(size_t)(ni*16 + c)*128 + kt*32 + g*8];
#pragma unroll
        for (int mi = 0; mi < 4; ++mi)
#pragma unroll
            for (int ni = 0; ni < 4; ++ni)
                acc[mi][ni] = __builtin_amdgcn_mfma_f32_16x16x32_bf16(af[mi], bfr[ni], acc[mi][ni], 0, 0, 0);
    }

    int h = n0 >> 7;
    float bs_[4];
#pragma unroll
    for (int ni = 0; ni < 4; ++ni) bs_[ni] = bias[n0 + wc*64 + ni*16 + c];

    if (which < 2) {
        float qscale = (which == 0) ? 0.08838834764831845f : 1.0f;
        unsigned short* out = (which == 0 ? qo : ko) + (size_t)fl * PERBUF;
#pragma unroll
        for (int mi = 0; mi < 4; ++mi) {
#pragma unroll
            for (int r = 0; r < 4; ++r) {
                int m = m0 + wr*64 + mi*16 + 4*g + r;
                int b = m >> 9, s = m & 511;
                unsigned short* orow = out + (((size_t)(b*H_ + h))*S_ + s)*128;
#pragma unroll
                for (int ni = 0; ni < 4; ++ni)
                    orow[wc*64 + ni*16 + c] = f2b((acc[mi][ni][r] + bs_[ni]) * qscale);
            }
        }
    } else {
        // Vt[bh][d][s/2] u32: lo = even s, hi = odd s.
        unsigned int* vtf = vto + (size_t)fl * (PERBUF/2);
#pragma unroll
        for (int mi = 0; mi < 4; ++mi) {
            int mbase = m0 + wr*64 + mi*16 + 4*g;      // multiple of 4
            int b = mbase >> 9, sh = (mbase & 511) >> 1;
            unsigned int* vtp = vtf + ((size_t)(b*H_ + h))*32768;
#pragma unroll
            for (int ni = 0; ni < 4; ++ni) {
                int d = wc*64 + ni*16 + c;
                float bb_ = bs_[ni];
                unsigned int p01 = (unsigned int)f2b(acc[mi][ni][0] + bb_)
                                 | ((unsigned int)f2b(acc[mi][ni][1] + bb_) << 16);
                unsigned int p23 = (unsigned int)f2b(acc[mi][ni][2] + bb_)
                                 | ((unsigned int)f2b(acc[mi][ni][3] + bb_) << 16);
                vtp[(size_t)d*256 + sh]     = p01;
                vtp[(size_t)d*256 + sh + 1] = p23;
            }
        }
    }
}

// ---------------------------------------------------------------------------
// MFMA flash attention, swapped-QK^T (T12) + LDS double-buffered pipeline.
// S^T = mfma(K, Q): lane (g,c) owns q-row c; scores for keys {4g+r} (s0)
// and {16+4g+r} (s1) live in registers -> softmax reduce = 7 VALU + 2 shfl.
// P -> PV A-frag via cvt_pk + 8 register shuffles (no P LDS buffer).
// q arrives pre-scaled by 1/sqrt(128). Defer-max (THR=8) skips acc rescale.
// ---------------------------------------------------------------------------
__global__ __launch_bounds__(256) void attn_mfma_kernel(
    const unsigned short* __restrict__ q, const unsigned short* __restrict__ k,
    const unsigned int* __restrict__ vt, unsigned short* __restrict__ wv)
{
    int t = threadIdx.x;
    int w = t >> 6, ln = t & 63, g = ln >> 4, c = ln & 15;
    int bid = blockIdx.x;
    int group = bid >> 5, within = bid & 31;
    int i = within >> 3, hl = within & 7;
    int hIdx = group*8 + hl;                 // 0 .. 64*fc-1
    int fl = hIdx >> 6, by = hIdx & 63;
    int q0 = i*128 + w*32;

    const unsigned short* qh = q + ((size_t)(fl*64 + by))*S_*128;
    const unsigned short* kh = k + ((size_t)(fl*64 + by))*S_*128;
    const unsigned int*  vth = vt + ((size_t)(fl*64 + by))*32768;
    int b = by >> 3, h = by & 7;
    unsigned short* wvh = wv + ((size_t)(fl*B_ + b))*S_*1024 + h*128;

    __shared__ alignas(16) unsigned short Ks[2][32][136];  // 17408 B
    __shared__ alignas(16) unsigned int   Vs[2][128][20];  // 20480 B

    // staging index split (256 threads)
    int krow = t >> 4, kseg = t & 15;   // K rows krow, krow+16 ; 16B segs
    int vrow = t >> 2, vseg = t & 3;    // V rows vrow, vrow+64 ; 16B segs

    bf16x8 qf[2][4];
#pragma unroll
    for (int gq = 0; gq < 2; ++gq)
#pragma unroll
        for (int d0 = 0; d0 < 4; ++d0)
            qf[gq][d0] = *(const bf16x8*)&qh[(size_t)(q0 + gq*16 + c)*128 + d0*32 + g*8];

    f32x4 acc[2][8];
#pragma unroll
    for (int gq = 0; gq < 2; ++gq)
#pragma unroll
        for (int i2 = 0; i2 < 8; ++i2) acc[gq][i2] = (f32x4){0.f, 0.f, 0.f, 0.f};
    float mrow[2] = {-1e30f, -1e30f};
    float lrow[2] = {0.f, 0.f};

    int srcA = ((g & 1) << 5) + c;   // source lane for low half of A-frag
    int srcB = srcA + 16;
    bool glow = (g < 2);

    uint4 kr0, kr1, vr0, vr1;
    // prologue: tile 0 -> buf 0
    {
        kr0 = *(const uint4*)&kh[(size_t)krow*128 + kseg*8];
        kr1 = *(const uint4*)&kh[(size_t)(krow + 16)*128 + kseg*8];
        vr0 = *(const uint4*)&vth[(size_t)vrow*256 + vseg*4];
        vr1 = *(const uint4*)&vth[(size_t)(vrow + 64)*256 + vseg*4];
        *(uint4*)&Ks[0][krow][kseg*8]      = kr0;
        *(uint4*)&Ks[0][krow + 16][kseg*8] = kr1;
        *(uint4*)&Vs[0][vrow][vseg*4]      = vr0;
        *(uint4*)&Vs[0][vrow + 64][vseg*4] = vr1;
    }
    __syncthreads();

    int cur = 0;
    for (int kt = 0; kt < 16; ++kt) {
        if (kt < 15) {
            const unsigned short* ks = kh + (size_t)(kt + 1)*32*128;
            const unsigned int*  vsp = vth + (kt + 1)*16;
            kr0 = *(const uint4*)&ks[(size_t)krow*128 + kseg*8];
            kr1 = *(const uint4*)&ks[(size_t)(krow + 16)*128 + kseg*8];
            vr0 = *(const uint4*)&vsp[(size_t)vrow*256 + vseg*4];
            vr1 = *(const uint4*)&vsp[(size_t)(vrow + 64)*256 + vseg*4];
        }

        // QK^T (swapped): s[gq][tile] = S^T[key][qrow]
        f32x4 s[2][2];
        s[0][0] = (f32x4){0.f,0.f,0.f,0.f}; s[0][1] = (f32x4){0.f,0.f,0.f,0.f};
        s[1][0] = (f32x4){0.f,0.f,0.f,0.f}; s[1][1] = (f32x4){0.f,0.f,0.f,0.f};
        __builtin_amdgcn_s_setprio(1);
#pragma unroll
        for (int d0 = 0; d0 < 4; ++d0) {
            bf16x8 k0 = *(const bf16x8*)&Ks[cur][c][g*8 + d0*32];
            bf16x8 k1 = *(const bf16x8*)&Ks[cur][16 + c][g*8 + d0*32];
#pragma unroll
            for (int gq = 0; gq < 2; ++gq) {
                s[gq][0] = __builtin_amdgcn_mfma_f32_16x16x32_bf16(k0, qf[gq][d0], s[gq][0], 0, 0, 0);
                s[gq][1] = __builtin_amdgcn_mfma_f32_16x16x32_bf16(k1, qf[gq][d0], s[gq][1], 0, 0, 0);
            }
        }
        __builtin_amdgcn_s_setprio(0);

        // softmax: lane owns qrow c for each gq; keys in regs (4g+r, 16+4g+r)
        float corr[2];
        bf16x8 pa[2];
        bool need = false;
#pragma unroll
        for (int gq = 0; gq < 2; ++gq) {
            float t0 = fmaxf(fmaxf(fmaxf(s[gq][0][0], s[gq][0][1]), fmaxf(s[gq][0][2], s[gq][0][3])),
                             fmaxf(fmaxf(s[gq][1][0], s[gq][1][1]), fmaxf(s[gq][1][2], s[gq][1][3])));
            t0 = fmaxf(t0, __shfl_xor(t0, 16));
            t0 = fmaxf(t0, __shfl_xor(t0, 32));
            float mo = mrow[gq];
            float mn = (t0 > mo + 8.f) ? t0 : mo;
            float co = __expf(mo - mn);
            corr[gq] = co;
            mrow[gq] = mn;
            float p00 = __expf(s[gq][0][0] - mn), p01 = __expf(s[gq][0][1] - mn);
            float p02 = __expf(s[gq][0][2] - mn), p03 = __expf(s[gq][0][3] - mn);
            float p10 = __expf(s[gq][1][0] - mn), p11 = __expf(s[gq][1][1] - mn);
            float p12 = __expf(s[gq][1][2] - mn), p13 = __expf(s[gq][1][3] - mn);
            float ps = ((p00 + p01) + (p02 + p03)) + ((p10 + p11) + (p12 + p13));
            ps += __shfl_xor(ps, 16);
            ps += __shfl_xor(ps, 32);
            lrow[gq] = lrow[gq]*co + ps;
            need = need || (co != 1.0f);

            // pack P to bf16 pairs and redistribute to A-frag layout
            unsigned int pk0 = cvtpk(p00, p01), pk1 = cvtpk(p02, p03);
            unsigned int pk2 = cvtpk(p10, p11), pk3 = cvtpk(p12, p13);
            unsigned int a0 = __shfl(pk0, srcA), a1 = __shfl(pk1, srcA);
            unsigned int b0 = __shfl(pk0, srcB), b1 = __shfl(pk1, srcB);
            unsigned int c0 = __shfl(pk2, srcA), c1 = __shfl(pk3, srcA);
            unsigned int d0_ = __shfl(pk2, srcB), d1_ = __shfl(pk3, srcB);
            u32x4 pu;
            pu[0] = glow ? a0 : c0;
            pu[1] = glow ? a1 : c1;
            pu[2] = glow ? b0 : d0_;
            pu[3] = glow ? b1 : d1_;
            pa[gq] = __builtin_bit_cast(bf16x8, pu);
        }

        if (__any(need)) {
#pragma unroll
            for (int gq = 0; gq < 2; ++gq) {
                float cr0 = __shfl(corr[gq], 4*g + 0);
                float cr1 = __shfl(corr[gq], 4*g + 1);
                float cr2 = __shfl(corr[gq], 4*g + 2);
                float cr3 = __shfl(corr[gq], 4*g + 3);
#pragma unroll
                for (int i2 = 0; i2 < 8; ++i2) {
                    f32x4 a = acc[gq][i2];
                    a[0] *= cr0; a[1] *= cr1; a[2] *= cr2; a[3] *= cr3;
                    acc[gq][i2] = a;
                }
            }
        }

        // PV
        __builtin_amdgcn_s_setprio(1);
#pragma unroll
        for (int i2 = 0; i2 < 8; ++i2) {
            bf16x8 vf = *(const bf16x8*)&Vs[cur][i2*16 + c][g*4];
            acc[0][i2] = __builtin_amdgcn_mfma_f32_16x16x32_bf16(pa[0], vf, acc[0][i2], 0, 0, 0);
            acc[1][i2] = __builtin_amdgcn_mfma_f32_16x16x32_bf16(pa[1], vf, acc[1][i2], 0, 0, 0);
        }
        __builtin_amdgcn_s_setprio(0);

        if (kt < 15) {
            __syncthreads();
            int nxt = cur ^ 1;
            *(uint4*)&Ks[nxt][krow][kseg*8]      = kr0;
            *(uint4*)&Ks[nxt][krow + 16][kseg*8] = kr1;
            *(uint4*)&Vs[nxt][vrow][vseg*4]      = vr0;
            *(uint4*)&Vs[nxt][vrow + 64][vseg*4] = vr1;
            __syncthreads();
            cur = nxt;
        }
    }

    // epilogue: 1/l per q-row (held at lane c), redistribute to (g,r)
#pragma unroll
    for (int gq = 0; gq < 2; ++gq) {
        float invq = 1.0f / lrow[gq];
        float iv0 = __shfl(invq, 4*g + 0);
        float iv1 = __shfl(invq, 4*g + 1);
        float iv2 = __shfl(invq, 4*g + 2);
        float iv3 = __shfl(invq, 4*g + 3);
#pragma unroll
        for (int i2 = 0; i2 < 8; ++i2) {
            unsigned short* wp = &wvh[(size_t)(q0 + gq*16 + 4*g)*1024 + i2*16 + c];
            wp[0]    = f2b(acc[gq][i2][0]*iv0);
            wp[1024] = f2b(acc[gq][i2][1]*iv1);
            wp[2048] = f2b(acc[gq][i2][2]*iv2);
            wp[3072] = f2b(acc[gq][i2][3]*iv3);
        }
    }
}

// ---------------------------------------------------------------------------
// Out-projection via MFMA + residual: x1 = x0 + wv @ Wo^T + bo (fp32 out).
// ---------------------------------------------------------------------------
__global__ __launch_bounds__(256) void outproj_mfma_kernel(
    const unsigned short* __restrict__ wv, const unsigned short* __restrict__ Wob,
    const float* __restrict__ bo, const float* __restrict__ xin,
    float* __restrict__ xout, int l, int f0)
{
    int fl = blockIdx.z, f = f0 + fl;
    int m0 = blockIdx.x * 128;
    int t = threadIdx.x, w = t >> 6, ln = t & 63, g = ln >> 4, c = ln & 15;
    int wr = w >> 1, wc = w & 1;

    const unsigned short* Ab = wv + ((size_t)fl*BS_ + m0 + wr*64)*1024;
    const unsigned short* Bb = Wob + (size_t)(l*F_ + f)*128*1024 + (size_t)(wc*64)*1024;
    const float* bob = bo + (size_t)(l*F_ + f)*128;

    f32x4 acc[4][4];
#pragma unroll
    for (int mi = 0; mi < 4; ++mi)
#pragma unroll
        for (int ni = 0; ni < 4; ++ni) acc[mi][ni] = (f32x4){0.f,0.f,0.f,0.f};

#pragma unroll 4
    for (int kt = 0; kt < 32; ++kt) {
        bf16x8 af[4], bfr[4];
#pragma unroll
        for (int mi = 0; mi < 4; ++mi)
            af[mi] = *(const bf16x8*)&Ab[(size_t)(mi*16 + c)*1024 + kt*32 + g*8];
#pragma unroll
        for (int ni = 0; ni < 4; ++ni)
            bfr[ni] = *(const bf16x8*)&Bb[(size_t)(ni*16 + c)*1024 + kt*32 + g*8];
#pragma unroll
        for (int mi = 0; mi < 4; ++mi)
#pragma unroll
            for (int ni = 0; ni < 4; ++ni)
                acc[mi][ni] = __builtin_amdgcn_mfma_f32_16x16x32_bf16(af[mi], bfr[ni], acc[mi][ni], 0, 0, 0);
    }

    float bs_[4];
#pragma unroll
    for (int ni = 0; ni < 4; ++ni) bs_[ni] = bob[wc*64 + ni*16 + c];

#pragma unroll
    for (int mi = 0; mi < 4; ++mi) {
#pragma unroll
        for (int r = 0; r < 4; ++r) {
            int m = m0 + wr*64 + mi*16 + 4*g + r;
            const float* xr = xin + ((size_t)f*BS_ + m)*128;
            float* xo = xout + ((size_t)f*BS_ + m)*128;
#pragma unroll
            for (int ni = 0; ni < 4; ++ni) {
                int n = wc*64 + ni*16 + c;
                xo[n] = acc[mi][ni][r] + bs_[ni] + xr[n];
            }
        }
    }
}

// ---------------------------------------------------------------------------
// LayerNorm over last dim (128). One wave per row. Emits fp32 + bf16.
// ---------------------------------------------------------------------------
__global__ __launch_bounds__(256) void ln_kernel(
    const float* __restrict__ xin, float* __restrict__ xout,
    unsigned short* __restrict__ xoutb,
    const float* __restrict__ g, const float* __restrict__ bb, int f0, int gstride)
{
    int t = threadIdx.x, lane = t & 63, w = t >> 6;
    int rowl = blockIdx.x * 4 + w;
    int fl = rowl >> 12;
    size_t row = (size_t)f0*BS_ + rowl;
    const float* xi = xin + row*128;
    float a = xi[lane], c = xi[64 + lane];
    float s = a + c;
#pragma unroll
    for (int off = 1; off < 64; off <<= 1) s += __shfl_xor(s, off);
    float mean = s * (1.0f/128.0f);
    float da = a - mean, dc = c - mean;
    float vs = da*da + dc*dc;
#pragma unroll
    for (int off = 1; off < 64; off <<= 1) vs += __shfl_xor(vs, off);
    float inv = rsqrtf(vs * (1.0f/128.0f) + 1e-5f);
    const float* gp = g + (size_t)fl*gstride;
    const float* bp = bb + (size_t)fl*gstride;
    float o0 = da*inv*gp[lane]      + bp[lane];
    float o1 = dc*inv*gp[64 + lane] + bp[64 + lane];
    float* xo = xout + row*128;
    xo[lane]      = o0;
    xo[64 + lane] = o1;
    xoutb[row*128 + lane]      = f2b(o0);
    xoutb[row*128 + 64 + lane] = f2b(o1);
}

// ---------------------------------------------------------------------------
// Softmax-pool over S (unchanged).
// ---------------------------------------------------------------------------
__global__ __launch_bounds__(256) void pool_kernel(
    const float* __restrict__ xB, const float* __restrict__ poolW,
    float* __restrict__ U, int f0)
{
    int f = f0 + blockIdx.x, b = blockIdx.y;
    const float* xb = xB + ((size_t)f*BS_ + (size_t)b*S_)*128;
    const float* pw = poolW + f*128;
    __shared__ float sc[512];
    __shared__ float red[8];
    __shared__ float MS[2];
    __shared__ float pool2[256];
    int t = threadIdx.x, lane = t & 63, w = t >> 6;

    float p0 = pw[lane], p1 = pw[64 + lane];
    for (int s = w; s < 512; s += 4) {
        float a = xb[(size_t)s*128 + lane]*p0 + xb[(size_t)s*128 + 64 + lane]*p1;
#pragma unroll
        for (int off = 1; off < 64; off <<= 1) a += __shfl_xor(a, off);
        if (lane == 0) sc[s] = a;
    }
    __syncthreads();

    float m = -1e30f;
    for (int s = t; s < 512; s += 256) m = fmaxf(m, sc[s]);
#pragma unroll
    for (int off = 1; off < 64; off <<= 1) m = fmaxf(m, __shfl_xor(m, off));
    if (lane == 0) red[w] = m;
    __syncthreads();
    if (t == 0) MS[0] = fmaxf(fmaxf(red[0], red[1]), fmaxf(red[2], red[3]));
    __syncthreads();
    float M = MS[0];

    float ssum = 0.f;
    for (int s = t; s < 512; s += 256) { float e = expf(sc[s] - M); sc[s] = e; ssum += e; }
#pragma unroll
    for (int off = 1; off < 64; off <<= 1) ssum += __shfl_xor(ssum, off);
    if (lane == 0) red[4 + w] = ssum;
    __syncthreads();
    if (t == 0) MS[1] = red[4] + red[5] + red[6] + red[7];
    __syncthreads();
    float inv = 1.0f / MS[1];

    int d = t & 127, hh = t >> 7;
    float a = 0.f;
    for (int s = hh*256; s < hh*256 + 256; ++s) a += sc[s]*xb[(size_t)s*128 + d];
    pool2[t] = a;
    __syncthreads();
    if (t < 128) U[((size_t)b*128 + d)*F_ + f] = (pool2[t] + pool2[t + 128]) * inv;
}

// ---------------------------------------------------------------------------
// Unified attention per (f,b) (unchanged).
// ---------------------------------------------------------------------------
__global__ __launch_bounds__(256) void unified_kernel(
    const float* __restrict__ U,
    const float* __restrict__ uQW, const float* __restrict__ uQB,
    const float* __restrict__ uKW, const float* __restrict__ uKB,
    const float* __restrict__ uVW, const float* __restrict__ uVB,
    float* __restrict__ outp)
{
    int f = blockIdx.x, b = blockIdx.y;
    __shared__ float Ub[128*9];
    __shared__ float Wj[128*9];
    __shared__ float zj[128];
    __shared__ float vm[128];
    __shared__ float Mm[81];
    __shared__ float wvm[9], bvec[9];
    __shared__ float cc_[2];
    int t = threadIdx.x;
    for (int i = t; i < 1152; i += 256) Ub[i] = U[(size_t)b*1152 + i];
    const float* qw = uQW + (size_t)f*1152;
    const float* kw = uKW + (size_t)f*1152;
    const float* vw = uVW + (size_t)f*1152;
    const float* qb = uQB + (size_t)f*128;
    const float* kb = uKB + (size_t)f*128;
    const float* vb = uVB + (size_t)f*128;

    if (t < 81) {
        int t1 = t/9, s1 = t%9; float a = 0.f;
        for (int kk = 0; kk < 128; ++kk) a += qw[kk*9 + t1]*kw[kk*9 + s1];
        Mm[t] = a;
    } else if (t < 90) {
        int s1 = t - 81; float a = 0.f;
        for (int kk = 0; kk < 128; ++kk) a += kw[kk*9 + s1]*qb[kk];
        bvec[s1] = a;
    } else if (t < 99) {
        int t1 = t - 90; float a = 0.f;
        for (int kk = 0; kk < 128; ++kk) a += vw[kk*9 + t1];
        wvm[t1] = a * (1.0f/128.0f);
    } else if (t == 99) {
        float a = 0.f, c2 = 0.f;
        for (int kk = 0; kk < 128; ++kk) { a += qb[kk]*kb[kk]; c2 += vb[kk]; }
        cc_[0] = a; cc_[1] = c2 * (1.0f/128.0f);
    }
    __syncthreads();

    if (t < 128) {
        int j = t;
        for (int t1 = 0; t1 < 9; ++t1) {
            float a = 0.f;
            for (int s1 = 0; s1 < 9; ++s1) a += Mm[t1*9 + s1]*Ub[j*9 + s1];
            Wj[j*9 + t1] = a;
        }
        float z = cc_[0], v2 = cc_[1];
        for (int s1 = 0; s1 < 9; ++s1) { z += bvec[s1]*Ub[j*9 + s1]; v2 += wvm[s1]*Ub[j*9 + s1]; }
        zj[j] = z; vm[j] = v2;
    }
    __syncthreads();

    int i = t >> 1, half = t & 1;
    float ui[9];
#pragma unroll
    for (int s1 = 0; s1 < 9; ++s1) ui[s1] = Ub[i*9 + s1];

    float mx = -1e30f;
    for (int jj = 0; jj < 64; ++jj) {
        int j = half*64 + jj;
        float a = zj[j];
#pragma unroll
        for (int s1 = 0; s1 < 9; ++s1) a += ui[s1]*Wj[j*9 + s1];
        mx = fmaxf(mx, a * (1.0f/3.0f));
    }
    mx = fmaxf(mx, __shfl_xor(mx, 1));
    float sum = 0.f, o = 0.f;
    for (int jj = 0; jj < 64; ++jj) {
        int j = half*64 + jj;
        float a = zj[j];
#pragma unroll
        for (int s1 = 0; s1 < 9; ++s1) a += ui[s1]*Wj[j*9 + s1];
        float p = expf(a * (1.0f/3.0f) - mx);
        sum += p; o += p*vm[j];
    }
    sum += __shfl_xor(sum, 1);
    o   += __shfl_xor(o, 1);
    if (half == 0) {
        float base;
        if (f > 0) base = ui[f];
        else { base = 0.f; for (int s1 = 0; s1 < 9; ++s1) base += ui[s1]; base *= (1.0f/9.0f); }
        outp[((size_t)b*128 + i)*10 + f] = o/sum + base;
    }
}

// ---------------------------------------------------------------------------
// Merge attention (features 3..8), writes output column 9 (unchanged).
// ---------------------------------------------------------------------------
__global__ __launch_bounds__(256) void merge_kernel(
    const float* __restrict__ U,
    const float* __restrict__ mQW, const float* __restrict__ mQB,
    const float* __restrict__ mKW, const float* __restrict__ mKB,
    const float* __restrict__ mVW, const float* __restrict__ mVB,
    float* __restrict__ outp)
{
    int b = blockIdx.x;
    __shared__ float Us[128*6];
    __shared__ float Wj[128*6];
    __shared__ float zj[128];
    __shared__ float vm[128];
    __shared__ float Mm[36];
    __shared__ float wvm[6], bvec[6];
    __shared__ float cc_[2];
    int t = threadIdx.x;
    for (int i = t; i < 768; i += 256) {
        int j = i/6, tt = i - j*6;
        Us[i] = U[(size_t)b*1152 + j*9 + 3 + tt];
    }
    if (t < 36) {
        int t1 = t/6, s1 = t%6; float a = 0.f;
        for (int kk = 0; kk < 128; ++kk) a += mQW[kk*6 + t1]*mKW[kk*6 + s1];
        Mm[t] = a;
    } else if (t < 42) {
        int s1 = t - 36; float a = 0.f;
        for (int kk = 0; kk < 128; ++kk) a += mKW[kk*6 + s1]*mQB[kk];
        bvec[s1] = a;
    } else if (t < 48) {
        int t1 = t - 42; float a = 0.f;
        for (int kk = 0; kk < 128; ++kk) a += mVW[kk*6 + t1];
        wvm[t1] = a * (1.0f/128.0f);
    } else if (t == 48) {
        float a = 0.f, c2 = 0.f;
        for (int kk = 0; kk < 128; ++kk) { a += mQB[kk]*mKB[kk]; c2 += mVB[kk]; }
        cc_[0] = a; cc_[1] = c2 * (1.0f/128.0f);
    }
    __syncthreads();

    if (t < 128) {
        int j = t;
        for (int t1 = 0; t1 < 6; ++t1) {
            float a = 0.f;
            for (int s1 = 0; s1 < 6; ++s1) a += Mm[t1*6 + s1]*Us[j*6 + s1];
            Wj[j*6 + t1] = a;
        }
        float z = cc_[0], v2 = cc_[1];
        for (int s1 = 0; s1 < 6; ++s1) { z += bvec[s1]*Us[j*6 + s1]; v2 += wvm[s1]*Us[j*6 + s1]; }
        zj[j] = z; vm[j] = v2;
    }
    __syncthreads();

    int i = t >> 1, half = t & 1;
    float ui[6];
#pragma unroll
    for (int s1 = 0; s1 < 6; ++s1) ui[s1] = Us[i*6 + s1];

    float mx = -1e30f;
    for (int jj = 0; jj < 64; ++jj) {
        int j = half*64 + jj;
        float a = zj[j];
#pragma unroll
        for (int s1 = 0; s1 < 6; ++s1) a += ui[s1]*Wj[j*6 + s1];
        mx = fmaxf(mx, a * (1.0f/3.0f));
    }
    mx = fmaxf(mx, __shfl_xor(mx, 1));
    float sum = 0.f, o = 0.f;
    for (int jj = 0; jj < 64; ++jj) {
        int j = half*64 + jj;
        float a = zj[j];
#pragma unroll
        for (int s1 = 0; s1 < 6; ++s1) a += ui[s1]*Wj[j*6 + s1];
        float p = expf(a * (1.0f/3.0f) - mx);
        sum += p; o += p*vm[j];
    }
    sum += __shfl_xor(sum, 1);
    o   += __shfl_xor(o, 1);
    if (half == 0) {
        float base = 0.f;
        for (int s1 = 0; s1 < 6; ++s1) base += ui[s1];
        base *= (1.0f/6.0f);
        outp[((size_t)b*128 + i)*10 + 9] = o/sum + base;
    }
}

// ---------------------------------------------------------------------------
extern "C" void kernel_launch(void* const* d_in, const int* in_sizes, int n_in,
                              void* d_out, int out_size, void* d_ws, size_t ws_size,
                              hipStream_t stream)
{
    const float* Y     = (const float*)d_in[0];
    const float* Gin   = (const float*)d_in[1];
    const float* posW1 = (const float*)d_in[2];
    const float* posB1 = (const float*)d_in[3];
    const float* posW2 = (const float*)d_in[4];
    const float* posB2 = (const float*)d_in[5];
    const float* posW3 = (const float*)d_in[6];
    const float* posB3 = (const float*)d_in[7];
    const float* Wq    = (const float*)d_in[8];
    const float* bq    = (const float*)d_in[9];
    const float* Wk    = (const float*)d_in[10];
    const float* bk    = (const float*)d_in[11];
    const float* Wv    = (const float*)d_in[12];
    const float* bv    = (const float*)d_in[13];
    const float* Wo    = (const float*)d_in[14];
    const float* bo    = (const float*)d_in[15];
    const float* lnG   = (const float*)d_in[16];
    const float* lnB   = (const float*)d_in[17];
    const float* fnG   = (const float*)d_in[18];
    const float* fnB   = (const float*)d_in[19];
    const float* poolW = (const float*)d_in[20];
    const float* uQW   = (const float*)d_in[21];
    const float* uQB   = (const float*)d_in[22];
    const float* uKW   = (const float*)d_in[23];
    const float* uKB   = (const float*)d_in[24];
    const float* uVW   = (const float*)d_in[25];
    const float* uVB   = (const float*)d_in[26];
    const float* mQW   = (const float*)d_in[27];
    const float* mQB   = (const float*)d_in[28];
    const float* mKW   = (const float*)d_in[29];
    const float* mKB   = (const float*)d_in[30];
    const float* mVW   = (const float*)d_in[31];
    const float* mVB   = (const float*)d_in[32];

    const size_t xelems = (size_t)F_ * BS_ * 128;     // 4,718,592
    char* p = (char*)d_ws;
    float* xA   = (float*)p;               p += xelems*4;
    float* xB   = (float*)p;               p += xelems*4;
    float* Ubuf = (float*)p;               p += 16384*4;
    unsigned short* xAb = (unsigned short*)p; p += xelems*2;
    unsigned short* Wqb = (unsigned short*)p; p += WELEMS*2;
    unsigned short* Wkb = (unsigned short*)p; p += WELEMS*2;
    unsigned short* Wvb = (unsigned short*)p; p += WELEMS*2;
    unsigned short* Wob = (unsigned short*)p; p += WELEMS*2;
    size_t fixed_bytes = (size_t)(p - (char*)d_ws);

    size_t avail = (ws_size > fixed_bytes) ? (ws_size - fixed_bytes) : 0;
    size_t per_f = 8UL * PERBUF;            // q(2B)+k(2B)+wv(2B)+Vt(2B eff) per elem
    int FC = (int)(avail / per_f);
    if (FC < 1) FC = 1;
    if (FC > F_) FC = F_;

    unsigned short* qb  = (unsigned short*)p;
    unsigned short* kb  = qb + (size_t)FC*PERBUF;
    unsigned short* wvb = kb + (size_t)FC*PERBUF;
    unsigned int*   vtb = (unsigned int*)(wvb + (size_t)FC*PERBUF);

    // Weight conversion to bf16 (once per launch, ~19 MB)
    {
        int n = (int)WELEMS, grid = (n/8 + 255)/256;
        cvt_kernel<<<grid, 256, 0, stream>>>(Wq, Wqb, n);
        cvt_kernel<<<grid, 256, 0, stream>>>(Wk, Wkb, n);
        cvt_kernel<<<grid, 256, 0, stream>>>(Wv, Wvb, n);
        cvt_kernel<<<grid, 256, 0, stream>>>(Wo, Wob, n);
    }

    posnet_kernel<<<dim3(1024, 1, F_), 256, 0, stream>>>(
        Y, Gin, posW1, posB1, posW2, posB2, posW3, posB3, xA, xAb);

    for (int l = 0; l < 2; ++l) {
        for (int f0 = 0; f0 < F_; f0 += FC) {
            int fc = (F_ - f0) < FC ? (F_ - f0) : FC;
            qkv_mfma_kernel<<<dim3(32, 8, 3*fc), 256, 0, stream>>>(
                xAb, Wqb, Wkb, Wvb, bq, bk, bv, qb, kb, vtb, l, f0);
            attn_mfma_kernel<<<dim3(256*fc), 256, 0, stream>>>(qb, kb, vtb, wvb);
            outproj_mfma_kernel<<<dim3(32, 1, fc), 256, 0, stream>>>(
                wvb, Wob, bo, xA, xB, l, f0);
            ln_kernel<<<dim3(fc*1024), 256, 0, stream>>>(
                xB, xA, xAb, lnG + (size_t)(l*F_ + f0)*128, lnB + (size_t)(l*F_ + f0)*128, f0, 128);
        }
    }

    for (int f0 = 0; f0 < F_; f0 += FC) {
        int fc = (F_ - f0) < FC ? (F_ - f0) : FC;
        ln_kernel<<<dim3(fc*1024), 256, 0, stream>>>(xA, xB, xAb, fnG, fnB, f0, 0);
        pool_kernel<<<dim3(fc, 8), 256, 0, stream>>>(xB, poolW, Ubuf, f0);
    }

    unified_kernel<<<dim3(F_, B_), 256, 0, stream>>>(
        Ubuf, uQW, uQB, uKW, uKB, uVW, uVB, (float*)d_out);
    merge_kernel<<<dim3(B_), 256, 0, stream>>>(
        Ubuf, mQW, mQB, mKW, mKB, mVW, mVB, (float*)d_out);
}